// Round 9
// baseline (686.665 us; speedup 1.0000x reference)
//
#include <hip/hip_runtime.h>
#include <hip/hip_bf16.h>

#define NQ 20
#define NLAY 51            // N_LAYER+1
#define FEAT 128
#define BATCH 128
#define NN (BATCH * NQ * NLAY)   // 130560
#define NE 524288
#define NPAIR (BATCH * NQ * NQ)  // 51200
#define NB (NN / 256)            // 510

typedef _Float16 half8 __attribute__((ext_vector_type(8)));
typedef float floatx4 __attribute__((ext_vector_type(4)));

__device__ __forceinline__ float lrelu(float v) { return v >= 0.f ? v : 0.01f * v; }

// ---------------- CSR build ----------------
__global__ void k_count(const int* __restrict__ dst, int* __restrict__ cnt) {
    int e = blockIdx.x * 256 + threadIdx.x;
    atomicAdd(&cnt[dst[e]], 1);
}

__global__ void k_partial(const int* __restrict__ cnt, int* __restrict__ part) {
    __shared__ int sm[256];
    int t = threadIdx.x;
    sm[t] = cnt[blockIdx.x * 256 + t];
    __syncthreads();
    for (int s = 128; s > 0; s >>= 1) {
        if (t < s) sm[t] += sm[t + s];
        __syncthreads();
    }
    if (t == 0) part[blockIdx.x] = sm[0];
}

__global__ void k_scanpart(const int* __restrict__ part, int* __restrict__ pscan, int nb) {
    __shared__ int sm[512];
    int t = threadIdx.x;
    int v = (t < nb) ? part[t] : 0;
    sm[t] = v;
    __syncthreads();
    for (int s = 1; s < 512; s <<= 1) {
        int add = (t >= s) ? sm[t - s] : 0;
        __syncthreads();
        sm[t] += add;
        __syncthreads();
    }
    if (t < nb) pscan[t] = sm[t] - v;   // exclusive
}

// offsets + dinv + packed meta {off, deg, dinv_bits, x[node]} (deterministic scan chain)
__global__ void k_offsets(const int* __restrict__ cnt, const int* __restrict__ pscan,
                          const int* __restrict__ x,
                          int* __restrict__ offs, float* __restrict__ dinv,
                          int4* __restrict__ meta) {
    __shared__ int sm[256];
    int t = threadIdx.x, g = blockIdx.x * 256 + t;
    int v = cnt[g];
    sm[t] = v;
    __syncthreads();
    for (int s = 1; s < 256; s <<= 1) {
        int add = (t >= s) ? sm[t - s] : 0;
        __syncthreads();
        sm[t] += add;
        __syncthreads();
    }
    int off = pscan[blockIdx.x] + sm[t] - v;
    float di = rsqrtf((float)(v + 1));  // +1 self loop
    offs[g] = off;
    dinv[g] = di;
    meta[g] = make_int4(off, v, __float_as_int(di), x[g]);
}

// fill packed edges {src, dinv[src]_bits}
__global__ void k_fill(const int* __restrict__ src, const int* __restrict__ dst,
                       const int* __restrict__ offs, int* __restrict__ fill,
                       const float* __restrict__ dinv, int2* __restrict__ csre) {
    int e = blockIdx.x * 256 + threadIdx.x;
    int d = dst[e];
    int s = src[e];
    int pos = offs[d] + atomicAdd(&fill[d], 1);
    csre[pos] = make_int2(s, __float_as_int(dinv[s]));
}

// ---------------- degree-bucketed node list (deterministic counting sort) ----------------
// per-block 32-bucket histogram (block-local LDS atomics: exact counts)
__global__ void k_bh(const int4* __restrict__ meta, int* __restrict__ parth) {
    __shared__ int lh[32];
    int t = threadIdx.x;
    if (t < 32) lh[t] = 0;
    __syncthreads();
    atomicAdd(&lh[min(meta[blockIdx.x * 256 + t].y, 31)], 1);
    __syncthreads();
    if (t < 32) parth[blockIdx.x * 32 + t] = lh[t];
}

// hierarchical exclusive scan -> gbase[blk][b] (one block, 512 thr: 32 buckets x 16 chunks)
__global__ void k_bs(const int* __restrict__ parth, int* __restrict__ gbase) {
    __shared__ int sm[512];
    __shared__ int btot[32];
    __shared__ int bb[32];
    int t = threadIdx.x;
    int b = t >> 4, c = t & 15;
    int hi = min(c * 32 + 32, NB);
    int s = 0;
    for (int blk = c * 32; blk < hi; blk++) s += parth[blk * 32 + b];
    sm[t] = s;
    __syncthreads();
    if (c == 0) {
        int acc = 0;
        for (int cc = 0; cc < 16; cc++) {
            int tmp = sm[b * 16 + cc];
            sm[b * 16 + cc] = acc;
            acc += tmp;
        }
        btot[b] = acc;
    }
    __syncthreads();
    if (t == 0) {
        int acc = 0;
        for (int i = 0; i < 32; i++) { bb[i] = acc; acc += btot[i]; }
    }
    __syncthreads();
    int acc = bb[b] + sm[b * 16 + c];
    for (int blk = c * 32; blk < hi; blk++) {
        gbase[blk * 32 + b] = acc;
        acc += parth[blk * 32 + b];
    }
}

// placement: slot = gbase[blk][bucket] + block-local rank (coverage exact by construction)
__global__ void k_bp(const int4* __restrict__ meta, const int* __restrict__ gbase,
                     int* __restrict__ nlist) {
    __shared__ int lr[32];
    int t = threadIdx.x;
    if (t < 32) lr[t] = 0;
    __syncthreads();
    int g = blockIdx.x * 256 + t;
    int b = min(meta[g].y, 31);
    int r = atomicAdd(&lr[b], 1);
    nlist[gbase[blockIdx.x * 32 + b] + r] = g;
}

// ---------------- weight transpose + fp16 hi/lo split, PACKED MFMA-fragment layout -------
#define OFF_GCN 0                 // 5 x K=128 N=128
#define OFF_P0  81920             // combined mw0: K=128 N=512
#define OFF_M1  147456            // mw1: K=256 N=128
#define OFF_M2  180224            // mw2: K=128 N=128
#define OFF_M3  196608            // mw3: K=128 N=64
#define OFF_M4  204800            // mw4: K=64  N=64
#define TS_TOTAL 208896

__global__ void k_tsplit_all(const float* __restrict__ gw, const float* __restrict__ mw0,
                             const float* __restrict__ mw1, const float* __restrict__ mw2,
                             const float* __restrict__ mw3, const float* __restrict__ mw4,
                             _Float16* __restrict__ hi, _Float16* __restrict__ lo) {
    int idx = blockIdx.x * 256 + threadIdx.x;
    const float* src;
    int K, N, rel;
    bool p0 = false;
    if (idx < OFF_P0) {
        int L = (idx - OFF_GCN) >> 14; rel = (idx - OFF_GCN) & 16383;
        src = gw + L * 16384; K = 128; N = 128;
    } else if (idx < OFF_M1) {
        rel = idx - OFF_P0; src = mw0; K = 128; N = 512; p0 = true;
    } else if (idx < OFF_M2) {
        rel = idx - OFF_M1;  src = mw1; K = 256; N = 128;
    } else if (idx < OFF_M3) {
        rel = idx - OFF_M2;  src = mw2; K = 128; N = 128;
    } else if (idx < OFF_M4) {
        rel = idx - OFF_M3;  src = mw3; K = 128; N = 64;
    } else {
        rel = idx - OFF_M4;  src = mw4; K = 64;  N = 64;
    }
    int kblks = K >> 5;
    int j = rel & 7;
    int lane = (rel >> 3) & 63;
    int t2 = rel >> 9;
    int kblk = t2 % kblks;
    int ntile = t2 / kblks;
    int col = ntile * 16 + (lane & 15);
    int k = kblk * 32 + ((lane >> 4) << 3) + j;
    float f;
    if (p0) {
        f = (col < 256) ? src[k * 256 + col] : src[(k + 128) * 256 + (col - 256)];
    } else {
        f = src[k * N + col];
    }
    _Float16 h = (_Float16)f;
    hi[idx] = h;
    lo[idx] = (_Float16)(f - (float)h);
}

// ---------------- split-fp16 MFMA GEMM ----------------
// B pre-packed in fragment order (hi/lo). 3-product Markidis split, fp32 accumulate.
// GATHA: A-rows indirected through gmap (embedding-gather fusion).
template <int NT_N, bool LEAKY, bool BIAS, bool P0SPLIT, bool FUSEA, bool GATHA>
__launch_bounds__(256, 2)
__global__ void hgemm(const float* __restrict__ A,
                      const float* __restrict__ FA, const float* __restrict__ FB,
                      const _Float16* __restrict__ Bh, const _Float16* __restrict__ Bl,
                      const float* __restrict__ bias,
                      float* __restrict__ C, float* __restrict__ C2,
                      int N, int K, const int* __restrict__ gmap) {
    const int KB = K >> 5;
    const int lane = threadIdx.x & 63;
    const int wid = threadIdx.x >> 6;
    const int lm = lane & 15, lq = lane >> 4;
    const int m0 = blockIdx.x * 128 + wid * 32;
    const int n0t = blockIdx.y * NT_N;

    const float* arow[2];
    const float* brow[2];
#pragma unroll
    for (int mt = 0; mt < 2; mt++) {
        int row = m0 + mt * 16 + lm;
        if (FUSEA) {
            int b = row / (NQ * NQ);
            int rr = row - b * (NQ * NQ);
            int i = rr / NQ;
            int j = rr - i * NQ;
            arow[mt] = FA + (size_t)(b * NQ + i) * 256;
            brow[mt] = FB + (size_t)(b * NQ + j) * 256;
        } else if (GATHA) {
            arow[mt] = A + (size_t)gmap[row] * K;
        } else {
            arow[mt] = A + (size_t)row * K;
        }
    }

    floatx4 acc[2][NT_N];
#pragma unroll
    for (int mt = 0; mt < 2; mt++)
#pragma unroll
        for (int nt = 0; nt < NT_N; nt++) acc[mt][nt] = (floatx4)0.f;

    for (int kb = 0; kb < KB; kb++) {
        const int k0 = kb * 32 + lq * 8;
        half8 ahi[2], alo[2];
#pragma unroll
        for (int mt = 0; mt < 2; mt++) {
            floatx4 av0, av1;
            if (FUSEA) {
                floatx4 fa0 = *(const floatx4*)(arow[mt] + k0);
                floatx4 fa1 = *(const floatx4*)(arow[mt] + k0 + 4);
                floatx4 fb0 = *(const floatx4*)(brow[mt] + k0);
                floatx4 fb1 = *(const floatx4*)(brow[mt] + k0 + 4);
#pragma unroll
                for (int q = 0; q < 4; q++) {
                    av0[q] = lrelu(fa0[q] + fb0[q]);
                    av1[q] = lrelu(fa1[q] + fb1[q]);
                }
            } else {
                av0 = *(const floatx4*)(arow[mt] + k0);
                av1 = *(const floatx4*)(arow[mt] + k0 + 4);
            }
#pragma unroll
            for (int q = 0; q < 4; q++) {
                _Float16 h0 = (_Float16)av0[q];
                ahi[mt][q] = h0;
                alo[mt][q] = (_Float16)(av0[q] - (float)h0);
                _Float16 h1 = (_Float16)av1[q];
                ahi[mt][4 + q] = h1;
                alo[mt][4 + q] = (_Float16)(av1[q] - (float)h1);
            }
        }
#pragma unroll
        for (int nt = 0; nt < NT_N; nt++) {
            size_t boff = (((size_t)(n0t + nt) * KB + kb) * 64 + lane) * 8;
            half8 bhi = *(const half8*)(Bh + boff);
            half8 blo = *(const half8*)(Bl + boff);
#pragma unroll
            for (int mt = 0; mt < 2; mt++) {
                acc[mt][nt] = __builtin_amdgcn_mfma_f32_16x16x32_f16(ahi[mt], bhi, acc[mt][nt], 0, 0, 0);
                acc[mt][nt] = __builtin_amdgcn_mfma_f32_16x16x32_f16(ahi[mt], blo, acc[mt][nt], 0, 0, 0);
                acc[mt][nt] = __builtin_amdgcn_mfma_f32_16x16x32_f16(alo[mt], bhi, acc[mt][nt], 0, 0, 0);
            }
        }
    }

    // epilogue: C/D layout col=lane&15, row=(lane>>4)*4+reg
#pragma unroll
    for (int nt = 0; nt < NT_N; nt++) {
        int col = (n0t + nt) * 16 + lm;
        float bv = (BIAS || P0SPLIT) ? bias[col < 256 ? col : 0] : 0.f;
#pragma unroll
        for (int mt = 0; mt < 2; mt++) {
#pragma unroll
            for (int r = 0; r < 4; r++) {
                int row = m0 + mt * 16 + lq * 4 + r;
                float val = acc[mt][nt][r];
                if (P0SPLIT) {
                    if (col < 256) C[(size_t)row * 256 + col] = val + bv;
                    else C2[(size_t)row * 256 + col - 256] = val;
                } else {
                    if (BIAS) val += bv;
                    if (LEAKY) val = lrelu(val);
                    C[(size_t)row * N + col] = val;
                }
            }
        }
    }
}

// ---------------- GCN aggregation + bias + leaky + residual (ping-pong) ----------------
// half-wave per TWO equal-degree nodes via deterministic degree-sorted nlist.
// Node ids CLAMPED to [0,NN) before any use -> wild reads/writes impossible.
// embt != null: residual rows come from embt[meta.w] (layer 0, h0 never materialized).
__global__ void k_agg(const float* __restrict__ hw, const float* __restrict__ hold,
                      const int4* __restrict__ meta, const int2* __restrict__ csre,
                      const int* __restrict__ nlist,
                      const float* __restrict__ bias, float* __restrict__ hnew,
                      const float* __restrict__ embt) {
    int tid = threadIdx.x;
    int sl = tid & 31;
    int p = blockIdx.x * 8 + (tid >> 5);
    int n0 = nlist[p * 2], n1 = nlist[p * 2 + 1];
    n0 = ((unsigned)n0 < (unsigned)NN) ? n0 : 0;   // safety clamp
    n1 = ((unsigned)n1 < (unsigned)NN) ? n1 : 0;
    int4 m0 = meta[n0], m1 = meta[n1];
    float di0 = __int_as_float(m0.z), di1 = __int_as_float(m1.z);
    int off0 = m0.x, deg0 = m0.y;
    int off1 = m1.x, deg1 = m1.y;
    float4 v0 = ((const float4*)(hw + (size_t)n0 * FEAT))[sl];
    float4 v1 = ((const float4*)(hw + (size_t)n1 * FEAT))[sl];
    float4 ho0, ho1;
    if (embt) {
        ho0 = ((const float4*)(embt + (size_t)m0.w * FEAT))[sl];
        ho1 = ((const float4*)(embt + (size_t)m1.w * FEAT))[sl];
    } else {
        ho0 = ((const float4*)(hold + (size_t)n0 * FEAT))[sl];
        ho1 = ((const float4*)(hold + (size_t)n1 * FEAT))[sl];
    }
    float s20 = di0 * di0, s21 = di1 * di1;
    float a0x = v0.x * s20, a0y = v0.y * s20, a0z = v0.z * s20, a0w = v0.w * s20;
    float a1x = v1.x * s21, a1y = v1.y * s21, a1z = v1.z * s21, a1w = v1.w * s21;
    int d0c = max(deg0 - 1, 0), d1c = max(deg1 - 1, 0);
    int dm = max(deg0, deg1);   // equal-degree pairs: dm == deg0 == deg1 almost always
    for (int e = 0; e < dm; e += 4) {
        int2 e00 = csre[off0 + min(e,     d0c)];
        int2 e01 = csre[off0 + min(e + 1, d0c)];
        int2 e02 = csre[off0 + min(e + 2, d0c)];
        int2 e03 = csre[off0 + min(e + 3, d0c)];
        int2 e10 = csre[off1 + min(e,     d1c)];
        int2 e11 = csre[off1 + min(e + 1, d1c)];
        int2 e12 = csre[off1 + min(e + 2, d1c)];
        int2 e13 = csre[off1 + min(e + 3, d1c)];
        float4 u00 = ((const float4*)(hw + (size_t)e00.x * FEAT))[sl];
        float4 u01 = ((const float4*)(hw + (size_t)e01.x * FEAT))[sl];
        float4 u02 = ((const float4*)(hw + (size_t)e02.x * FEAT))[sl];
        float4 u03 = ((const float4*)(hw + (size_t)e03.x * FEAT))[sl];
        float4 u10 = ((const float4*)(hw + (size_t)e10.x * FEAT))[sl];
        float4 u11 = ((const float4*)(hw + (size_t)e11.x * FEAT))[sl];
        float4 u12 = ((const float4*)(hw + (size_t)e12.x * FEAT))[sl];
        float4 u13 = ((const float4*)(hw + (size_t)e13.x * FEAT))[sl];
        float w00 = (e     < deg0) ? __int_as_float(e00.y) * di0 : 0.f;
        float w01 = (e + 1 < deg0) ? __int_as_float(e01.y) * di0 : 0.f;
        float w02 = (e + 2 < deg0) ? __int_as_float(e02.y) * di0 : 0.f;
        float w03 = (e + 3 < deg0) ? __int_as_float(e03.y) * di0 : 0.f;
        float w10 = (e     < deg1) ? __int_as_float(e10.y) * di1 : 0.f;
        float w11 = (e + 1 < deg1) ? __int_as_float(e11.y) * di1 : 0.f;
        float w12 = (e + 2 < deg1) ? __int_as_float(e12.y) * di1 : 0.f;
        float w13 = (e + 3 < deg1) ? __int_as_float(e13.y) * di1 : 0.f;
        a0x += u00.x * w00 + u01.x * w01 + u02.x * w02 + u03.x * w03;
        a0y += u00.y * w00 + u01.y * w01 + u02.y * w02 + u03.y * w03;
        a0z += u00.z * w00 + u01.z * w01 + u02.z * w02 + u03.z * w03;
        a0w += u00.w * w00 + u01.w * w01 + u02.w * w02 + u03.w * w03;
        a1x += u10.x * w10 + u11.x * w11 + u12.x * w12 + u13.x * w13;
        a1y += u10.y * w10 + u11.y * w11 + u12.y * w12 + u13.y * w13;
        a1z += u10.z * w10 + u11.z * w11 + u12.z * w12 + u13.z * w13;
        a1w += u10.w * w10 + u11.w * w11 + u12.w * w12 + u13.w * w13;
    }
    float4 bv = ((const float4*)bias)[sl];
    float4 r0, r1;
    r0.x = lrelu(a0x + bv.x) + ho0.x;
    r0.y = lrelu(a0y + bv.y) + ho0.y;
    r0.z = lrelu(a0z + bv.z) + ho0.z;
    r0.w = lrelu(a0w + bv.w) + ho0.w;
    r1.x = lrelu(a1x + bv.x) + ho1.x;
    r1.y = lrelu(a1y + bv.y) + ho1.y;
    r1.z = lrelu(a1z + bv.z) + ho1.z;
    r1.w = lrelu(a1w + bv.w) + ho1.w;
    ((float4*)(hnew + (size_t)n0 * FEAT))[sl] = r0;
    ((float4*)(hnew + (size_t)n1 * FEAT))[sl] = r1;
}

// ---------------- selective final agg (layer 4): S0 rows only -> hq, no leaky ----------------
__global__ void k_aggq(const float* __restrict__ hw, const float* __restrict__ h,
                       const int4* __restrict__ meta, const int2* __restrict__ csre,
                       const float* __restrict__ gbias, float* __restrict__ hq) {
    int tid = threadIdx.x;
    int sl = tid & 31;
    int q = blockIdx.x * 8 + (tid >> 5);   // 0..2559
    int b = q / NQ, i = q - b * NQ;
    int node = b * (NQ * NLAY) + i;
    int4 m = meta[node];
    float di = __int_as_float(m.z);
    int off = m.x, deg = m.y;
    float s2 = di * di;
    float4 v = ((const float4*)(hw + (size_t)node * FEAT))[sl];
    float ax = v.x * s2, ay = v.y * s2, az = v.z * s2, aw = v.w * s2;
    int dc = max(deg - 1, 0);
    for (int e = 0; e < deg; e += 4) {
        int2 e0 = csre[off + min(e,     dc)];
        int2 e1 = csre[off + min(e + 1, dc)];
        int2 e2 = csre[off + min(e + 2, dc)];
        int2 e3 = csre[off + min(e + 3, dc)];
        float4 u0 = ((const float4*)(hw + (size_t)e0.x * FEAT))[sl];
        float4 u1 = ((const float4*)(hw + (size_t)e1.x * FEAT))[sl];
        float4 u2 = ((const float4*)(hw + (size_t)e2.x * FEAT))[sl];
        float4 u3 = ((const float4*)(hw + (size_t)e3.x * FEAT))[sl];
        float w0 = (e     < deg) ? __int_as_float(e0.y) * di : 0.f;
        float w1 = (e + 1 < deg) ? __int_as_float(e1.y) * di : 0.f;
        float w2 = (e + 2 < deg) ? __int_as_float(e2.y) * di : 0.f;
        float w3 = (e + 3 < deg) ? __int_as_float(e3.y) * di : 0.f;
        ax += u0.x * w0 + u1.x * w1 + u2.x * w2 + u3.x * w3;
        ay += u0.y * w0 + u1.y * w1 + u2.y * w2 + u3.y * w3;
        az += u0.z * w0 + u1.z * w1 + u2.z * w2 + u3.z * w3;
        aw += u0.w * w0 + u1.w * w1 + u2.w * w2 + u3.w * w3;
    }
    float4 bv = ((const float4*)gbias)[sl];
    float4 ho = ((const float4*)(h + (size_t)node * FEAT))[sl];
    ((float4*)(hq + (size_t)q * FEAT))[sl] =
        make_float4(ax + bv.x + ho.x, ay + bv.y + ho.y, az + bv.z + ho.z, aw + bv.w + ho.w);
}

// ---------------- last layer + symmetrize, one block per batch ----------------
__global__ void k_lastsym(const float* __restrict__ X4, const float* __restrict__ mw5,
                          const float* __restrict__ mb5, float* __restrict__ out) {
    __shared__ float w[64];
    __shared__ float sm[NQ * NQ];
    int t = threadIdx.x;
    if (t < 64) w[t] = mw5[t];
    __syncthreads();
    int b = blockIdx.x;
    for (int p = t; p < NQ * NQ; p += 256) {
        const float4* row = (const float4*)(X4 + (size_t)(b * NQ * NQ + p) * 64);
        float s = 0.f;
#pragma unroll
        for (int k4 = 0; k4 < 16; k4++) {
            float4 v = row[k4];
            s += v.x * w[k4 * 4] + v.y * w[k4 * 4 + 1] + v.z * w[k4 * 4 + 2] + v.w * w[k4 * 4 + 3];
        }
        sm[p] = s + mb5[0];
    }
    __syncthreads();
    for (int r = t; r < NQ * NQ; r += 256) {
        int i = r / NQ, j = r % NQ;
        out[(size_t)b * NQ * NQ + r] = 0.5f * (sm[r] + sm[j * NQ + i]);
    }
}

extern "C" void kernel_launch(void* const* d_in, const int* in_sizes, int n_in,
                              void* d_out, int out_size, void* d_ws, size_t ws_size,
                              hipStream_t stream) {
    const int* x = (const int*)d_in[0];
    const int* ei = (const int*)d_in[1];
    const int* e_src = ei;
    const int* e_dst = ei + NE;
    const float* emb = (const float*)d_in[2];
    const float* gw = (const float*)d_in[3];   // [5,128,128]
    const float* gb = (const float*)d_in[4];   // [5,128]
    const float* mw0 = (const float*)d_in[5];
    const float* mb0 = (const float*)d_in[6];
    const float* mw1 = (const float*)d_in[7];
    const float* mb1 = (const float*)d_in[8];
    const float* mw2 = (const float*)d_in[9];
    const float* mb2 = (const float*)d_in[10];
    const float* mw3 = (const float*)d_in[11];
    const float* mb3 = (const float*)d_in[12];
    const float* mw4 = (const float*)d_in[13];
    const float* mb4 = (const float*)d_in[14];
    const float* mw5 = (const float*)d_in[15];
    const float* mb5 = (const float*)d_in[16];
    float* out = (float*)d_out;

    float* wsf = (float*)d_ws;
    size_t o = 0;
    const size_t HSZ = (size_t)NN * FEAT;             // 16,711,680
    float* hA = wsf + o; o += HSZ;
    float* hw = wsf + o; o += HSZ;
    float* hB = wsf + o; o += HSZ;
    int* cnt  = (int*)(wsf + o); o += NN;
    int* fill = (int*)(wsf + o); o += NN;   // adjacent to cnt -> single memset
    int* offs = (int*)(wsf + o); o += NN;
    float* dinv = wsf + o; o += NN;
    int4* meta = (int4*)(wsf + o); o += 4 * (size_t)NN;
    int2* csre = (int2*)(wsf + o); o += 2 * (size_t)(NE + 8);  // +8 slop for deg-0 clamp
    int* part  = (int*)(wsf + o); o += 512;
    int* pscan = (int*)(wsf + o); o += 512;
    int* parth = (int*)(wsf + o); o += NB * 32;   // per-block degree histograms
    int* gbase = (int*)(wsf + o); o += NB * 32;   // per-(block,bucket) bases
    int* nlist = (int*)(wsf + o); o += NN;        // degree-sorted node list
    float* hq = wsf + o; o += (size_t)BATCH * NQ * FEAT;     // 327,680
    float* Abuf = wsf + o; o += (size_t)BATCH * NQ * 256;    // 655,360
    float* Bbuf = wsf + o; o += (size_t)BATCH * NQ * 256;    // 655,360
    _Float16* bt_hi = (_Float16*)(wsf + o); o += (TS_TOTAL + 2) / 2;
    _Float16* bt_lo = (_Float16*)(wsf + o); o += (TS_TOTAL + 2) / 2;
    // pair-phase aliases (buffers dead by then; hA holds h4 until aggq, hB/hw free after)
    float* X1 = hw;                         // 51200*128 (hw dead after aggq)
    float* X2 = hw + (size_t)NPAIR * 128;   // 51200*128
    float* X3 = hB;                         // 51200*64
    float* X4 = hB + (size_t)NPAIR * 64;    // 51200*64

    // --- weight transpose+split+pack ---
    k_tsplit_all<<<TS_TOTAL / 256, 256, 0, stream>>>(gw, mw0, mw1, mw2, mw3, mw4, bt_hi, bt_lo);

    // --- CSR build (deterministic scan chain, as in stable R7) ---
    hipMemsetAsync(cnt, 0, 2 * NN * sizeof(int), stream);    // cnt + fill
    hipMemsetAsync(csre + NE, 0, 8 * sizeof(int2), stream);  // slop: node 0, weight 0
    k_count<<<NE / 256, 256, 0, stream>>>(e_dst, cnt);
    k_partial<<<NB, 256, 0, stream>>>(cnt, part);
    k_scanpart<<<1, 512, 0, stream>>>(part, pscan, NB);
    k_offsets<<<NB, 256, 0, stream>>>(cnt, pscan, x, offs, dinv, meta);
    k_fill<<<NE / 256, 256, 0, stream>>>(e_src, e_dst, offs, fill, dinv, csre);

    // --- degree-sorted node list (deterministic counting sort; every slot written once) ---
    k_bh<<<NB, 256, 0, stream>>>(meta, parth);
    k_bs<<<1, 512, 0, stream>>>(parth, gbase);
    k_bp<<<NB, 256, 0, stream>>>(meta, gbase, nlist);

    // --- layer 0: gemm gathers A-rows straight from emb via x (h0 never materialized) ---
    hgemm<8, false, false, false, false, true><<<dim3(NN / 128, 1), 256, 0, stream>>>(
        emb, nullptr, nullptr, bt_hi + OFF_GCN, bt_lo + OFF_GCN,
        nullptr, hw, nullptr, FEAT, FEAT, x);
    // agg0: residual rows from emb[meta.w] -> h1 in hB
    k_agg<<<NN / 16, 256, 0, stream>>>(hw, nullptr, meta, csre, nlist, gb + 0 * FEAT, hB, emb);

    // --- layers 1..3: gemm(hin->hw) + agg(hw,hin->hout), ping-pong hB/hA ---
    float* hin = hB;
    float* hout = hA;
    for (int L = 1; L < 4; L++) {
        hgemm<8, false, false, false, false, false><<<dim3(NN / 128, 1), 256, 0, stream>>>(
            hin, nullptr, nullptr, bt_hi + OFF_GCN + L * 16384, bt_lo + OFF_GCN + L * 16384,
            nullptr, hw, nullptr, FEAT, FEAT, nullptr);
        k_agg<<<NN / 16, 256, 0, stream>>>(hw, hin, meta, csre, nlist, gb + (size_t)L * FEAT,
                                           hout, nullptr);
        float* t = hin; hin = hout; hout = t;
    }
    // h4 in hin (== hA)

    // --- layer 4: full gemm, selective agg (only the 2560 pair-phase rows) -> hq ---
    hgemm<8, false, false, false, false, false><<<dim3(NN / 128, 1), 256, 0, stream>>>(
        hin, nullptr, nullptr, bt_hi + OFF_GCN + 4 * 16384, bt_lo + OFF_GCN + 4 * 16384,
        nullptr, hw, nullptr, FEAT, FEAT, nullptr);
    k_aggq<<<(BATCH * NQ) / 8, 256, 0, stream>>>(hw, hin, meta, csre,
                                                 gb + 4 * (size_t)FEAT, hq);

    // --- pair MLP ---
    // combined P0: Abuf = hq@mw0_top + mb0 ; Bbuf = hq@mw0_bot   (M=2560, K=128, N=512)
    hgemm<8, false, false, true, false, false><<<dim3(20, 4), 256, 0, stream>>>(
        hq, nullptr, nullptr, bt_hi + OFF_P0, bt_lo + OFF_P0, mb0, Abuf, Bbuf, 512, 128, nullptr);
    // L1 fused pair0: A[p,:] = lrelu(Abuf[b,i,:] + Bbuf[b,j,:]) ; [51200,256]@[256,128]
    hgemm<8, true, true, false, true, false><<<dim3(NPAIR / 128, 1), 256, 0, stream>>>(
        nullptr, Abuf, Bbuf, bt_hi + OFF_M1, bt_lo + OFF_M1, mb1, X1, nullptr, 128, 256, nullptr);
    // L2: [51200,128] @ [128,128]
    hgemm<8, true, true, false, false, false><<<dim3(NPAIR / 128, 1), 256, 0, stream>>>(
        X1, nullptr, nullptr, bt_hi + OFF_M2, bt_lo + OFF_M2, mb2, X2, nullptr, 128, 128, nullptr);
    // L3: [51200,128] @ [128,64]
    hgemm<4, true, true, false, false, false><<<dim3(NPAIR / 128, 1), 256, 0, stream>>>(
        X2, nullptr, nullptr, bt_hi + OFF_M3, bt_lo + OFF_M3, mb3, X3, nullptr, 64, 128, nullptr);
    // L4: [51200,64] @ [64,64]
    hgemm<4, true, true, false, false, false><<<dim3(NPAIR / 128, 1), 256, 0, stream>>>(
        X3, nullptr, nullptr, bt_hi + OFF_M4, bt_lo + OFF_M4, mb4, X4, nullptr, 64, 64, nullptr);
    // L5 + symmetrize
    k_lastsym<<<BATCH, 256, 0, stream>>>(X4, mw5, mb5, out);
}

// Round 10
// 592.217 us; speedup vs baseline: 1.1595x; 1.1595x over previous
//
#include <hip/hip_runtime.h>
#include <hip/hip_bf16.h>

#define NQ 20
#define NLAY 51            // N_LAYER+1
#define FEAT 128
#define BATCH 128
#define NN (BATCH * NQ * NLAY)   // 130560
#define NE 524288
#define NPAIR (BATCH * NQ * NQ)  // 51200
#define NB (NN / 256)            // 510

typedef _Float16 half8 __attribute__((ext_vector_type(8)));
typedef float floatx4 __attribute__((ext_vector_type(4)));

__device__ __forceinline__ float lrelu(float v) { return v >= 0.f ? v : 0.01f * v; }

// ---------------- CSR build ----------------
__global__ void k_count(const int* __restrict__ dst, int* __restrict__ cnt) {
    int e = blockIdx.x * 256 + threadIdx.x;
    atomicAdd(&cnt[dst[e]], 1);
}

__global__ void k_partial(const int* __restrict__ cnt, int* __restrict__ part) {
    __shared__ int sm[256];
    int t = threadIdx.x;
    sm[t] = cnt[blockIdx.x * 256 + t];
    __syncthreads();
    for (int s = 128; s > 0; s >>= 1) {
        if (t < s) sm[t] += sm[t + s];
        __syncthreads();
    }
    if (t == 0) part[blockIdx.x] = sm[0];
}

__global__ void k_scanpart(const int* __restrict__ part, int* __restrict__ pscan, int nb) {
    __shared__ int sm[512];
    int t = threadIdx.x;
    int v = (t < nb) ? part[t] : 0;
    sm[t] = v;
    __syncthreads();
    for (int s = 1; s < 512; s <<= 1) {
        int add = (t >= s) ? sm[t - s] : 0;
        __syncthreads();
        sm[t] += add;
        __syncthreads();
    }
    if (t < nb) pscan[t] = sm[t] - v;   // exclusive
}

// offsets + dinv + packed meta {off, deg, dinv_bits, x[node]}
__global__ void k_offsets(const int* __restrict__ cnt, const int* __restrict__ pscan,
                          const int* __restrict__ x,
                          int* __restrict__ offs, float* __restrict__ dinv,
                          int4* __restrict__ meta) {
    __shared__ int sm[256];
    int t = threadIdx.x, g = blockIdx.x * 256 + t;
    int v = cnt[g];
    sm[t] = v;
    __syncthreads();
    for (int s = 1; s < 256; s <<= 1) {
        int add = (t >= s) ? sm[t - s] : 0;
        __syncthreads();
        sm[t] += add;
        __syncthreads();
    }
    int off = pscan[blockIdx.x] + sm[t] - v;
    float di = rsqrtf((float)(v + 1));  // +1 self loop
    offs[g] = off;
    dinv[g] = di;
    meta[g] = make_int4(off, v, __float_as_int(di), x[g]);
}

// fill packed edges {src, dinv[src]_bits}
__global__ void k_fill(const int* __restrict__ src, const int* __restrict__ dst,
                       const int* __restrict__ offs, int* __restrict__ fill,
                       const float* __restrict__ dinv, int2* __restrict__ csre) {
    int e = blockIdx.x * 256 + threadIdx.x;
    int d = dst[e];
    int s = src[e];
    int pos = offs[d] + atomicAdd(&fill[d], 1);
    csre[pos] = make_int2(s, __float_as_int(dinv[s]));
}

// ---------------- dependency-cone sets (replay-safe: sentinel-padded lists) ----------------
// S0 = 2560 pair rows (static). S1 = S0 ∪ N_in(S0). S2 = S1 ∪ N_in(S1).
__global__ void k_markS1(const int4* __restrict__ meta, const int2* __restrict__ csre,
                         int* __restrict__ flag) {
    int q = blockIdx.x * 256 + threadIdx.x;   // 0..2559
    if (q >= BATCH * NQ) return;
    int node = (q / NQ) * (NQ * NLAY) + (q % NQ);
    flag[node] = 1;
    int4 m = meta[node];
    for (int e = 0; e < m.y; e++) flag[csre[m.x + e].x] = 1;   // benign races (all write 1)
}

// iterate list1 (sentinel -1 padded, full NN slots, static grid)
__global__ void k_markS2(const int4* __restrict__ meta, const int2* __restrict__ csre,
                         const int* __restrict__ list1, int* __restrict__ flag) {
    int i = blockIdx.x * 256 + threadIdx.x;
    int node = list1[i];
    if ((unsigned)node >= (unsigned)NN) return;   // sentinel
    flag[node] = 1;
    int4 m = meta[node];
    for (int e = 0; e < m.y; e++) flag[csre[m.x + e].x] = 1;
}

// scan-ordered compaction: members land in slots [0,|S|) in ASCENDING node order
__global__ void k_emit(const int* __restrict__ flag, const int* __restrict__ pscan,
                       int* __restrict__ list) {
    __shared__ int sm[256];
    int t = threadIdx.x, g = blockIdx.x * 256 + t;
    int v = flag[g];
    sm[t] = v;
    __syncthreads();
    for (int s = 1; s < 256; s <<= 1) {
        int add = (t >= s) ? sm[t - s] : 0;
        __syncthreads();
        sm[t] += add;
        __syncthreads();
    }
    if (v) list[pscan[blockIdx.x] + sm[t] - 1] = g;
}

// ---------------- weight transpose + fp16 hi/lo split, PACKED MFMA-fragment layout -------
#define OFF_GCN 0                 // 5 x K=128 N=128
#define OFF_P0  81920             // combined mw0: K=128 N=512
#define OFF_M1  147456            // mw1: K=256 N=128
#define OFF_M2  180224            // mw2: K=128 N=128
#define OFF_M3  196608            // mw3: K=128 N=64
#define OFF_M4  204800            // mw4: K=64  N=64
#define TS_TOTAL 208896

__global__ void k_tsplit_all(const float* __restrict__ gw, const float* __restrict__ mw0,
                             const float* __restrict__ mw1, const float* __restrict__ mw2,
                             const float* __restrict__ mw3, const float* __restrict__ mw4,
                             _Float16* __restrict__ hi, _Float16* __restrict__ lo) {
    int idx = blockIdx.x * 256 + threadIdx.x;
    const float* src;
    int K, N, rel;
    bool p0 = false;
    if (idx < OFF_P0) {
        int L = (idx - OFF_GCN) >> 14; rel = (idx - OFF_GCN) & 16383;
        src = gw + L * 16384; K = 128; N = 128;
    } else if (idx < OFF_M1) {
        rel = idx - OFF_P0; src = mw0; K = 128; N = 512; p0 = true;
    } else if (idx < OFF_M2) {
        rel = idx - OFF_M1;  src = mw1; K = 256; N = 128;
    } else if (idx < OFF_M3) {
        rel = idx - OFF_M2;  src = mw2; K = 128; N = 128;
    } else if (idx < OFF_M4) {
        rel = idx - OFF_M3;  src = mw3; K = 128; N = 64;
    } else {
        rel = idx - OFF_M4;  src = mw4; K = 64;  N = 64;
    }
    int kblks = K >> 5;
    int j = rel & 7;
    int lane = (rel >> 3) & 63;
    int t2 = rel >> 9;
    int kblk = t2 % kblks;
    int ntile = t2 / kblks;
    int col = ntile * 16 + (lane & 15);
    int k = kblk * 32 + ((lane >> 4) << 3) + j;
    float f;
    if (p0) {
        f = (col < 256) ? src[k * 256 + col] : src[(k + 128) * 256 + (col - 256)];
    } else {
        f = src[k * N + col];
    }
    _Float16 h = (_Float16)f;
    hi[idx] = h;
    lo[idx] = (_Float16)(f - (float)h);
}

// ---------------- split-fp16 MFMA GEMM ----------------
// B pre-packed in fragment order (hi/lo). 3-product Markidis split, fp32 accumulate.
// GATHA: A-rows indirected through gmap (embedding-gather fusion).
template <int NT_N, bool LEAKY, bool BIAS, bool P0SPLIT, bool FUSEA, bool GATHA>
__launch_bounds__(256, 2)
__global__ void hgemm(const float* __restrict__ A,
                      const float* __restrict__ FA, const float* __restrict__ FB,
                      const _Float16* __restrict__ Bh, const _Float16* __restrict__ Bl,
                      const float* __restrict__ bias,
                      float* __restrict__ C, float* __restrict__ C2,
                      int N, int K, const int* __restrict__ gmap) {
    const int KB = K >> 5;
    const int lane = threadIdx.x & 63;
    const int wid = threadIdx.x >> 6;
    const int lm = lane & 15, lq = lane >> 4;
    const int m0 = blockIdx.x * 128 + wid * 32;
    const int n0t = blockIdx.y * NT_N;

    const float* arow[2];
    const float* brow[2];
#pragma unroll
    for (int mt = 0; mt < 2; mt++) {
        int row = m0 + mt * 16 + lm;
        if (FUSEA) {
            int b = row / (NQ * NQ);
            int rr = row - b * (NQ * NQ);
            int i = rr / NQ;
            int j = rr - i * NQ;
            arow[mt] = FA + (size_t)(b * NQ + i) * 256;
            brow[mt] = FB + (size_t)(b * NQ + j) * 256;
        } else if (GATHA) {
            arow[mt] = A + (size_t)gmap[row] * K;
        } else {
            arow[mt] = A + (size_t)row * K;
        }
    }

    floatx4 acc[2][NT_N];
#pragma unroll
    for (int mt = 0; mt < 2; mt++)
#pragma unroll
        for (int nt = 0; nt < NT_N; nt++) acc[mt][nt] = (floatx4)0.f;

    for (int kb = 0; kb < KB; kb++) {
        const int k0 = kb * 32 + lq * 8;
        half8 ahi[2], alo[2];
#pragma unroll
        for (int mt = 0; mt < 2; mt++) {
            floatx4 av0, av1;
            if (FUSEA) {
                floatx4 fa0 = *(const floatx4*)(arow[mt] + k0);
                floatx4 fa1 = *(const floatx4*)(arow[mt] + k0 + 4);
                floatx4 fb0 = *(const floatx4*)(brow[mt] + k0);
                floatx4 fb1 = *(const floatx4*)(brow[mt] + k0 + 4);
#pragma unroll
                for (int q = 0; q < 4; q++) {
                    av0[q] = lrelu(fa0[q] + fb0[q]);
                    av1[q] = lrelu(fa1[q] + fb1[q]);
                }
            } else {
                av0 = *(const floatx4*)(arow[mt] + k0);
                av1 = *(const floatx4*)(arow[mt] + k0 + 4);
            }
#pragma unroll
            for (int q = 0; q < 4; q++) {
                _Float16 h0 = (_Float16)av0[q];
                ahi[mt][q] = h0;
                alo[mt][q] = (_Float16)(av0[q] - (float)h0);
                _Float16 h1 = (_Float16)av1[q];
                ahi[mt][4 + q] = h1;
                alo[mt][4 + q] = (_Float16)(av1[q] - (float)h1);
            }
        }
#pragma unroll
        for (int nt = 0; nt < NT_N; nt++) {
            size_t boff = (((size_t)(n0t + nt) * KB + kb) * 64 + lane) * 8;
            half8 bhi = *(const half8*)(Bh + boff);
            half8 blo = *(const half8*)(Bl + boff);
#pragma unroll
            for (int mt = 0; mt < 2; mt++) {
                acc[mt][nt] = __builtin_amdgcn_mfma_f32_16x16x32_f16(ahi[mt], bhi, acc[mt][nt], 0, 0, 0);
                acc[mt][nt] = __builtin_amdgcn_mfma_f32_16x16x32_f16(ahi[mt], blo, acc[mt][nt], 0, 0, 0);
                acc[mt][nt] = __builtin_amdgcn_mfma_f32_16x16x32_f16(alo[mt], bhi, acc[mt][nt], 0, 0, 0);
            }
        }
    }

    // epilogue: C/D layout col=lane&15, row=(lane>>4)*4+reg
#pragma unroll
    for (int nt = 0; nt < NT_N; nt++) {
        int col = (n0t + nt) * 16 + lm;
        float bv = (BIAS || P0SPLIT) ? bias[col < 256 ? col : 0] : 0.f;
#pragma unroll
        for (int mt = 0; mt < 2; mt++) {
#pragma unroll
            for (int r = 0; r < 4; r++) {
                int row = m0 + mt * 16 + lq * 4 + r;
                float val = acc[mt][nt][r];
                if (P0SPLIT) {
                    if (col < 256) C[(size_t)row * 256 + col] = val + bv;
                    else C2[(size_t)row * 256 + col - 256] = val;
                } else {
                    if (BIAS) val += bv;
                    if (LEAKY) val = lrelu(val);
                    C[(size_t)row * N + col] = val;
                }
            }
        }
    }
}

// ---------------- GCN aggregation + bias + leaky + residual (ping-pong) ----------------
// half-wave per TWO nodes. list==null: sequential node ids (full layer, R7-proven).
// list!=null: sliced layer — sentinel(-1)-padded list, ids clamped, store suppressed
// for sentinel slots. Static grid either way; no device-count reads.
// embt != null: residual rows come from embt[meta.w] (layer 0, h0 never materialized).
__global__ void k_agg(const float* __restrict__ hw, const float* __restrict__ hold,
                      const int4* __restrict__ meta, const int2* __restrict__ csre,
                      const int* __restrict__ list,
                      const float* __restrict__ bias, float* __restrict__ hnew,
                      const float* __restrict__ embt) {
    int tid = threadIdx.x;
    int sl = tid & 31;
    int p = blockIdx.x * 8 + (tid >> 5);
    int n0, n1;
    bool val0 = true, val1 = true;
    if (list) {
        n0 = list[p * 2];
        n1 = list[p * 2 + 1];
        val0 = (unsigned)n0 < (unsigned)NN;
        val1 = (unsigned)n1 < (unsigned)NN;
        n0 = val0 ? n0 : 0;
        n1 = val1 ? n1 : 0;
    } else {
        n0 = p * 2;
        n1 = n0 + 1;
    }
    int4 m0 = meta[n0], m1 = meta[n1];
    float di0 = __int_as_float(m0.z), di1 = __int_as_float(m1.z);
    int off0 = m0.x, deg0 = val0 ? m0.y : 0;
    int off1 = m1.x, deg1 = val1 ? m1.y : 0;
    float4 v0 = ((const float4*)(hw + (size_t)n0 * FEAT))[sl];
    float4 v1 = ((const float4*)(hw + (size_t)n1 * FEAT))[sl];
    float4 ho0, ho1;
    if (embt) {
        ho0 = ((const float4*)(embt + (size_t)m0.w * FEAT))[sl];
        ho1 = ((const float4*)(embt + (size_t)m1.w * FEAT))[sl];
    } else {
        ho0 = ((const float4*)(hold + (size_t)n0 * FEAT))[sl];
        ho1 = ((const float4*)(hold + (size_t)n1 * FEAT))[sl];
    }
    float s20 = di0 * di0, s21 = di1 * di1;
    float a0x = v0.x * s20, a0y = v0.y * s20, a0z = v0.z * s20, a0w = v0.w * s20;
    float a1x = v1.x * s21, a1y = v1.y * s21, a1z = v1.z * s21, a1w = v1.w * s21;
    int d0c = max(deg0 - 1, 0), d1c = max(deg1 - 1, 0);
    int dm = max(deg0, deg1);
    for (int e = 0; e < dm; e += 4) {
        int2 e00 = csre[off0 + min(e,     d0c)];
        int2 e01 = csre[off0 + min(e + 1, d0c)];
        int2 e02 = csre[off0 + min(e + 2, d0c)];
        int2 e03 = csre[off0 + min(e + 3, d0c)];
        int2 e10 = csre[off1 + min(e,     d1c)];
        int2 e11 = csre[off1 + min(e + 1, d1c)];
        int2 e12 = csre[off1 + min(e + 2, d1c)];
        int2 e13 = csre[off1 + min(e + 3, d1c)];
        float4 u00 = ((const float4*)(hw + (size_t)e00.x * FEAT))[sl];
        float4 u01 = ((const float4*)(hw + (size_t)e01.x * FEAT))[sl];
        float4 u02 = ((const float4*)(hw + (size_t)e02.x * FEAT))[sl];
        float4 u03 = ((const float4*)(hw + (size_t)e03.x * FEAT))[sl];
        float4 u10 = ((const float4*)(hw + (size_t)e10.x * FEAT))[sl];
        float4 u11 = ((const float4*)(hw + (size_t)e11.x * FEAT))[sl];
        float4 u12 = ((const float4*)(hw + (size_t)e12.x * FEAT))[sl];
        float4 u13 = ((const float4*)(hw + (size_t)e13.x * FEAT))[sl];
        float w00 = (e     < deg0) ? __int_as_float(e00.y) * di0 : 0.f;
        float w01 = (e + 1 < deg0) ? __int_as_float(e01.y) * di0 : 0.f;
        float w02 = (e + 2 < deg0) ? __int_as_float(e02.y) * di0 : 0.f;
        float w03 = (e + 3 < deg0) ? __int_as_float(e03.y) * di0 : 0.f;
        float w10 = (e     < deg1) ? __int_as_float(e10.y) * di1 : 0.f;
        float w11 = (e + 1 < deg1) ? __int_as_float(e11.y) * di1 : 0.f;
        float w12 = (e + 2 < deg1) ? __int_as_float(e12.y) * di1 : 0.f;
        float w13 = (e + 3 < deg1) ? __int_as_float(e13.y) * di1 : 0.f;
        a0x += u00.x * w00 + u01.x * w01 + u02.x * w02 + u03.x * w03;
        a0y += u00.y * w00 + u01.y * w01 + u02.y * w02 + u03.y * w03;
        a0z += u00.z * w00 + u01.z * w01 + u02.z * w02 + u03.z * w03;
        a0w += u00.w * w00 + u01.w * w01 + u02.w * w02 + u03.w * w03;
        a1x += u10.x * w10 + u11.x * w11 + u12.x * w12 + u13.x * w13;
        a1y += u10.y * w10 + u11.y * w11 + u12.y * w12 + u13.y * w13;
        a1z += u10.z * w10 + u11.z * w11 + u12.z * w12 + u13.z * w13;
        a1w += u10.w * w10 + u11.w * w11 + u12.w * w12 + u13.w * w13;
    }
    float4 bv = ((const float4*)bias)[sl];
    float4 r0, r1;
    r0.x = lrelu(a0x + bv.x) + ho0.x;
    r0.y = lrelu(a0y + bv.y) + ho0.y;
    r0.z = lrelu(a0z + bv.z) + ho0.z;
    r0.w = lrelu(a0w + bv.w) + ho0.w;
    r1.x = lrelu(a1x + bv.x) + ho1.x;
    r1.y = lrelu(a1y + bv.y) + ho1.y;
    r1.z = lrelu(a1z + bv.z) + ho1.z;
    r1.w = lrelu(a1w + bv.w) + ho1.w;
    if (val0) ((float4*)(hnew + (size_t)n0 * FEAT))[sl] = r0;
    if (val1) ((float4*)(hnew + (size_t)n1 * FEAT))[sl] = r1;
}

// ---------------- selective final agg (layer 4): S0 rows only -> hq, no leaky ----------------
__global__ void k_aggq(const float* __restrict__ hw, const float* __restrict__ h,
                       const int4* __restrict__ meta, const int2* __restrict__ csre,
                       const float* __restrict__ gbias, float* __restrict__ hq) {
    int tid = threadIdx.x;
    int sl = tid & 31;
    int q = blockIdx.x * 8 + (tid >> 5);   // 0..2559
    int b = q / NQ, i = q - b * NQ;
    int node = b * (NQ * NLAY) + i;
    int4 m = meta[node];
    float di = __int_as_float(m.z);
    int off = m.x, deg = m.y;
    float s2 = di * di;
    float4 v = ((const float4*)(hw + (size_t)node * FEAT))[sl];
    float ax = v.x * s2, ay = v.y * s2, az = v.z * s2, aw = v.w * s2;
    int dc = max(deg - 1, 0);
    for (int e = 0; e < deg; e += 4) {
        int2 e0 = csre[off + min(e,     dc)];
        int2 e1 = csre[off + min(e + 1, dc)];
        int2 e2 = csre[off + min(e + 2, dc)];
        int2 e3 = csre[off + min(e + 3, dc)];
        float4 u0 = ((const float4*)(hw + (size_t)e0.x * FEAT))[sl];
        float4 u1 = ((const float4*)(hw + (size_t)e1.x * FEAT))[sl];
        float4 u2 = ((const float4*)(hw + (size_t)e2.x * FEAT))[sl];
        float4 u3 = ((const float4*)(hw + (size_t)e3.x * FEAT))[sl];
        float w0 = (e     < deg) ? __int_as_float(e0.y) * di : 0.f;
        float w1 = (e + 1 < deg) ? __int_as_float(e1.y) * di : 0.f;
        float w2 = (e + 2 < deg) ? __int_as_float(e2.y) * di : 0.f;
        float w3 = (e + 3 < deg) ? __int_as_float(e3.y) * di : 0.f;
        ax += u0.x * w0 + u1.x * w1 + u2.x * w2 + u3.x * w3;
        ay += u0.y * w0 + u1.y * w1 + u2.y * w2 + u3.y * w3;
        az += u0.z * w0 + u1.z * w1 + u2.z * w2 + u3.z * w3;
        aw += u0.w * w0 + u1.w * w1 + u2.w * w2 + u3.w * w3;
    }
    float4 bv = ((const float4*)gbias)[sl];
    float4 ho = ((const float4*)(h + (size_t)node * FEAT))[sl];
    ((float4*)(hq + (size_t)q * FEAT))[sl] =
        make_float4(ax + bv.x + ho.x, ay + bv.y + ho.y, az + bv.z + ho.z, aw + bv.w + ho.w);
}

// ---------------- last layer + symmetrize, one block per batch ----------------
__global__ void k_lastsym(const float* __restrict__ X4, const float* __restrict__ mw5,
                          const float* __restrict__ mb5, float* __restrict__ out) {
    __shared__ float w[64];
    __shared__ float sm[NQ * NQ];
    int t = threadIdx.x;
    if (t < 64) w[t] = mw5[t];
    __syncthreads();
    int b = blockIdx.x;
    for (int p = t; p < NQ * NQ; p += 256) {
        const float4* row = (const float4*)(X4 + (size_t)(b * NQ * NQ + p) * 64);
        float s = 0.f;
#pragma unroll
        for (int k4 = 0; k4 < 16; k4++) {
            float4 v = row[k4];
            s += v.x * w[k4 * 4] + v.y * w[k4 * 4 + 1] + v.z * w[k4 * 4 + 2] + v.w * w[k4 * 4 + 3];
        }
        sm[p] = s + mb5[0];
    }
    __syncthreads();
    for (int r = t; r < NQ * NQ; r += 256) {
        int i = r / NQ, j = r % NQ;
        out[(size_t)b * NQ * NQ + r] = 0.5f * (sm[r] + sm[j * NQ + i]);
    }
}

extern "C" void kernel_launch(void* const* d_in, const int* in_sizes, int n_in,
                              void* d_out, int out_size, void* d_ws, size_t ws_size,
                              hipStream_t stream) {
    const int* x = (const int*)d_in[0];
    const int* ei = (const int*)d_in[1];
    const int* e_src = ei;
    const int* e_dst = ei + NE;
    const float* emb = (const float*)d_in[2];
    const float* gw = (const float*)d_in[3];   // [5,128,128]
    const float* gb = (const float*)d_in[4];   // [5,128]
    const float* mw0 = (const float*)d_in[5];
    const float* mb0 = (const float*)d_in[6];
    const float* mw1 = (const float*)d_in[7];
    const float* mb1 = (const float*)d_in[8];
    const float* mw2 = (const float*)d_in[9];
    const float* mb2 = (const float*)d_in[10];
    const float* mw3 = (const float*)d_in[11];
    const float* mb3 = (const float*)d_in[12];
    const float* mw4 = (const float*)d_in[13];
    const float* mb4 = (const float*)d_in[14];
    const float* mw5 = (const float*)d_in[15];
    const float* mb5 = (const float*)d_in[16];
    float* out = (float*)d_out;

    float* wsf = (float*)d_ws;
    size_t o = 0;
    const size_t HSZ = (size_t)NN * FEAT;             // 16,711,680
    float* hA = wsf + o; o += HSZ;
    float* hw = wsf + o; o += HSZ;
    float* hB = wsf + o; o += HSZ;
    // zero-memset region: cnt, fill, flag1, flag2 (contiguous)
    int* cnt   = (int*)(wsf + o); o += NN;
    int* fill  = (int*)(wsf + o); o += NN;
    int* flag1 = (int*)(wsf + o); o += NN;
    int* flag2 = (int*)(wsf + o); o += NN;
    // 0xFF-memset region: list1, list2 (contiguous, sentinel -1)
    int* list1 = (int*)(wsf + o); o += NN;
    int* list2 = (int*)(wsf + o); o += NN;
    int* offs = (int*)(wsf + o); o += NN;
    float* dinv = wsf + o; o += NN;
    int4* meta = (int4*)(wsf + o); o += 4 * (size_t)NN;
    int2* csre = (int2*)(wsf + o); o += 2 * (size_t)(NE + 8);  // +8 slop for deg-0 clamp
    int* part  = (int*)(wsf + o); o += 512;
    int* pscan = (int*)(wsf + o); o += 512;
    float* hq = wsf + o; o += (size_t)BATCH * NQ * FEAT;     // 327,680
    float* Abuf = wsf + o; o += (size_t)BATCH * NQ * 256;    // 655,360
    float* Bbuf = wsf + o; o += (size_t)BATCH * NQ * 256;    // 655,360
    _Float16* bt_hi = (_Float16*)(wsf + o); o += (TS_TOTAL + 2) / 2;
    _Float16* bt_lo = (_Float16*)(wsf + o); o += (TS_TOTAL + 2) / 2;
    // pair-phase aliases (buffers dead by then; hA holds h4 until aggq, hB/hw free after)
    float* X1 = hw;                         // 51200*128 (hw dead after aggq)
    float* X2 = hw + (size_t)NPAIR * 128;   // 51200*128
    float* X3 = hB;                         // 51200*64
    float* X4 = hB + (size_t)NPAIR * 64;    // 51200*64

    // --- weight transpose+split+pack ---
    k_tsplit_all<<<TS_TOTAL / 256, 256, 0, stream>>>(gw, mw0, mw1, mw2, mw3, mw4, bt_hi, bt_lo);

    // --- CSR build (deterministic scan chain) ---
    hipMemsetAsync(cnt, 0, 4 * NN * sizeof(int), stream);     // cnt+fill+flag1+flag2
    hipMemsetAsync(list1, 0xFF, 2 * NN * sizeof(int), stream); // list sentinels (-1)
    hipMemsetAsync(csre + NE, 0, 8 * sizeof(int2), stream);   // slop: node 0, weight 0
    k_count<<<NE / 256, 256, 0, stream>>>(e_dst, cnt);
    k_partial<<<NB, 256, 0, stream>>>(cnt, part);
    k_scanpart<<<1, 512, 0, stream>>>(part, pscan, NB);
    k_offsets<<<NB, 256, 0, stream>>>(cnt, pscan, x, offs, dinv, meta);
    k_fill<<<NE / 256, 256, 0, stream>>>(e_src, e_dst, offs, fill, dinv, csre);

    // --- dependency-cone lists S1, S2 (sentinel-padded, ascending order) ---
    k_markS1<<<(BATCH * NQ + 255) / 256, 256, 0, stream>>>(meta, csre, flag1);
    k_partial<<<NB, 256, 0, stream>>>(flag1, part);
    k_scanpart<<<1, 512, 0, stream>>>(part, pscan, NB);
    k_emit<<<NB, 256, 0, stream>>>(flag1, pscan, list1);
    k_markS2<<<NB, 256, 0, stream>>>(meta, csre, list1, flag2);
    k_partial<<<NB, 256, 0, stream>>>(flag2, part);
    k_scanpart<<<1, 512, 0, stream>>>(part, pscan, NB);
    k_emit<<<NB, 256, 0, stream>>>(flag2, pscan, list2);

    // --- layer 0: gemm gathers A-rows straight from emb via x (h0 never materialized) ---
    hgemm<8, false, false, false, false, true><<<dim3(NN / 128, 1), 256, 0, stream>>>(
        emb, nullptr, nullptr, bt_hi + OFF_GCN, bt_lo + OFF_GCN,
        nullptr, hw, nullptr, FEAT, FEAT, x);
    // agg0 full: residual rows from emb[meta.w] -> h1 in hB
    k_agg<<<NN / 16, 256, 0, stream>>>(hw, nullptr, meta, csre, nullptr, gb + 0 * FEAT, hB, emb);

    // --- layer 1: full gemm + full agg -> h2 in hA ---
    hgemm<8, false, false, false, false, false><<<dim3(NN / 128, 1), 256, 0, stream>>>(
        hB, nullptr, nullptr, bt_hi + OFF_GCN + 1 * 16384, bt_lo + OFF_GCN + 1 * 16384,
        nullptr, hw, nullptr, FEAT, FEAT, nullptr);
    k_agg<<<NN / 16, 256, 0, stream>>>(hw, hB, meta, csre, nullptr, gb + 1 * FEAT, hA, nullptr);

    // --- layer 2: full gemm + agg@S2 -> h3 (S2 rows) in hB ---
    // (non-S2 rows of hB stale — never read: gemm3 output is only consumed on S2 rows)
    hgemm<8, false, false, false, false, false><<<dim3(NN / 128, 1), 256, 0, stream>>>(
        hA, nullptr, nullptr, bt_hi + OFF_GCN + 2 * 16384, bt_lo + OFF_GCN + 2 * 16384,
        nullptr, hw, nullptr, FEAT, FEAT, nullptr);
    k_agg<<<NN / 16, 256, 0, stream>>>(hw, hA, meta, csre, list2, gb + 2 * FEAT, hB, nullptr);

    // --- layer 3: full gemm + agg@S1 -> h4 (S1 rows) in hA ---
    hgemm<8, false, false, false, false, false><<<dim3(NN / 128, 1), 256, 0, stream>>>(
        hB, nullptr, nullptr, bt_hi + OFF_GCN + 3 * 16384, bt_lo + OFF_GCN + 3 * 16384,
        nullptr, hw, nullptr, FEAT, FEAT, nullptr);
    k_agg<<<NN / 16, 256, 0, stream>>>(hw, hB, meta, csre, list1, gb + 3 * FEAT, hA, nullptr);

    // --- layer 4: full gemm + selective agg@S0 -> hq ---
    hgemm<8, false, false, false, false, false><<<dim3(NN / 128, 1), 256, 0, stream>>>(
        hA, nullptr, nullptr, bt_hi + OFF_GCN + 4 * 16384, bt_lo + OFF_GCN + 4 * 16384,
        nullptr, hw, nullptr, FEAT, FEAT, nullptr);
    k_aggq<<<(BATCH * NQ) / 8, 256, 0, stream>>>(hw, hA, meta, csre,
                                                 gb + 4 * (size_t)FEAT, hq);

    // --- pair MLP ---
    // combined P0: Abuf = hq@mw0_top + mb0 ; Bbuf = hq@mw0_bot   (M=2560, K=128, N=512)
    hgemm<8, false, false, true, false, false><<<dim3(20, 4), 256, 0, stream>>>(
        hq, nullptr, nullptr, bt_hi + OFF_P0, bt_lo + OFF_P0, mb0, Abuf, Bbuf, 512, 128, nullptr);
    // L1 fused pair0: A[p,:] = lrelu(Abuf[b,i,:] + Bbuf[b,j,:]) ; [51200,256]@[256,128]
    hgemm<8, true, true, false, true, false><<<dim3(NPAIR / 128, 1), 256, 0, stream>>>(
        nullptr, Abuf, Bbuf, bt_hi + OFF_M1, bt_lo + OFF_M1, mb1, X1, nullptr, 128, 256, nullptr);
    // L2: [51200,128] @ [128,128]
    hgemm<8, true, true, false, false, false><<<dim3(NPAIR / 128, 1), 256, 0, stream>>>(
        X1, nullptr, nullptr, bt_hi + OFF_M2, bt_lo + OFF_M2, mb2, X2, nullptr, 128, 128, nullptr);
    // L3: [51200,128] @ [128,64]
    hgemm<4, true, true, false, false, false><<<dim3(NPAIR / 128, 1), 256, 0, stream>>>(
        X2, nullptr, nullptr, bt_hi + OFF_M3, bt_lo + OFF_M3, mb3, X3, nullptr, 64, 128, nullptr);
    // L4: [51200,64] @ [64,64]
    hgemm<4, true, true, false, false, false><<<dim3(NPAIR / 128, 1), 256, 0, stream>>>(
        X3, nullptr, nullptr, bt_hi + OFF_M4, bt_lo + OFF_M4, mb4, X4, nullptr, 64, 64, nullptr);
    // L5 + symmetrize
    k_lastsym<<<BATCH, 256, 0, stream>>>(X4, mw5, mb5, out);
}

// Round 11
// 568.282 us; speedup vs baseline: 1.2083x; 1.0421x over previous
//
#include <hip/hip_runtime.h>
#include <hip/hip_bf16.h>

#define NQ 20
#define NLAY 51            // N_LAYER+1
#define FEAT 128
#define BATCH 128
#define NN (BATCH * NQ * NLAY)   // 130560
#define NE 524288
#define NPAIR (BATCH * NQ * NQ)  // 51200
#define NB (NN / 256)            // 510

typedef _Float16 half8 __attribute__((ext_vector_type(8)));
typedef float floatx4 __attribute__((ext_vector_type(4)));

__device__ __forceinline__ float lrelu(float v) { return v >= 0.f ? v : 0.01f * v; }

// ---------------- CSR build ----------------
__global__ void k_count(const int* __restrict__ dst, int* __restrict__ cnt) {
    int e = blockIdx.x * 256 + threadIdx.x;
    atomicAdd(&cnt[dst[e]], 1);
}

__global__ void k_partial(const int* __restrict__ cnt, int* __restrict__ part) {
    __shared__ int sm[256];
    int t = threadIdx.x;
    sm[t] = cnt[blockIdx.x * 256 + t];
    __syncthreads();
    for (int s = 128; s > 0; s >>= 1) {
        if (t < s) sm[t] += sm[t + s];
        __syncthreads();
    }
    if (t == 0) part[blockIdx.x] = sm[0];
}

__global__ void k_scanpart(const int* __restrict__ part, int* __restrict__ pscan, int nb) {
    __shared__ int sm[512];
    int t = threadIdx.x;
    int v = (t < nb) ? part[t] : 0;
    sm[t] = v;
    __syncthreads();
    for (int s = 1; s < 512; s <<= 1) {
        int add = (t >= s) ? sm[t - s] : 0;
        __syncthreads();
        sm[t] += add;
        __syncthreads();
    }
    if (t < nb) pscan[t] = sm[t] - v;   // exclusive
}

// offsets + dinv + packed meta {off, deg, dinv_bits, x[node]}
__global__ void k_offsets(const int* __restrict__ cnt, const int* __restrict__ pscan,
                          const int* __restrict__ x,
                          int* __restrict__ offs, float* __restrict__ dinv,
                          int4* __restrict__ meta) {
    __shared__ int sm[256];
    int t = threadIdx.x, g = blockIdx.x * 256 + t;
    int v = cnt[g];
    sm[t] = v;
    __syncthreads();
    for (int s = 1; s < 256; s <<= 1) {
        int add = (t >= s) ? sm[t - s] : 0;
        __syncthreads();
        sm[t] += add;
        __syncthreads();
    }
    int off = pscan[blockIdx.x] + sm[t] - v;
    float di = rsqrtf((float)(v + 1));  // +1 self loop
    offs[g] = off;
    dinv[g] = di;
    meta[g] = make_int4(off, v, __float_as_int(di), x[g]);
}

// fill packed edges {src, dinv[src]_bits}
__global__ void k_fill(const int* __restrict__ src, const int* __restrict__ dst,
                       const int* __restrict__ offs, int* __restrict__ fill,
                       const float* __restrict__ dinv, int2* __restrict__ csre) {
    int e = blockIdx.x * 256 + threadIdx.x;
    int d = dst[e];
    int s = src[e];
    int pos = offs[d] + atomicAdd(&fill[d], 1);
    csre[pos] = make_int2(s, __float_as_int(dinv[s]));
}

// ---------------- dependency-cone sets (replay-safe: sentinel-padded lists) ----------------
__global__ void k_markS1(const int4* __restrict__ meta, const int2* __restrict__ csre,
                         int* __restrict__ flag) {
    int q = blockIdx.x * 256 + threadIdx.x;   // 0..2559
    if (q >= BATCH * NQ) return;
    int node = (q / NQ) * (NQ * NLAY) + (q % NQ);
    flag[node] = 1;
    int4 m = meta[node];
    for (int e = 0; e < m.y; e++) flag[csre[m.x + e].x] = 1;   // benign races (all write 1)
}

__global__ void k_markS2(const int4* __restrict__ meta, const int2* __restrict__ csre,
                         const int* __restrict__ list1, int* __restrict__ flag) {
    int i = blockIdx.x * 256 + threadIdx.x;
    int node = list1[i];
    if ((unsigned)node >= (unsigned)NN) return;   // sentinel
    flag[node] = 1;
    int4 m = meta[node];
    for (int e = 0; e < m.y; e++) flag[csre[m.x + e].x] = 1;
}

// scan-ordered compaction: members land in slots [0,|S|) in ASCENDING node order
__global__ void k_emit(const int* __restrict__ flag, const int* __restrict__ pscan,
                       int* __restrict__ list) {
    __shared__ int sm[256];
    int t = threadIdx.x, g = blockIdx.x * 256 + t;
    int v = flag[g];
    sm[t] = v;
    __syncthreads();
    for (int s = 1; s < 256; s <<= 1) {
        int add = (t >= s) ? sm[t - s] : 0;
        __syncthreads();
        sm[t] += add;
        __syncthreads();
    }
    if (v) list[pscan[blockIdx.x] + sm[t] - 1] = g;
}

// ---------------- weight transpose + fp16 hi/lo split, PACKED MFMA-fragment layout -------
#define OFF_GCN 0                 // 5 x K=128 N=128
#define OFF_P0  81920             // combined mw0: K=128 N=512
#define OFF_M1  147456            // mw1: K=256 N=128
#define OFF_M2  180224            // mw2: K=128 N=128
#define OFF_M3  196608            // mw3: K=128 N=64
#define OFF_M4  204800            // mw4: K=64  N=64
#define TS_TOTAL 208896

__global__ void k_tsplit_all(const float* __restrict__ gw, const float* __restrict__ mw0,
                             const float* __restrict__ mw1, const float* __restrict__ mw2,
                             const float* __restrict__ mw3, const float* __restrict__ mw4,
                             _Float16* __restrict__ hi, _Float16* __restrict__ lo) {
    int idx = blockIdx.x * 256 + threadIdx.x;
    const float* src;
    int K, N, rel;
    bool p0 = false;
    if (idx < OFF_P0) {
        int L = (idx - OFF_GCN) >> 14; rel = (idx - OFF_GCN) & 16383;
        src = gw + L * 16384; K = 128; N = 128;
    } else if (idx < OFF_M1) {
        rel = idx - OFF_P0; src = mw0; K = 128; N = 512; p0 = true;
    } else if (idx < OFF_M2) {
        rel = idx - OFF_M1;  src = mw1; K = 256; N = 128;
    } else if (idx < OFF_M3) {
        rel = idx - OFF_M2;  src = mw2; K = 128; N = 128;
    } else if (idx < OFF_M4) {
        rel = idx - OFF_M3;  src = mw3; K = 128; N = 64;
    } else {
        rel = idx - OFF_M4;  src = mw4; K = 64;  N = 64;
    }
    int kblks = K >> 5;
    int j = rel & 7;
    int lane = (rel >> 3) & 63;
    int t2 = rel >> 9;
    int kblk = t2 % kblks;
    int ntile = t2 / kblks;
    int col = ntile * 16 + (lane & 15);
    int k = kblk * 32 + ((lane >> 4) << 3) + j;
    float f;
    if (p0) {
        f = (col < 256) ? src[k * 256 + col] : src[(k + 128) * 256 + (col - 256)];
    } else {
        f = src[k * N + col];
    }
    _Float16 h = (_Float16)f;
    hi[idx] = h;
    lo[idx] = (_Float16)(f - (float)h);
}

// ---------------- split-fp16 MFMA GEMM ----------------
// B pre-packed in fragment order (hi/lo). 3-product Markidis split, fp32 accumulate.
// GATHA: A-rows indirected through gmap (embedding-gather fusion).
// LISTM: M-rows indirected through sentinel-padded ascending list (cone slicing);
//        whole block skips if its first slot is sentinel; boundary rows clamped,
//        stores suppressed. No device-count reads.
template <int NT_N, bool LEAKY, bool BIAS, bool P0SPLIT, bool FUSEA, bool GATHA, bool LISTM>
__launch_bounds__(256, 2)
__global__ void hgemm(const float* __restrict__ A,
                      const float* __restrict__ FA, const float* __restrict__ FB,
                      const _Float16* __restrict__ Bh, const _Float16* __restrict__ Bl,
                      const float* __restrict__ bias,
                      float* __restrict__ C, float* __restrict__ C2,
                      int N, int K, const int* __restrict__ gmap,
                      const int* __restrict__ listm) {
    if (LISTM) {
        if ((unsigned)listm[blockIdx.x * 128] >= (unsigned)NN) return;  // all-sentinel block
    }
    const int KB = K >> 5;
    const int lane = threadIdx.x & 63;
    const int wid = threadIdx.x >> 6;
    const int lm = lane & 15, lq = lane >> 4;
    const int m0 = blockIdx.x * 128 + wid * 32;
    const int n0t = blockIdx.y * NT_N;

    const float* arow[2];
    const float* brow[2];
#pragma unroll
    for (int mt = 0; mt < 2; mt++) {
        int row = m0 + mt * 16 + lm;
        if (FUSEA) {
            int b = row / (NQ * NQ);
            int rr = row - b * (NQ * NQ);
            int i = rr / NQ;
            int j = rr - i * NQ;
            arow[mt] = FA + (size_t)(b * NQ + i) * 256;
            brow[mt] = FB + (size_t)(b * NQ + j) * 256;
        } else if (GATHA) {
            arow[mt] = A + (size_t)gmap[row] * K;
        } else if (LISTM) {
            int lr = listm[row];
            lr = ((unsigned)lr < (unsigned)NN) ? lr : 0;
            arow[mt] = A + (size_t)lr * K;
        } else {
            arow[mt] = A + (size_t)row * K;
        }
    }

    floatx4 acc[2][NT_N];
#pragma unroll
    for (int mt = 0; mt < 2; mt++)
#pragma unroll
        for (int nt = 0; nt < NT_N; nt++) acc[mt][nt] = (floatx4)0.f;

    for (int kb = 0; kb < KB; kb++) {
        const int k0 = kb * 32 + lq * 8;
        half8 ahi[2], alo[2];
#pragma unroll
        for (int mt = 0; mt < 2; mt++) {
            floatx4 av0, av1;
            if (FUSEA) {
                floatx4 fa0 = *(const floatx4*)(arow[mt] + k0);
                floatx4 fa1 = *(const floatx4*)(arow[mt] + k0 + 4);
                floatx4 fb0 = *(const floatx4*)(brow[mt] + k0);
                floatx4 fb1 = *(const floatx4*)(brow[mt] + k0 + 4);
#pragma unroll
                for (int q = 0; q < 4; q++) {
                    av0[q] = lrelu(fa0[q] + fb0[q]);
                    av1[q] = lrelu(fa1[q] + fb1[q]);
                }
            } else {
                av0 = *(const floatx4*)(arow[mt] + k0);
                av1 = *(const floatx4*)(arow[mt] + k0 + 4);
            }
#pragma unroll
            for (int q = 0; q < 4; q++) {
                _Float16 h0 = (_Float16)av0[q];
                ahi[mt][q] = h0;
                alo[mt][q] = (_Float16)(av0[q] - (float)h0);
                _Float16 h1 = (_Float16)av1[q];
                ahi[mt][4 + q] = h1;
                alo[mt][4 + q] = (_Float16)(av1[q] - (float)h1);
            }
        }
#pragma unroll
        for (int nt = 0; nt < NT_N; nt++) {
            size_t boff = (((size_t)(n0t + nt) * KB + kb) * 64 + lane) * 8;
            half8 bhi = *(const half8*)(Bh + boff);
            half8 blo = *(const half8*)(Bl + boff);
#pragma unroll
            for (int mt = 0; mt < 2; mt++) {
                acc[mt][nt] = __builtin_amdgcn_mfma_f32_16x16x32_f16(ahi[mt], bhi, acc[mt][nt], 0, 0, 0);
                acc[mt][nt] = __builtin_amdgcn_mfma_f32_16x16x32_f16(ahi[mt], blo, acc[mt][nt], 0, 0, 0);
                acc[mt][nt] = __builtin_amdgcn_mfma_f32_16x16x32_f16(alo[mt], bhi, acc[mt][nt], 0, 0, 0);
            }
        }
    }

    // store-row mapping (C/D layout: col=lane&15, row=(lane>>4)*4+reg)
    int strow[2][4];
    bool svalid[2][4];
#pragma unroll
    for (int mt = 0; mt < 2; mt++)
#pragma unroll
        for (int r = 0; r < 4; r++) {
            int mlog = m0 + mt * 16 + lq * 4 + r;
            if (LISTM) {
                int sr = listm[mlog];
                svalid[mt][r] = (unsigned)sr < (unsigned)NN;
                strow[mt][r] = svalid[mt][r] ? sr : 0;
            } else {
                svalid[mt][r] = true;
                strow[mt][r] = mlog;
            }
        }

#pragma unroll
    for (int nt = 0; nt < NT_N; nt++) {
        int col = (n0t + nt) * 16 + lm;
        float bv = (BIAS || P0SPLIT) ? bias[col < 256 ? col : 0] : 0.f;
#pragma unroll
        for (int mt = 0; mt < 2; mt++) {
#pragma unroll
            for (int r = 0; r < 4; r++) {
                if (!svalid[mt][r]) continue;
                int row = strow[mt][r];
                float val = acc[mt][nt][r];
                if (P0SPLIT) {
                    if (col < 256) C[(size_t)row * 256 + col] = val + bv;
                    else C2[(size_t)row * 256 + col - 256] = val;
                } else {
                    if (BIAS) val += bv;
                    if (LEAKY) val = lrelu(val);
                    C[(size_t)row * N + col] = val;
                }
            }
        }
    }
}

// ---------------- GCN aggregation + bias + leaky + residual (ping-pong) ----------------
// Templated on LIST: false -> sequential node ids (R7-proven code path, no branch);
// true -> sentinel-padded ascending list, ids clamped, stores suppressed.
// embt != null: residual rows come from embt[meta.w] (layer 0, h0 never materialized).
template <bool LIST>
__global__ void k_agg(const float* __restrict__ hw, const float* __restrict__ hold,
                      const int4* __restrict__ meta, const int2* __restrict__ csre,
                      const int* __restrict__ list,
                      const float* __restrict__ bias, float* __restrict__ hnew,
                      const float* __restrict__ embt) {
    int tid = threadIdx.x;
    int sl = tid & 31;
    int p = blockIdx.x * 8 + (tid >> 5);
    int n0, n1;
    bool val0 = true, val1 = true;
    if (LIST) {
        n0 = list[p * 2];
        n1 = list[p * 2 + 1];
        val0 = (unsigned)n0 < (unsigned)NN;
        val1 = (unsigned)n1 < (unsigned)NN;
        n0 = val0 ? n0 : 0;
        n1 = val1 ? n1 : 0;
    } else {
        n0 = p * 2;
        n1 = n0 + 1;
    }
    int4 m0 = meta[n0], m1 = meta[n1];
    float di0 = __int_as_float(m0.z), di1 = __int_as_float(m1.z);
    int off0 = m0.x, deg0 = LIST ? (val0 ? m0.y : 0) : m0.y;
    int off1 = m1.x, deg1 = LIST ? (val1 ? m1.y : 0) : m1.y;
    float4 v0 = ((const float4*)(hw + (size_t)n0 * FEAT))[sl];
    float4 v1 = ((const float4*)(hw + (size_t)n1 * FEAT))[sl];
    float4 ho0, ho1;
    if (embt) {
        ho0 = ((const float4*)(embt + (size_t)m0.w * FEAT))[sl];
        ho1 = ((const float4*)(embt + (size_t)m1.w * FEAT))[sl];
    } else {
        ho0 = ((const float4*)(hold + (size_t)n0 * FEAT))[sl];
        ho1 = ((const float4*)(hold + (size_t)n1 * FEAT))[sl];
    }
    float s20 = di0 * di0, s21 = di1 * di1;
    float a0x = v0.x * s20, a0y = v0.y * s20, a0z = v0.z * s20, a0w = v0.w * s20;
    float a1x = v1.x * s21, a1y = v1.y * s21, a1z = v1.z * s21, a1w = v1.w * s21;
    int d0c = max(deg0 - 1, 0), d1c = max(deg1 - 1, 0);
    int dm = max(deg0, deg1);
    for (int e = 0; e < dm; e += 4) {
        int2 e00 = csre[off0 + min(e,     d0c)];
        int2 e01 = csre[off0 + min(e + 1, d0c)];
        int2 e02 = csre[off0 + min(e + 2, d0c)];
        int2 e03 = csre[off0 + min(e + 3, d0c)];
        int2 e10 = csre[off1 + min(e,     d1c)];
        int2 e11 = csre[off1 + min(e + 1, d1c)];
        int2 e12 = csre[off1 + min(e + 2, d1c)];
        int2 e13 = csre[off1 + min(e + 3, d1c)];
        float4 u00 = ((const float4*)(hw + (size_t)e00.x * FEAT))[sl];
        float4 u01 = ((const float4*)(hw + (size_t)e01.x * FEAT))[sl];
        float4 u02 = ((const float4*)(hw + (size_t)e02.x * FEAT))[sl];
        float4 u03 = ((const float4*)(hw + (size_t)e03.x * FEAT))[sl];
        float4 u10 = ((const float4*)(hw + (size_t)e10.x * FEAT))[sl];
        float4 u11 = ((const float4*)(hw + (size_t)e11.x * FEAT))[sl];
        float4 u12 = ((const float4*)(hw + (size_t)e12.x * FEAT))[sl];
        float4 u13 = ((const float4*)(hw + (size_t)e13.x * FEAT))[sl];
        float w00 = (e     < deg0) ? __int_as_float(e00.y) * di0 : 0.f;
        float w01 = (e + 1 < deg0) ? __int_as_float(e01.y) * di0 : 0.f;
        float w02 = (e + 2 < deg0) ? __int_as_float(e02.y) * di0 : 0.f;
        float w03 = (e + 3 < deg0) ? __int_as_float(e03.y) * di0 : 0.f;
        float w10 = (e     < deg1) ? __int_as_float(e10.y) * di1 : 0.f;
        float w11 = (e + 1 < deg1) ? __int_as_float(e11.y) * di1 : 0.f;
        float w12 = (e + 2 < deg1) ? __int_as_float(e12.y) * di1 : 0.f;
        float w13 = (e + 3 < deg1) ? __int_as_float(e13.y) * di1 : 0.f;
        a0x += u00.x * w00 + u01.x * w01 + u02.x * w02 + u03.x * w03;
        a0y += u00.y * w00 + u01.y * w01 + u02.y * w02 + u03.y * w03;
        a0z += u00.z * w00 + u01.z * w01 + u02.z * w02 + u03.z * w03;
        a0w += u00.w * w00 + u01.w * w01 + u02.w * w02 + u03.w * w03;
        a1x += u10.x * w10 + u11.x * w11 + u12.x * w12 + u13.x * w13;
        a1y += u10.y * w10 + u11.y * w11 + u12.y * w12 + u13.y * w13;
        a1z += u10.z * w10 + u11.z * w11 + u12.z * w12 + u13.z * w13;
        a1w += u10.w * w10 + u11.w * w11 + u12.w * w12 + u13.w * w13;
    }
    float4 bv = ((const float4*)bias)[sl];
    float4 r0, r1;
    r0.x = lrelu(a0x + bv.x) + ho0.x;
    r0.y = lrelu(a0y + bv.y) + ho0.y;
    r0.z = lrelu(a0z + bv.z) + ho0.z;
    r0.w = lrelu(a0w + bv.w) + ho0.w;
    r1.x = lrelu(a1x + bv.x) + ho1.x;
    r1.y = lrelu(a1y + bv.y) + ho1.y;
    r1.z = lrelu(a1z + bv.z) + ho1.z;
    r1.w = lrelu(a1w + bv.w) + ho1.w;
    if (!LIST || val0) ((float4*)(hnew + (size_t)n0 * FEAT))[sl] = r0;
    if (!LIST || val1) ((float4*)(hnew + (size_t)n1 * FEAT))[sl] = r1;
}

// ---------------- selective final agg (layer 4): S0 rows only -> hq, no leaky ----------------
__global__ void k_aggq(const float* __restrict__ hw, const float* __restrict__ h,
                       const int4* __restrict__ meta, const int2* __restrict__ csre,
                       const float* __restrict__ gbias, float* __restrict__ hq) {
    int tid = threadIdx.x;
    int sl = tid & 31;
    int q = blockIdx.x * 8 + (tid >> 5);   // 0..2559
    int b = q / NQ, i = q - b * NQ;
    int node = b * (NQ * NLAY) + i;
    int4 m = meta[node];
    float di = __int_as_float(m.z);
    int off = m.x, deg = m.y;
    float s2 = di * di;
    float4 v = ((const float4*)(hw + (size_t)node * FEAT))[sl];
    float ax = v.x * s2, ay = v.y * s2, az = v.z * s2, aw = v.w * s2;
    int dc = max(deg - 1, 0);
    for (int e = 0; e < deg; e += 4) {
        int2 e0 = csre[off + min(e,     dc)];
        int2 e1 = csre[off + min(e + 1, dc)];
        int2 e2 = csre[off + min(e + 2, dc)];
        int2 e3 = csre[off + min(e + 3, dc)];
        float4 u0 = ((const float4*)(hw + (size_t)e0.x * FEAT))[sl];
        float4 u1 = ((const float4*)(hw + (size_t)e1.x * FEAT))[sl];
        float4 u2 = ((const float4*)(hw + (size_t)e2.x * FEAT))[sl];
        float4 u3 = ((const float4*)(hw + (size_t)e3.x * FEAT))[sl];
        float w0 = (e     < deg) ? __int_as_float(e0.y) * di : 0.f;
        float w1 = (e + 1 < deg) ? __int_as_float(e1.y) * di : 0.f;
        float w2 = (e + 2 < deg) ? __int_as_float(e2.y) * di : 0.f;
        float w3 = (e + 3 < deg) ? __int_as_float(e3.y) * di : 0.f;
        ax += u0.x * w0 + u1.x * w1 + u2.x * w2 + u3.x * w3;
        ay += u0.y * w0 + u1.y * w1 + u2.y * w2 + u3.y * w3;
        az += u0.z * w0 + u1.z * w1 + u2.z * w2 + u3.z * w3;
        aw += u0.w * w0 + u1.w * w1 + u2.w * w2 + u3.w * w3;
    }
    float4 bv = ((const float4*)gbias)[sl];
    float4 ho = ((const float4*)(h + (size_t)node * FEAT))[sl];
    ((float4*)(hq + (size_t)q * FEAT))[sl] =
        make_float4(ax + bv.x + ho.x, ay + bv.y + ho.y, az + bv.z + ho.z, aw + bv.w + ho.w);
}

// ---------------- last layer + symmetrize, one block per batch ----------------
__global__ void k_lastsym(const float* __restrict__ X4, const float* __restrict__ mw5,
                          const float* __restrict__ mb5, float* __restrict__ out) {
    __shared__ float w[64];
    __shared__ float sm[NQ * NQ];
    int t = threadIdx.x;
    if (t < 64) w[t] = mw5[t];
    __syncthreads();
    int b = blockIdx.x;
    for (int p = t; p < NQ * NQ; p += 256) {
        const float4* row = (const float4*)(X4 + (size_t)(b * NQ * NQ + p) * 64);
        float s = 0.f;
#pragma unroll
        for (int k4 = 0; k4 < 16; k4++) {
            float4 v = row[k4];
            s += v.x * w[k4 * 4] + v.y * w[k4 * 4 + 1] + v.z * w[k4 * 4 + 2] + v.w * w[k4 * 4 + 3];
        }
        sm[p] = s + mb5[0];
    }
    __syncthreads();
    for (int r = t; r < NQ * NQ; r += 256) {
        int i = r / NQ, j = r % NQ;
        out[(size_t)b * NQ * NQ + r] = 0.5f * (sm[r] + sm[j * NQ + i]);
    }
}

extern "C" void kernel_launch(void* const* d_in, const int* in_sizes, int n_in,
                              void* d_out, int out_size, void* d_ws, size_t ws_size,
                              hipStream_t stream) {
    const int* x = (const int*)d_in[0];
    const int* ei = (const int*)d_in[1];
    const int* e_src = ei;
    const int* e_dst = ei + NE;
    const float* emb = (const float*)d_in[2];
    const float* gw = (const float*)d_in[3];   // [5,128,128]
    const float* gb = (const float*)d_in[4];   // [5,128]
    const float* mw0 = (const float*)d_in[5];
    const float* mb0 = (const float*)d_in[6];
    const float* mw1 = (const float*)d_in[7];
    const float* mb1 = (const float*)d_in[8];
    const float* mw2 = (const float*)d_in[9];
    const float* mb2 = (const float*)d_in[10];
    const float* mw3 = (const float*)d_in[11];
    const float* mb3 = (const float*)d_in[12];
    const float* mw4 = (const float*)d_in[13];
    const float* mb4 = (const float*)d_in[14];
    const float* mw5 = (const float*)d_in[15];
    const float* mb5 = (const float*)d_in[16];
    float* out = (float*)d_out;

    float* wsf = (float*)d_ws;
    size_t o = 0;
    const size_t HSZ = (size_t)NN * FEAT;             // 16,711,680
    float* hA = wsf + o; o += HSZ;
    float* hw = wsf + o; o += HSZ;
    float* hB = wsf + o; o += HSZ;
    // zero-memset region: cnt, fill, flag1, flag2 (contiguous)
    int* cnt   = (int*)(wsf + o); o += NN;
    int* fill  = (int*)(wsf + o); o += NN;
    int* flag1 = (int*)(wsf + o); o += NN;
    int* flag2 = (int*)(wsf + o); o += NN;
    // 0xFF-memset region: list1, list2 (contiguous, sentinel -1)
    int* list1 = (int*)(wsf + o); o += NN;
    int* list2 = (int*)(wsf + o); o += NN;
    int* offs = (int*)(wsf + o); o += NN;
    float* dinv = wsf + o; o += NN;
    int4* meta = (int4*)(wsf + o); o += 4 * (size_t)NN;
    int2* csre = (int2*)(wsf + o); o += 2 * (size_t)(NE + 8);  // +8 slop for deg-0 clamp
    int* part  = (int*)(wsf + o); o += 512;
    int* pscan = (int*)(wsf + o); o += 512;
    float* hq = wsf + o; o += (size_t)BATCH * NQ * FEAT;     // 327,680
    float* Abuf = wsf + o; o += (size_t)BATCH * NQ * 256;    // 655,360
    float* Bbuf = wsf + o; o += (size_t)BATCH * NQ * 256;    // 655,360
    _Float16* bt_hi = (_Float16*)(wsf + o); o += (TS_TOTAL + 2) / 2;
    _Float16* bt_lo = (_Float16*)(wsf + o); o += (TS_TOTAL + 2) / 2;
    // pair-phase aliases (buffers dead by then; hA holds h4 until aggq, hB/hw free after)
    float* X1 = hw;                         // 51200*128 (hw dead after aggq)
    float* X2 = hw + (size_t)NPAIR * 128;   // 51200*128
    float* X3 = hB;                         // 51200*64
    float* X4 = hB + (size_t)NPAIR * 64;    // 51200*64

    // --- weight transpose+split+pack ---
    k_tsplit_all<<<TS_TOTAL / 256, 256, 0, stream>>>(gw, mw0, mw1, mw2, mw3, mw4, bt_hi, bt_lo);

    // --- CSR build (deterministic scan chain) ---
    hipMemsetAsync(cnt, 0, 4 * NN * sizeof(int), stream);      // cnt+fill+flag1+flag2
    hipMemsetAsync(list1, 0xFF, 2 * NN * sizeof(int), stream); // list sentinels (-1)
    hipMemsetAsync(csre + NE, 0, 8 * sizeof(int2), stream);    // slop: node 0, weight 0
    k_count<<<NE / 256, 256, 0, stream>>>(e_dst, cnt);
    k_partial<<<NB, 256, 0, stream>>>(cnt, part);
    k_scanpart<<<1, 512, 0, stream>>>(part, pscan, NB);
    k_offsets<<<NB, 256, 0, stream>>>(cnt, pscan, x, offs, dinv, meta);
    k_fill<<<NE / 256, 256, 0, stream>>>(e_src, e_dst, offs, fill, dinv, csre);

    // --- dependency-cone lists S1, S2 (sentinel-padded, ascending order) ---
    k_markS1<<<(BATCH * NQ + 255) / 256, 256, 0, stream>>>(meta, csre, flag1);
    k_partial<<<NB, 256, 0, stream>>>(flag1, part);
    k_scanpart<<<1, 512, 0, stream>>>(part, pscan, NB);
    k_emit<<<NB, 256, 0, stream>>>(flag1, pscan, list1);
    k_markS2<<<NB, 256, 0, stream>>>(meta, csre, list1, flag2);
    k_partial<<<NB, 256, 0, stream>>>(flag2, part);
    k_scanpart<<<1, 512, 0, stream>>>(part, pscan, NB);
    k_emit<<<NB, 256, 0, stream>>>(flag2, pscan, list2);

    // --- layer 0: gemm gathers A-rows straight from emb via x (h0 never materialized) ---
    hgemm<8, false, false, false, false, true, false><<<dim3(NN / 128, 1), 256, 0, stream>>>(
        emb, nullptr, nullptr, bt_hi + OFF_GCN, bt_lo + OFF_GCN,
        nullptr, hw, nullptr, FEAT, FEAT, x, nullptr);
    // agg0 full: residual rows from emb[meta.w] -> h1 in hB
    k_agg<false><<<NN / 16, 256, 0, stream>>>(hw, nullptr, meta, csre, nullptr,
                                              gb + 0 * FEAT, hB, emb);

    // --- layer 1: full gemm + full agg -> h2 in hA ---
    hgemm<8, false, false, false, false, false, false><<<dim3(NN / 128, 1), 256, 0, stream>>>(
        hB, nullptr, nullptr, bt_hi + OFF_GCN + 1 * 16384, bt_lo + OFF_GCN + 1 * 16384,
        nullptr, hw, nullptr, FEAT, FEAT, nullptr, nullptr);
    k_agg<false><<<NN / 16, 256, 0, stream>>>(hw, hB, meta, csre, nullptr,
                                              gb + 1 * FEAT, hA, nullptr);

    // --- layer 2: full gemm + agg@S2 -> h3 (S2 rows) in hB ---
    hgemm<8, false, false, false, false, false, false><<<dim3(NN / 128, 1), 256, 0, stream>>>(
        hA, nullptr, nullptr, bt_hi + OFF_GCN + 2 * 16384, bt_lo + OFF_GCN + 2 * 16384,
        nullptr, hw, nullptr, FEAT, FEAT, nullptr, nullptr);
    k_agg<true><<<NN / 16, 256, 0, stream>>>(hw, hA, meta, csre, list2,
                                             gb + 2 * FEAT, hB, nullptr);

    // --- layer 3: gemm@S2 + agg@S1 -> h4 (S1 rows) in hA ---
    // gemm3 only needs hw rows in S1∪N(S1) ⊆ S2; A rows read ⊆ S2 (h3 valid there)
    hgemm<8, false, false, false, false, false, true><<<dim3(NN / 128, 1), 256, 0, stream>>>(
        hB, nullptr, nullptr, bt_hi + OFF_GCN + 3 * 16384, bt_lo + OFF_GCN + 3 * 16384,
        nullptr, hw, nullptr, FEAT, FEAT, nullptr, list2);
    k_agg<true><<<NN / 16, 256, 0, stream>>>(hw, hB, meta, csre, list1,
                                             gb + 3 * FEAT, hA, nullptr);

    // --- layer 4: gemm@S1 + selective agg@S0 -> hq ---
    // gemm4 only needs hw rows in S0∪N(S0) ⊆ S1
    hgemm<8, false, false, false, false, false, true><<<dim3(NN / 128, 1), 256, 0, stream>>>(
        hA, nullptr, nullptr, bt_hi + OFF_GCN + 4 * 16384, bt_lo + OFF_GCN + 4 * 16384,
        nullptr, hw, nullptr, FEAT, FEAT, nullptr, list1);
    k_aggq<<<(BATCH * NQ) / 8, 256, 0, stream>>>(hw, hA, meta, csre,
                                                 gb + 4 * (size_t)FEAT, hq);

    // --- pair MLP ---
    // combined P0: Abuf = hq@mw0_top + mb0 ; Bbuf = hq@mw0_bot   (M=2560, K=128, N=512)
    hgemm<8, false, false, true, false, false, false><<<dim3(20, 4), 256, 0, stream>>>(
        hq, nullptr, nullptr, bt_hi + OFF_P0, bt_lo + OFF_P0, mb0, Abuf, Bbuf, 512, 128,
        nullptr, nullptr);
    // L1 fused pair0: A[p,:] = lrelu(Abuf[b,i,:] + Bbuf[b,j,:]) ; [51200,256]@[256,128]
    hgemm<8, true, true, false, true, false, false><<<dim3(NPAIR / 128, 1), 256, 0, stream>>>(
        nullptr, Abuf, Bbuf, bt_hi + OFF_M1, bt_lo + OFF_M1, mb1, X1, nullptr, 128, 256,
        nullptr, nullptr);
    // L2: [51200,128] @ [128,128]
    hgemm<8, true, true, false, false, false, false><<<dim3(NPAIR / 128, 1), 256, 0, stream>>>(
        X1, nullptr, nullptr, bt_hi + OFF_M2, bt_lo + OFF_M2, mb2, X2, nullptr, 128, 128,
        nullptr, nullptr);
    // L3: [51200,128] @ [128,64]
    hgemm<4, true, true, false, false, false, false><<<dim3(NPAIR / 128, 1), 256, 0, stream>>>(
        X2, nullptr, nullptr, bt_hi + OFF_M3, bt_lo + OFF_M3, mb3, X3, nullptr, 64, 128,
        nullptr, nullptr);
    // L4: [51200,64] @ [64,64]
    hgemm<4, true, true, false, false, false, false><<<dim3(NPAIR / 128, 1), 256, 0, stream>>>(
        X3, nullptr, nullptr, bt_hi + OFF_M4, bt_lo + OFF_M4, mb4, X4, nullptr, 64, 64,
        nullptr, nullptr);
    // L5 + symmetrize
    k_lastsym<<<BATCH, 256, 0, stream>>>(X4, mw5, mb5, out);
}

// Round 12
// 560.948 us; speedup vs baseline: 1.2241x; 1.0131x over previous
//
#include <hip/hip_runtime.h>
#include <hip/hip_bf16.h>

#define NQ 20
#define NLAY 51            // N_LAYER+1
#define FEAT 128
#define BATCH 128
#define NN (BATCH * NQ * NLAY)   // 130560
#define NE 524288
#define NPAIR (BATCH * NQ * NQ)  // 51200
#define NB (NN / 256)            // 510

typedef _Float16 half8 __attribute__((ext_vector_type(8)));
typedef float floatx4 __attribute__((ext_vector_type(4)));

__device__ __forceinline__ float lrelu(float v) { return v >= 0.f ? v : 0.01f * v; }

// ---------------- CSR build ----------------
__global__ void k_count(const int* __restrict__ dst, int* __restrict__ cnt) {
    int e = blockIdx.x * 256 + threadIdx.x;
    atomicAdd(&cnt[dst[e]], 1);
}

__global__ void k_partial(const int* __restrict__ cnt, int* __restrict__ part) {
    __shared__ int sm[256];
    int t = threadIdx.x;
    sm[t] = cnt[blockIdx.x * 256 + t];
    __syncthreads();
    for (int s = 128; s > 0; s >>= 1) {
        if (t < s) sm[t] += sm[t + s];
        __syncthreads();
    }
    if (t == 0) part[blockIdx.x] = sm[0];
}

__global__ void k_scanpart(const int* __restrict__ part, int* __restrict__ pscan, int nb) {
    __shared__ int sm[512];
    int t = threadIdx.x;
    int v = (t < nb) ? part[t] : 0;
    sm[t] = v;
    __syncthreads();
    for (int s = 1; s < 512; s <<= 1) {
        int add = (t >= s) ? sm[t - s] : 0;
        __syncthreads();
        sm[t] += add;
        __syncthreads();
    }
    if (t < nb) pscan[t] = sm[t] - v;   // exclusive
}

// offsets + dinv + packed meta {off, deg, dinv_bits, x[node]}
__global__ void k_offsets(const int* __restrict__ cnt, const int* __restrict__ pscan,
                          const int* __restrict__ x,
                          int* __restrict__ offs, float* __restrict__ dinv,
                          int4* __restrict__ meta) {
    __shared__ int sm[256];
    int t = threadIdx.x, g = blockIdx.x * 256 + t;
    int v = cnt[g];
    sm[t] = v;
    __syncthreads();
    for (int s = 1; s < 256; s <<= 1) {
        int add = (t >= s) ? sm[t - s] : 0;
        __syncthreads();
        sm[t] += add;
        __syncthreads();
    }
    int off = pscan[blockIdx.x] + sm[t] - v;
    float di = rsqrtf((float)(v + 1));  // +1 self loop
    offs[g] = off;
    dinv[g] = di;
    meta[g] = make_int4(off, v, __float_as_int(di), x[g]);
}

// fill packed edges {src, dinv[src]_bits}
__global__ void k_fill(const int* __restrict__ src, const int* __restrict__ dst,
                       const int* __restrict__ offs, int* __restrict__ fill,
                       const float* __restrict__ dinv, int2* __restrict__ csre) {
    int e = blockIdx.x * 256 + threadIdx.x;
    int d = dst[e];
    int s = src[e];
    int pos = offs[d] + atomicAdd(&fill[d], 1);
    csre[pos] = make_int2(s, __float_as_int(dinv[s]));
}

// ---------------- dependency-cone sets (replay-safe: sentinel-padded lists) ----------------
__global__ void k_markS1(const int4* __restrict__ meta, const int2* __restrict__ csre,
                         int* __restrict__ flag) {
    int q = blockIdx.x * 256 + threadIdx.x;   // 0..2559
    if (q >= BATCH * NQ) return;
    int node = (q / NQ) * (NQ * NLAY) + (q % NQ);
    flag[node] = 1;
    int4 m = meta[node];
    for (int e = 0; e < m.y; e++) flag[csre[m.x + e].x] = 1;   // benign races (all write 1)
}

__global__ void k_markS2(const int4* __restrict__ meta, const int2* __restrict__ csre,
                         const int* __restrict__ list1, int* __restrict__ flag) {
    int i = blockIdx.x * 256 + threadIdx.x;
    int node = list1[i];
    if ((unsigned)node >= (unsigned)NN) return;   // sentinel
    flag[node] = 1;
    int4 m = meta[node];
    for (int e = 0; e < m.y; e++) flag[csre[m.x + e].x] = 1;
}

// scan-ordered compaction: members land in slots [0,|S|) in ASCENDING node order
__global__ void k_emit(const int* __restrict__ flag, const int* __restrict__ pscan,
                       int* __restrict__ list) {
    __shared__ int sm[256];
    int t = threadIdx.x, g = blockIdx.x * 256 + t;
    int v = flag[g];
    sm[t] = v;
    __syncthreads();
    for (int s = 1; s < 256; s <<= 1) {
        int add = (t >= s) ? sm[t - s] : 0;
        __syncthreads();
        sm[t] += add;
        __syncthreads();
    }
    if (v) list[pscan[blockIdx.x] + sm[t] - 1] = g;
}

// ---------------- weight transpose + fp16 hi/lo split, PACKED MFMA-fragment layout -------
#define OFF_GCN 0                 // 5 x K=128 N=128
#define OFF_P0  81920             // combined mw0: K=128 N=512
#define OFF_M1  147456            // mw1: K=256 N=128
#define OFF_M2  180224            // mw2: K=128 N=128
#define OFF_M3  196608            // mw3: K=128 N=64
#define OFF_M4  204800            // mw4: K=64  N=64
#define TS_TOTAL 208896

__global__ void k_tsplit_all(const float* __restrict__ gw, const float* __restrict__ mw0,
                             const float* __restrict__ mw1, const float* __restrict__ mw2,
                             const float* __restrict__ mw3, const float* __restrict__ mw4,
                             _Float16* __restrict__ hi, _Float16* __restrict__ lo) {
    int idx = blockIdx.x * 256 + threadIdx.x;
    const float* src;
    int K, N, rel;
    bool p0 = false;
    if (idx < OFF_P0) {
        int L = (idx - OFF_GCN) >> 14; rel = (idx - OFF_GCN) & 16383;
        src = gw + L * 16384; K = 128; N = 128;
    } else if (idx < OFF_M1) {
        rel = idx - OFF_P0; src = mw0; K = 128; N = 512; p0 = true;
    } else if (idx < OFF_M2) {
        rel = idx - OFF_M1;  src = mw1; K = 256; N = 128;
    } else if (idx < OFF_M3) {
        rel = idx - OFF_M2;  src = mw2; K = 128; N = 128;
    } else if (idx < OFF_M4) {
        rel = idx - OFF_M3;  src = mw3; K = 128; N = 64;
    } else {
        rel = idx - OFF_M4;  src = mw4; K = 64;  N = 64;
    }
    int kblks = K >> 5;
    int j = rel & 7;
    int lane = (rel >> 3) & 63;
    int t2 = rel >> 9;
    int kblk = t2 % kblks;
    int ntile = t2 / kblks;
    int col = ntile * 16 + (lane & 15);
    int k = kblk * 32 + ((lane >> 4) << 3) + j;
    float f;
    if (p0) {
        f = (col < 256) ? src[k * 256 + col] : src[(k + 128) * 256 + (col - 256)];
    } else {
        f = src[k * N + col];
    }
    _Float16 h = (_Float16)f;
    hi[idx] = h;
    lo[idx] = (_Float16)(f - (float)h);
}

// ---------------- split-fp16 MFMA GEMM ----------------
// B pre-packed in fragment order (hi/lo). 3-product Markidis split, fp32 accumulate.
// GATHA: A-rows indirected through gmap (embedding-gather fusion).
// LISTM: M-rows indirected through sentinel-padded ascending list (cone slicing).
template <int NT_N, bool LEAKY, bool BIAS, bool P0SPLIT, bool FUSEA, bool GATHA, bool LISTM>
__launch_bounds__(256, 2)
__global__ void hgemm(const float* __restrict__ A,
                      const float* __restrict__ FA, const float* __restrict__ FB,
                      const _Float16* __restrict__ Bh, const _Float16* __restrict__ Bl,
                      const float* __restrict__ bias,
                      float* __restrict__ C, float* __restrict__ C2,
                      int N, int K, const int* __restrict__ gmap,
                      const int* __restrict__ listm) {
    if (LISTM) {
        if ((unsigned)listm[blockIdx.x * 128] >= (unsigned)NN) return;  // all-sentinel block
    }
    const int KB = K >> 5;
    const int lane = threadIdx.x & 63;
    const int wid = threadIdx.x >> 6;
    const int lm = lane & 15, lq = lane >> 4;
    const int m0 = blockIdx.x * 128 + wid * 32;
    const int n0t = blockIdx.y * NT_N;

    const float* arow[2];
    const float* brow[2];
#pragma unroll
    for (int mt = 0; mt < 2; mt++) {
        int row = m0 + mt * 16 + lm;
        if (FUSEA) {
            int b = row / (NQ * NQ);
            int rr = row - b * (NQ * NQ);
            int i = rr / NQ;
            int j = rr - i * NQ;
            arow[mt] = FA + (size_t)(b * NQ + i) * 256;
            brow[mt] = FB + (size_t)(b * NQ + j) * 256;
        } else if (GATHA) {
            arow[mt] = A + (size_t)gmap[row] * K;
        } else if (LISTM) {
            int lr = listm[row];
            lr = ((unsigned)lr < (unsigned)NN) ? lr : 0;
            arow[mt] = A + (size_t)lr * K;
        } else {
            arow[mt] = A + (size_t)row * K;
        }
    }

    floatx4 acc[2][NT_N];
#pragma unroll
    for (int mt = 0; mt < 2; mt++)
#pragma unroll
        for (int nt = 0; nt < NT_N; nt++) acc[mt][nt] = (floatx4)0.f;

    for (int kb = 0; kb < KB; kb++) {
        const int k0 = kb * 32 + lq * 8;
        half8 ahi[2], alo[2];
#pragma unroll
        for (int mt = 0; mt < 2; mt++) {
            floatx4 av0, av1;
            if (FUSEA) {
                floatx4 fa0 = *(const floatx4*)(arow[mt] + k0);
                floatx4 fa1 = *(const floatx4*)(arow[mt] + k0 + 4);
                floatx4 fb0 = *(const floatx4*)(brow[mt] + k0);
                floatx4 fb1 = *(const floatx4*)(brow[mt] + k0 + 4);
#pragma unroll
                for (int q = 0; q < 4; q++) {
                    av0[q] = lrelu(fa0[q] + fb0[q]);
                    av1[q] = lrelu(fa1[q] + fb1[q]);
                }
            } else {
                av0 = *(const floatx4*)(arow[mt] + k0);
                av1 = *(const floatx4*)(arow[mt] + k0 + 4);
            }
#pragma unroll
            for (int q = 0; q < 4; q++) {
                _Float16 h0 = (_Float16)av0[q];
                ahi[mt][q] = h0;
                alo[mt][q] = (_Float16)(av0[q] - (float)h0);
                _Float16 h1 = (_Float16)av1[q];
                ahi[mt][4 + q] = h1;
                alo[mt][4 + q] = (_Float16)(av1[q] - (float)h1);
            }
        }
#pragma unroll
        for (int nt = 0; nt < NT_N; nt++) {
            size_t boff = (((size_t)(n0t + nt) * KB + kb) * 64 + lane) * 8;
            half8 bhi = *(const half8*)(Bh + boff);
            half8 blo = *(const half8*)(Bl + boff);
#pragma unroll
            for (int mt = 0; mt < 2; mt++) {
                acc[mt][nt] = __builtin_amdgcn_mfma_f32_16x16x32_f16(ahi[mt], bhi, acc[mt][nt], 0, 0, 0);
                acc[mt][nt] = __builtin_amdgcn_mfma_f32_16x16x32_f16(ahi[mt], blo, acc[mt][nt], 0, 0, 0);
                acc[mt][nt] = __builtin_amdgcn_mfma_f32_16x16x32_f16(alo[mt], bhi, acc[mt][nt], 0, 0, 0);
            }
        }
    }

    // store-row mapping (C/D layout: col=lane&15, row=(lane>>4)*4+reg)
    int strow[2][4];
    bool svalid[2][4];
#pragma unroll
    for (int mt = 0; mt < 2; mt++)
#pragma unroll
        for (int r = 0; r < 4; r++) {
            int mlog = m0 + mt * 16 + lq * 4 + r;
            if (LISTM) {
                int sr = listm[mlog];
                svalid[mt][r] = (unsigned)sr < (unsigned)NN;
                strow[mt][r] = svalid[mt][r] ? sr : 0;
            } else {
                svalid[mt][r] = true;
                strow[mt][r] = mlog;
            }
        }

#pragma unroll
    for (int nt = 0; nt < NT_N; nt++) {
        int col = (n0t + nt) * 16 + lm;
        float bv = (BIAS || P0SPLIT) ? bias[col < 256 ? col : 0] : 0.f;
#pragma unroll
        for (int mt = 0; mt < 2; mt++) {
#pragma unroll
            for (int r = 0; r < 4; r++) {
                if (!svalid[mt][r]) continue;
                int row = strow[mt][r];
                float val = acc[mt][nt][r];
                if (P0SPLIT) {
                    if (col < 256) C[(size_t)row * 256 + col] = val + bv;
                    else C2[(size_t)row * 256 + col - 256] = val;
                } else {
                    if (BIAS) val += bv;
                    if (LEAKY) val = lrelu(val);
                    C[(size_t)row * N + col] = val;
                }
            }
        }
    }
}

// ---------------- GCN aggregation + bias + leaky + residual, h IN PLACE ----------------
// Each row owned by exactly one half-wave: read residual h[n] -> write h[n]; gathers
// read hw only. Single h buffer keeps working set (h+hw = 134 MB) inside the 256 MB LLC.
// LIST=false: sequential ids. LIST=true: sentinel-padded ascending list, clamped,
// stores suppressed. embt != null: residual from embt[meta.w] (layer 0).
template <bool LIST>
__global__ void k_agg(const float* __restrict__ hw, float* __restrict__ h,
                      const int4* __restrict__ meta, const int2* __restrict__ csre,
                      const int* __restrict__ list,
                      const float* __restrict__ bias,
                      const float* __restrict__ embt) {
    int tid = threadIdx.x;
    int sl = tid & 31;
    int p = blockIdx.x * 8 + (tid >> 5);
    int n0, n1;
    bool val0 = true, val1 = true;
    if (LIST) {
        n0 = list[p * 2];
        n1 = list[p * 2 + 1];
        val0 = (unsigned)n0 < (unsigned)NN;
        val1 = (unsigned)n1 < (unsigned)NN;
        n0 = val0 ? n0 : 0;
        n1 = val1 ? n1 : 0;
    } else {
        n0 = p * 2;
        n1 = n0 + 1;
    }
    int4 m0 = meta[n0], m1 = meta[n1];
    float di0 = __int_as_float(m0.z), di1 = __int_as_float(m1.z);
    int off0 = m0.x, deg0 = LIST ? (val0 ? m0.y : 0) : m0.y;
    int off1 = m1.x, deg1 = LIST ? (val1 ? m1.y : 0) : m1.y;
    float4 v0 = ((const float4*)(hw + (size_t)n0 * FEAT))[sl];
    float4 v1 = ((const float4*)(hw + (size_t)n1 * FEAT))[sl];
    float4 ho0, ho1;
    if (embt) {
        ho0 = ((const float4*)(embt + (size_t)m0.w * FEAT))[sl];
        ho1 = ((const float4*)(embt + (size_t)m1.w * FEAT))[sl];
    } else {
        ho0 = ((const float4*)(h + (size_t)n0 * FEAT))[sl];
        ho1 = ((const float4*)(h + (size_t)n1 * FEAT))[sl];
    }
    float s20 = di0 * di0, s21 = di1 * di1;
    float a0x = v0.x * s20, a0y = v0.y * s20, a0z = v0.z * s20, a0w = v0.w * s20;
    float a1x = v1.x * s21, a1y = v1.y * s21, a1z = v1.z * s21, a1w = v1.w * s21;
    int d0c = max(deg0 - 1, 0), d1c = max(deg1 - 1, 0);
    int dm = max(deg0, deg1);
    for (int e = 0; e < dm; e += 4) {
        int2 e00 = csre[off0 + min(e,     d0c)];
        int2 e01 = csre[off0 + min(e + 1, d0c)];
        int2 e02 = csre[off0 + min(e + 2, d0c)];
        int2 e03 = csre[off0 + min(e + 3, d0c)];
        int2 e10 = csre[off1 + min(e,     d1c)];
        int2 e11 = csre[off1 + min(e + 1, d1c)];
        int2 e12 = csre[off1 + min(e + 2, d1c)];
        int2 e13 = csre[off1 + min(e + 3, d1c)];
        float4 u00 = ((const float4*)(hw + (size_t)e00.x * FEAT))[sl];
        float4 u01 = ((const float4*)(hw + (size_t)e01.x * FEAT))[sl];
        float4 u02 = ((const float4*)(hw + (size_t)e02.x * FEAT))[sl];
        float4 u03 = ((const float4*)(hw + (size_t)e03.x * FEAT))[sl];
        float4 u10 = ((const float4*)(hw + (size_t)e10.x * FEAT))[sl];
        float4 u11 = ((const float4*)(hw + (size_t)e11.x * FEAT))[sl];
        float4 u12 = ((const float4*)(hw + (size_t)e12.x * FEAT))[sl];
        float4 u13 = ((const float4*)(hw + (size_t)e13.x * FEAT))[sl];
        float w00 = (e     < deg0) ? __int_as_float(e00.y) * di0 : 0.f;
        float w01 = (e + 1 < deg0) ? __int_as_float(e01.y) * di0 : 0.f;
        float w02 = (e + 2 < deg0) ? __int_as_float(e02.y) * di0 : 0.f;
        float w03 = (e + 3 < deg0) ? __int_as_float(e03.y) * di0 : 0.f;
        float w10 = (e     < deg1) ? __int_as_float(e10.y) * di1 : 0.f;
        float w11 = (e + 1 < deg1) ? __int_as_float(e11.y) * di1 : 0.f;
        float w12 = (e + 2 < deg1) ? __int_as_float(e12.y) * di1 : 0.f;
        float w13 = (e + 3 < deg1) ? __int_as_float(e13.y) * di1 : 0.f;
        a0x += u00.x * w00 + u01.x * w01 + u02.x * w02 + u03.x * w03;
        a0y += u00.y * w00 + u01.y * w01 + u02.y * w02 + u03.y * w03;
        a0z += u00.z * w00 + u01.z * w01 + u02.z * w02 + u03.z * w03;
        a0w += u00.w * w00 + u01.w * w01 + u02.w * w02 + u03.w * w03;
        a1x += u10.x * w10 + u11.x * w11 + u12.x * w12 + u13.x * w13;
        a1y += u10.y * w10 + u11.y * w11 + u12.y * w12 + u13.y * w13;
        a1z += u10.z * w10 + u11.z * w11 + u12.z * w12 + u13.z * w13;
        a1w += u10.w * w10 + u11.w * w11 + u12.w * w12 + u13.w * w13;
    }
    float4 bv = ((const float4*)bias)[sl];
    float4 r0, r1;
    r0.x = lrelu(a0x + bv.x) + ho0.x;
    r0.y = lrelu(a0y + bv.y) + ho0.y;
    r0.z = lrelu(a0z + bv.z) + ho0.z;
    r0.w = lrelu(a0w + bv.w) + ho0.w;
    r1.x = lrelu(a1x + bv.x) + ho1.x;
    r1.y = lrelu(a1y + bv.y) + ho1.y;
    r1.z = lrelu(a1z + bv.z) + ho1.z;
    r1.w = lrelu(a1w + bv.w) + ho1.w;
    if (!LIST || val0) ((float4*)(h + (size_t)n0 * FEAT))[sl] = r0;
    if (!LIST || val1) ((float4*)(h + (size_t)n1 * FEAT))[sl] = r1;
}

// ---------------- selective final agg (layer 4): S0 rows only -> hq, no leaky ----------------
__global__ void k_aggq(const float* __restrict__ hw, const float* __restrict__ h,
                       const int4* __restrict__ meta, const int2* __restrict__ csre,
                       const float* __restrict__ gbias, float* __restrict__ hq) {
    int tid = threadIdx.x;
    int sl = tid & 31;
    int q = blockIdx.x * 8 + (tid >> 5);   // 0..2559
    int b = q / NQ, i = q - b * NQ;
    int node = b * (NQ * NLAY) + i;
    int4 m = meta[node];
    float di = __int_as_float(m.z);
    int off = m.x, deg = m.y;
    float s2 = di * di;
    float4 v = ((const float4*)(hw + (size_t)node * FEAT))[sl];
    float ax = v.x * s2, ay = v.y * s2, az = v.z * s2, aw = v.w * s2;
    int dc = max(deg - 1, 0);
    for (int e = 0; e < deg; e += 4) {
        int2 e0 = csre[off + min(e,     dc)];
        int2 e1 = csre[off + min(e + 1, dc)];
        int2 e2 = csre[off + min(e + 2, dc)];
        int2 e3 = csre[off + min(e + 3, dc)];
        float4 u0 = ((const float4*)(hw + (size_t)e0.x * FEAT))[sl];
        float4 u1 = ((const float4*)(hw + (size_t)e1.x * FEAT))[sl];
        float4 u2 = ((const float4*)(hw + (size_t)e2.x * FEAT))[sl];
        float4 u3 = ((const float4*)(hw + (size_t)e3.x * FEAT))[sl];
        float w0 = (e     < deg) ? __int_as_float(e0.y) * di : 0.f;
        float w1 = (e + 1 < deg) ? __int_as_float(e1.y) * di : 0.f;
        float w2 = (e + 2 < deg) ? __int_as_float(e2.y) * di : 0.f;
        float w3 = (e + 3 < deg) ? __int_as_float(e3.y) * di : 0.f;
        ax += u0.x * w0 + u1.x * w1 + u2.x * w2 + u3.x * w3;
        ay += u0.y * w0 + u1.y * w1 + u2.y * w2 + u3.y * w3;
        az += u0.z * w0 + u1.z * w1 + u2.z * w2 + u3.z * w3;
        aw += u0.w * w0 + u1.w * w1 + u2.w * w2 + u3.w * w3;
    }
    float4 bv = ((const float4*)gbias)[sl];
    float4 ho = ((const float4*)(h + (size_t)node * FEAT))[sl];
    ((float4*)(hq + (size_t)q * FEAT))[sl] =
        make_float4(ax + bv.x + ho.x, ay + bv.y + ho.y, az + bv.z + ho.z, aw + bv.w + ho.w);
}

// ---------------- last layer + symmetrize, one block per batch ----------------
__global__ void k_lastsym(const float* __restrict__ X4, const float* __restrict__ mw5,
                          const float* __restrict__ mb5, float* __restrict__ out) {
    __shared__ float w[64];
    __shared__ float sm[NQ * NQ];
    int t = threadIdx.x;
    if (t < 64) w[t] = mw5[t];
    __syncthreads();
    int b = blockIdx.x;
    for (int p = t; p < NQ * NQ; p += 256) {
        const float4* row = (const float4*)(X4 + (size_t)(b * NQ * NQ + p) * 64);
        float s = 0.f;
#pragma unroll
        for (int k4 = 0; k4 < 16; k4++) {
            float4 v = row[k4];
            s += v.x * w[k4 * 4] + v.y * w[k4 * 4 + 1] + v.z * w[k4 * 4 + 2] + v.w * w[k4 * 4 + 3];
        }
        sm[p] = s + mb5[0];
    }
    __syncthreads();
    for (int r = t; r < NQ * NQ; r += 256) {
        int i = r / NQ, j = r % NQ;
        out[(size_t)b * NQ * NQ + r] = 0.5f * (sm[r] + sm[j * NQ + i]);
    }
}

extern "C" void kernel_launch(void* const* d_in, const int* in_sizes, int n_in,
                              void* d_out, int out_size, void* d_ws, size_t ws_size,
                              hipStream_t stream) {
    const int* x = (const int*)d_in[0];
    const int* ei = (const int*)d_in[1];
    const int* e_src = ei;
    const int* e_dst = ei + NE;
    const float* emb = (const float*)d_in[2];
    const float* gw = (const float*)d_in[3];   // [5,128,128]
    const float* gb = (const float*)d_in[4];   // [5,128]
    const float* mw0 = (const float*)d_in[5];
    const float* mb0 = (const float*)d_in[6];
    const float* mw1 = (const float*)d_in[7];
    const float* mb1 = (const float*)d_in[8];
    const float* mw2 = (const float*)d_in[9];
    const float* mb2 = (const float*)d_in[10];
    const float* mw3 = (const float*)d_in[11];
    const float* mb3 = (const float*)d_in[12];
    const float* mw4 = (const float*)d_in[13];
    const float* mb4 = (const float*)d_in[14];
    const float* mw5 = (const float*)d_in[15];
    const float* mb5 = (const float*)d_in[16];
    float* out = (float*)d_out;

    float* wsf = (float*)d_ws;
    size_t o = 0;
    const size_t HSZ = (size_t)NN * FEAT;             // 16,711,680
    float* h  = wsf + o; o += HSZ;    // single in-place h buffer (working set = h+hw < LLC)
    float* hw = wsf + o; o += HSZ;
    // zero-memset region: cnt, fill, flag1, flag2 (contiguous)
    int* cnt   = (int*)(wsf + o); o += NN;
    int* fill  = (int*)(wsf + o); o += NN;
    int* flag1 = (int*)(wsf + o); o += NN;
    int* flag2 = (int*)(wsf + o); o += NN;
    // 0xFF-memset region: list1, list2 (contiguous, sentinel -1)
    int* list1 = (int*)(wsf + o); o += NN;
    int* list2 = (int*)(wsf + o); o += NN;
    int* offs = (int*)(wsf + o); o += NN;
    float* dinv = wsf + o; o += NN;
    int4* meta = (int4*)(wsf + o); o += 4 * (size_t)NN;
    int2* csre = (int2*)(wsf + o); o += 2 * (size_t)(NE + 8);  // +8 slop for deg-0 clamp
    int* part  = (int*)(wsf + o); o += 512;
    int* pscan = (int*)(wsf + o); o += 512;
    float* hq = wsf + o; o += (size_t)BATCH * NQ * FEAT;     // 327,680
    float* Abuf = wsf + o; o += (size_t)BATCH * NQ * 256;    // 655,360
    float* Bbuf = wsf + o; o += (size_t)BATCH * NQ * 256;    // 655,360
    _Float16* bt_hi = (_Float16*)(wsf + o); o += (TS_TOTAL + 2) / 2;
    _Float16* bt_lo = (_Float16*)(wsf + o); o += (TS_TOTAL + 2) / 2;
    // pair-phase aliases (hw dead after aggq; h dead after aggq)
    float* X1 = hw;                         // 51200*128
    float* X2 = hw + (size_t)NPAIR * 128;   // 51200*128
    float* X3 = h;                          // 51200*64
    float* X4 = h + (size_t)NPAIR * 64;     // 51200*64

    // --- weight transpose+split+pack ---
    k_tsplit_all<<<TS_TOTAL / 256, 256, 0, stream>>>(gw, mw0, mw1, mw2, mw3, mw4, bt_hi, bt_lo);

    // --- CSR build (deterministic scan chain) ---
    hipMemsetAsync(cnt, 0, 4 * NN * sizeof(int), stream);      // cnt+fill+flag1+flag2
    hipMemsetAsync(list1, 0xFF, 2 * NN * sizeof(int), stream); // list sentinels (-1)
    hipMemsetAsync(csre + NE, 0, 8 * sizeof(int2), stream);    // slop: node 0, weight 0
    k_count<<<NE / 256, 256, 0, stream>>>(e_dst, cnt);
    k_partial<<<NB, 256, 0, stream>>>(cnt, part);
    k_scanpart<<<1, 512, 0, stream>>>(part, pscan, NB);
    k_offsets<<<NB, 256, 0, stream>>>(cnt, pscan, x, offs, dinv, meta);
    k_fill<<<NE / 256, 256, 0, stream>>>(e_src, e_dst, offs, fill, dinv, csre);

    // --- dependency-cone lists S1, S2 (sentinel-padded, ascending order) ---
    k_markS1<<<(BATCH * NQ + 255) / 256, 256, 0, stream>>>(meta, csre, flag1);
    k_partial<<<NB, 256, 0, stream>>>(flag1, part);
    k_scanpart<<<1, 512, 0, stream>>>(part, pscan, NB);
    k_emit<<<NB, 256, 0, stream>>>(flag1, pscan, list1);
    k_markS2<<<NB, 256, 0, stream>>>(meta, csre, list1, flag2);
    k_partial<<<NB, 256, 0, stream>>>(flag2, part);
    k_scanpart<<<1, 512, 0, stream>>>(part, pscan, NB);
    k_emit<<<NB, 256, 0, stream>>>(flag2, pscan, list2);

    // --- layer 0: gemm gathers A-rows straight from emb via x (h0 never materialized) ---
    hgemm<8, false, false, false, false, true, false><<<dim3(NN / 128, 1), 256, 0, stream>>>(
        emb, nullptr, nullptr, bt_hi + OFF_GCN, bt_lo + OFF_GCN,
        nullptr, hw, nullptr, FEAT, FEAT, x, nullptr);
    // agg0 full: residual from emb[meta.w], writes h (first touch)
    k_agg<false><<<NN / 16, 256, 0, stream>>>(hw, h, meta, csre, nullptr,
                                              gb + 0 * FEAT, emb);

    // --- layer 1: full gemm + full agg (h in place) ---
    hgemm<8, false, false, false, false, false, false><<<dim3(NN / 128, 1), 256, 0, stream>>>(
        h, nullptr, nullptr, bt_hi + OFF_GCN + 1 * 16384, bt_lo + OFF_GCN + 1 * 16384,
        nullptr, hw, nullptr, FEAT, FEAT, nullptr, nullptr);
    k_agg<false><<<NN / 16, 256, 0, stream>>>(hw, h, meta, csre, nullptr,
                                              gb + 1 * FEAT, nullptr);

    // --- layer 2: full gemm + agg@S2 (h in place; non-S2 rows keep h2 — never read) ---
    hgemm<8, false, false, false, false, false, false><<<dim3(NN / 128, 1), 256, 0, stream>>>(
        h, nullptr, nullptr, bt_hi + OFF_GCN + 2 * 16384, bt_lo + OFF_GCN + 2 * 16384,
        nullptr, hw, nullptr, FEAT, FEAT, nullptr, nullptr);
    k_agg<true><<<NN / 16, 256, 0, stream>>>(hw, h, meta, csre, list2,
                                             gb + 2 * FEAT, nullptr);

    // --- layer 3: gemm@S2 + agg@S1 ---
    hgemm<8, false, false, false, false, false, true><<<dim3(NN / 128, 1), 256, 0, stream>>>(
        h, nullptr, nullptr, bt_hi + OFF_GCN + 3 * 16384, bt_lo + OFF_GCN + 3 * 16384,
        nullptr, hw, nullptr, FEAT, FEAT, nullptr, list2);
    k_agg<true><<<NN / 16, 256, 0, stream>>>(hw, h, meta, csre, list1,
                                             gb + 3 * FEAT, nullptr);

    // --- layer 4: gemm@S1 + selective agg@S0 -> hq ---
    hgemm<8, false, false, false, false, false, true><<<dim3(NN / 128, 1), 256, 0, stream>>>(
        h, nullptr, nullptr, bt_hi + OFF_GCN + 4 * 16384, bt_lo + OFF_GCN + 4 * 16384,
        nullptr, hw, nullptr, FEAT, FEAT, nullptr, list1);
    k_aggq<<<(BATCH * NQ) / 8, 256, 0, stream>>>(hw, h, meta, csre,
                                                 gb + 4 * (size_t)FEAT, hq);

    // --- pair MLP ---
    // combined P0: Abuf = hq@mw0_top + mb0 ; Bbuf = hq@mw0_bot   (M=2560, K=128, N=512)
    hgemm<8, false, false, true, false, false, false><<<dim3(20, 4), 256, 0, stream>>>(
        hq, nullptr, nullptr, bt_hi + OFF_P0, bt_lo + OFF_P0, mb0, Abuf, Bbuf, 512, 128,
        nullptr, nullptr);
    // L1 fused pair0: A[p,:] = lrelu(Abuf[b,i,:] + Bbuf[b,j,:]) ; [51200,256]@[256,128]
    hgemm<8, true, true, false, true, false, false><<<dim3(NPAIR / 128, 1), 256, 0, stream>>>(
        nullptr, Abuf, Bbuf, bt_hi + OFF_M1, bt_lo + OFF_M1, mb1, X1, nullptr, 128, 256,
        nullptr, nullptr);
    // L2: [51200,128] @ [128,128]
    hgemm<8, true, true, false, false, false, false><<<dim3(NPAIR / 128, 1), 256, 0, stream>>>(
        X1, nullptr, nullptr, bt_hi + OFF_M2, bt_lo + OFF_M2, mb2, X2, nullptr, 128, 128,
        nullptr, nullptr);
    // L3: [51200,128] @ [128,64]
    hgemm<4, true, true, false, false, false, false><<<dim3(NPAIR / 128, 1), 256, 0, stream>>>(
        X2, nullptr, nullptr, bt_hi + OFF_M3, bt_lo + OFF_M3, mb3, X3, nullptr, 64, 128,
        nullptr, nullptr);
    // L4: [51200,64] @ [64,64]
    hgemm<4, true, true, false, false, false, false><<<dim3(NPAIR / 128, 1), 256, 0, stream>>>(
        X3, nullptr, nullptr, bt_hi + OFF_M4, bt_lo + OFF_M4, mb4, X4, nullptr, 64, 64,
        nullptr, nullptr);
    // L5 + symmetrize
    k_lastsym<<<BATCH, 256, 0, stream>>>(X4, mw5, mb5, out);
}

// Round 13
// 548.356 us; speedup vs baseline: 1.2522x; 1.0230x over previous
//
#include <hip/hip_runtime.h>
#include <hip/hip_bf16.h>

#define NQ 20
#define NLAY 51            // N_LAYER+1
#define FEAT 128
#define BATCH 128
#define NN (BATCH * NQ * NLAY)   // 130560
#define NE 524288
#define NPAIR (BATCH * NQ * NQ)  // 51200
#define NB (NN / 256)            // 510
#define VOCAB 1021

typedef _Float16 half8 __attribute__((ext_vector_type(8)));
typedef float floatx4 __attribute__((ext_vector_type(4)));

__device__ __forceinline__ float lrelu(float v) { return v >= 0.f ? v : 0.01f * v; }

// ---------------- CSR build ----------------
__global__ void k_count(const int* __restrict__ dst, int* __restrict__ cnt) {
    int e = blockIdx.x * 256 + threadIdx.x;
    atomicAdd(&cnt[dst[e]], 1);
}

__global__ void k_partial(const int* __restrict__ cnt, int* __restrict__ part) {
    __shared__ int sm[256];
    int t = threadIdx.x;
    sm[t] = cnt[blockIdx.x * 256 + t];
    __syncthreads();
    for (int s = 128; s > 0; s >>= 1) {
        if (t < s) sm[t] += sm[t + s];
        __syncthreads();
    }
    if (t == 0) part[blockIdx.x] = sm[0];
}

__global__ void k_scanpart(const int* __restrict__ part, int* __restrict__ pscan, int nb) {
    __shared__ int sm[512];
    int t = threadIdx.x;
    int v = (t < nb) ? part[t] : 0;
    sm[t] = v;
    __syncthreads();
    for (int s = 1; s < 512; s <<= 1) {
        int add = (t >= s) ? sm[t - s] : 0;
        __syncthreads();
        sm[t] += add;
        __syncthreads();
    }
    if (t < nb) pscan[t] = sm[t] - v;   // exclusive
}

// offsets + dinv + packed meta {off, deg, dinv_bits, x[node]}; also clamped identity map
__global__ void k_offsets(const int* __restrict__ cnt, const int* __restrict__ pscan,
                          const int* __restrict__ x,
                          int* __restrict__ offs, float* __restrict__ dinv,
                          int4* __restrict__ meta, int* __restrict__ idmap) {
    __shared__ int sm[256];
    int t = threadIdx.x, g = blockIdx.x * 256 + t;
    int v = cnt[g];
    sm[t] = v;
    __syncthreads();
    for (int s = 1; s < 256; s <<= 1) {
        int add = (t >= s) ? sm[t - s] : 0;
        __syncthreads();
        sm[t] += add;
        __syncthreads();
    }
    int off = pscan[blockIdx.x] + sm[t] - v;
    float di = rsqrtf((float)(v + 1));  // +1 self loop
    offs[g] = off;
    dinv[g] = di;
    meta[g] = make_int4(off, v, __float_as_int(di), x[g]);
    if (g < 1024) idmap[g] = min(g, VOCAB - 1);
}

// fill packed edges {src, dinv[src]_bits} and token edges {x[src], dinv[src]_bits}
__global__ void k_fill(const int* __restrict__ src, const int* __restrict__ dst,
                       const int* __restrict__ offs, int* __restrict__ fill,
                       const float* __restrict__ dinv, const int* __restrict__ x,
                       int2* __restrict__ csre, int2* __restrict__ csre0) {
    int e = blockIdx.x * 256 + threadIdx.x;
    int d = dst[e];
    int s = src[e];
    int pos = offs[d] + atomicAdd(&fill[d], 1);
    int wb = __float_as_int(dinv[s]);
    csre[pos] = make_int2(s, wb);
    csre0[pos] = make_int2(x[s], wb);
}

// ---------------- dependency-cone sets (replay-safe: sentinel-padded lists) ----------------
__global__ void k_markS1(const int4* __restrict__ meta, const int2* __restrict__ csre,
                         int* __restrict__ flag) {
    int q = blockIdx.x * 256 + threadIdx.x;   // 0..2559
    if (q >= BATCH * NQ) return;
    int node = (q / NQ) * (NQ * NLAY) + (q % NQ);
    flag[node] = 1;
    int4 m = meta[node];
    for (int e = 0; e < m.y; e++) flag[csre[m.x + e].x] = 1;   // benign races (all write 1)
}

__global__ void k_markS2(const int4* __restrict__ meta, const int2* __restrict__ csre,
                         const int* __restrict__ list1, int* __restrict__ flag) {
    int i = blockIdx.x * 256 + threadIdx.x;
    int node = list1[i];
    if ((unsigned)node >= (unsigned)NN) return;   // sentinel
    flag[node] = 1;
    int4 m = meta[node];
    for (int e = 0; e < m.y; e++) flag[csre[m.x + e].x] = 1;
}

// scan-ordered compaction: members land in slots [0,|S|) in ASCENDING node order
__global__ void k_emit(const int* __restrict__ flag, const int* __restrict__ pscan,
                       int* __restrict__ list) {
    __shared__ int sm[256];
    int t = threadIdx.x, g = blockIdx.x * 256 + t;
    int v = flag[g];
    sm[t] = v;
    __syncthreads();
    for (int s = 1; s < 256; s <<= 1) {
        int add = (t >= s) ? sm[t - s] : 0;
        __syncthreads();
        sm[t] += add;
        __syncthreads();
    }
    if (v) list[pscan[blockIdx.x] + sm[t] - 1] = g;
}

// ---------------- weight transpose + fp16 hi/lo split, PACKED MFMA-fragment layout -------
#define OFF_GCN 0                 // 5 x K=128 N=128
#define OFF_P0  81920             // combined mw0: K=128 N=512
#define OFF_M1  147456            // mw1: K=256 N=128
#define OFF_M2  180224            // mw2: K=128 N=128
#define OFF_M3  196608            // mw3: K=128 N=64
#define OFF_M4  204800            // mw4: K=64  N=64
#define TS_TOTAL 208896

__global__ void k_tsplit_all(const float* __restrict__ gw, const float* __restrict__ mw0,
                             const float* __restrict__ mw1, const float* __restrict__ mw2,
                             const float* __restrict__ mw3, const float* __restrict__ mw4,
                             _Float16* __restrict__ hi, _Float16* __restrict__ lo) {
    int idx = blockIdx.x * 256 + threadIdx.x;
    const float* src;
    int K, N, rel;
    bool p0 = false;
    if (idx < OFF_P0) {
        int L = (idx - OFF_GCN) >> 14; rel = (idx - OFF_GCN) & 16383;
        src = gw + L * 16384; K = 128; N = 128;
    } else if (idx < OFF_M1) {
        rel = idx - OFF_P0; src = mw0; K = 128; N = 512; p0 = true;
    } else if (idx < OFF_M2) {
        rel = idx - OFF_M1;  src = mw1; K = 256; N = 128;
    } else if (idx < OFF_M3) {
        rel = idx - OFF_M2;  src = mw2; K = 128; N = 128;
    } else if (idx < OFF_M4) {
        rel = idx - OFF_M3;  src = mw3; K = 128; N = 64;
    } else {
        rel = idx - OFF_M4;  src = mw4; K = 64;  N = 64;
    }
    int kblks = K >> 5;
    int j = rel & 7;
    int lane = (rel >> 3) & 63;
    int t2 = rel >> 9;
    int kblk = t2 % kblks;
    int ntile = t2 / kblks;
    int col = ntile * 16 + (lane & 15);
    int k = kblk * 32 + ((lane >> 4) << 3) + j;
    float f;
    if (p0) {
        f = (col < 256) ? src[k * 256 + col] : src[(k + 128) * 256 + (col - 256)];
    } else {
        f = src[k * N + col];
    }
    _Float16 h = (_Float16)f;
    hi[idx] = h;
    lo[idx] = (_Float16)(f - (float)h);
}

// ---------------- split-fp16 MFMA GEMM ----------------
// B pre-packed in fragment order (hi/lo). 3-product Markidis split, fp32 accumulate.
// GATHA: A-rows indirected through gmap. LISTM: cone slicing via sentinel list.
template <int NT_N, bool LEAKY, bool BIAS, bool P0SPLIT, bool FUSEA, bool GATHA, bool LISTM>
__launch_bounds__(256, 2)
__global__ void hgemm(const float* __restrict__ A,
                      const float* __restrict__ FA, const float* __restrict__ FB,
                      const _Float16* __restrict__ Bh, const _Float16* __restrict__ Bl,
                      const float* __restrict__ bias,
                      float* __restrict__ C, float* __restrict__ C2,
                      int N, int K, const int* __restrict__ gmap,
                      const int* __restrict__ listm) {
    if (LISTM) {
        if ((unsigned)listm[blockIdx.x * 128] >= (unsigned)NN) return;  // all-sentinel block
    }
    const int KB = K >> 5;
    const int lane = threadIdx.x & 63;
    const int wid = threadIdx.x >> 6;
    const int lm = lane & 15, lq = lane >> 4;
    const int m0 = blockIdx.x * 128 + wid * 32;
    const int n0t = blockIdx.y * NT_N;

    const float* arow[2];
    const float* brow[2];
#pragma unroll
    for (int mt = 0; mt < 2; mt++) {
        int row = m0 + mt * 16 + lm;
        if (FUSEA) {
            int b = row / (NQ * NQ);
            int rr = row - b * (NQ * NQ);
            int i = rr / NQ;
            int j = rr - i * NQ;
            arow[mt] = FA + (size_t)(b * NQ + i) * 256;
            brow[mt] = FB + (size_t)(b * NQ + j) * 256;
        } else if (GATHA) {
            arow[mt] = A + (size_t)gmap[row] * K;
        } else if (LISTM) {
            int lr = listm[row];
            lr = ((unsigned)lr < (unsigned)NN) ? lr : 0;
            arow[mt] = A + (size_t)lr * K;
        } else {
            arow[mt] = A + (size_t)row * K;
        }
    }

    floatx4 acc[2][NT_N];
#pragma unroll
    for (int mt = 0; mt < 2; mt++)
#pragma unroll
        for (int nt = 0; nt < NT_N; nt++) acc[mt][nt] = (floatx4)0.f;

    for (int kb = 0; kb < KB; kb++) {
        const int k0 = kb * 32 + lq * 8;
        half8 ahi[2], alo[2];
#pragma unroll
        for (int mt = 0; mt < 2; mt++) {
            floatx4 av0, av1;
            if (FUSEA) {
                floatx4 fa0 = *(const floatx4*)(arow[mt] + k0);
                floatx4 fa1 = *(const floatx4*)(arow[mt] + k0 + 4);
                floatx4 fb0 = *(const floatx4*)(brow[mt] + k0);
                floatx4 fb1 = *(const floatx4*)(brow[mt] + k0 + 4);
#pragma unroll
                for (int q = 0; q < 4; q++) {
                    av0[q] = lrelu(fa0[q] + fb0[q]);
                    av1[q] = lrelu(fa1[q] + fb1[q]);
                }
            } else {
                av0 = *(const floatx4*)(arow[mt] + k0);
                av1 = *(const floatx4*)(arow[mt] + k0 + 4);
            }
#pragma unroll
            for (int q = 0; q < 4; q++) {
                _Float16 h0 = (_Float16)av0[q];
                ahi[mt][q] = h0;
                alo[mt][q] = (_Float16)(av0[q] - (float)h0);
                _Float16 h1 = (_Float16)av1[q];
                ahi[mt][4 + q] = h1;
                alo[mt][4 + q] = (_Float16)(av1[q] - (float)h1);
            }
        }
#pragma unroll
        for (int nt = 0; nt < NT_N; nt++) {
            size_t boff = (((size_t)(n0t + nt) * KB + kb) * 64 + lane) * 8;
            half8 bhi = *(const half8*)(Bh + boff);
            half8 blo = *(const half8*)(Bl + boff);
#pragma unroll
            for (int mt = 0; mt < 2; mt++) {
                acc[mt][nt] = __builtin_amdgcn_mfma_f32_16x16x32_f16(ahi[mt], bhi, acc[mt][nt], 0, 0, 0);
                acc[mt][nt] = __builtin_amdgcn_mfma_f32_16x16x32_f16(ahi[mt], blo, acc[mt][nt], 0, 0, 0);
                acc[mt][nt] = __builtin_amdgcn_mfma_f32_16x16x32_f16(alo[mt], bhi, acc[mt][nt], 0, 0, 0);
            }
        }
    }

    // store-row mapping (C/D layout: col=lane&15, row=(lane>>4)*4+reg)
    int strow[2][4];
    bool svalid[2][4];
#pragma unroll
    for (int mt = 0; mt < 2; mt++)
#pragma unroll
        for (int r = 0; r < 4; r++) {
            int mlog = m0 + mt * 16 + lq * 4 + r;
            if (LISTM) {
                int sr = listm[mlog];
                svalid[mt][r] = (unsigned)sr < (unsigned)NN;
                strow[mt][r] = svalid[mt][r] ? sr : 0;
            } else {
                svalid[mt][r] = true;
                strow[mt][r] = mlog;
            }
        }

#pragma unroll
    for (int nt = 0; nt < NT_N; nt++) {
        int col = (n0t + nt) * 16 + lm;
        float bv = (BIAS || P0SPLIT) ? bias[col < 256 ? col : 0] : 0.f;
#pragma unroll
        for (int mt = 0; mt < 2; mt++) {
#pragma unroll
            for (int r = 0; r < 4; r++) {
                if (!svalid[mt][r]) continue;
                int row = strow[mt][r];
                float val = acc[mt][nt][r];
                if (P0SPLIT) {
                    if (col < 256) C[(size_t)row * 256 + col] = val + bv;
                    else C2[(size_t)row * 256 + col - 256] = val;
                } else {
                    if (BIAS) val += bv;
                    if (LEAKY) val = lrelu(val);
                    C[(size_t)row * N + col] = val;
                }
            }
        }
    }
}

// ---------------- layer-0 aggregation from the L2-resident token table ----------------
// hw0[n] == embW[x[n]] (only 1021 distinct rows). Gathers hit a 522 KB table.
// h[n] = lrelu(s2*embW[x[n]] + sum w*embW[x[src]] + bias) + emb[x[n]]
__global__ void k_agg0(const float* __restrict__ embW, const float* __restrict__ emb,
                       float* __restrict__ h,
                       const int4* __restrict__ meta, const int2* __restrict__ csre0,
                       const float* __restrict__ bias) {
    int tid = threadIdx.x;
    int sl = tid & 31;
    int p = blockIdx.x * 8 + (tid >> 5);
    int n0 = p * 2, n1 = n0 + 1;
    int4 m0 = meta[n0], m1 = meta[n1];
    float di0 = __int_as_float(m0.z), di1 = __int_as_float(m1.z);
    int off0 = m0.x, deg0 = m0.y;
    int off1 = m1.x, deg1 = m1.y;
    float4 v0 = ((const float4*)(embW + (size_t)m0.w * FEAT))[sl];
    float4 v1 = ((const float4*)(embW + (size_t)m1.w * FEAT))[sl];
    float4 ho0 = ((const float4*)(emb + (size_t)m0.w * FEAT))[sl];
    float4 ho1 = ((const float4*)(emb + (size_t)m1.w * FEAT))[sl];
    float s20 = di0 * di0, s21 = di1 * di1;
    float a0x = v0.x * s20, a0y = v0.y * s20, a0z = v0.z * s20, a0w = v0.w * s20;
    float a1x = v1.x * s21, a1y = v1.y * s21, a1z = v1.z * s21, a1w = v1.w * s21;
    int d0c = max(deg0 - 1, 0), d1c = max(deg1 - 1, 0);
    int dm = max(deg0, deg1);
    for (int e = 0; e < dm; e += 4) {
        int2 e00 = csre0[off0 + min(e,     d0c)];
        int2 e01 = csre0[off0 + min(e + 1, d0c)];
        int2 e02 = csre0[off0 + min(e + 2, d0c)];
        int2 e03 = csre0[off0 + min(e + 3, d0c)];
        int2 e10 = csre0[off1 + min(e,     d1c)];
        int2 e11 = csre0[off1 + min(e + 1, d1c)];
        int2 e12 = csre0[off1 + min(e + 2, d1c)];
        int2 e13 = csre0[off1 + min(e + 3, d1c)];
        float4 u00 = ((const float4*)(embW + (size_t)e00.x * FEAT))[sl];
        float4 u01 = ((const float4*)(embW + (size_t)e01.x * FEAT))[sl];
        float4 u02 = ((const float4*)(embW + (size_t)e02.x * FEAT))[sl];
        float4 u03 = ((const float4*)(embW + (size_t)e03.x * FEAT))[sl];
        float4 u10 = ((const float4*)(embW + (size_t)e10.x * FEAT))[sl];
        float4 u11 = ((const float4*)(embW + (size_t)e11.x * FEAT))[sl];
        float4 u12 = ((const float4*)(embW + (size_t)e12.x * FEAT))[sl];
        float4 u13 = ((const float4*)(embW + (size_t)e13.x * FEAT))[sl];
        float w00 = (e     < deg0) ? __int_as_float(e00.y) * di0 : 0.f;
        float w01 = (e + 1 < deg0) ? __int_as_float(e01.y) * di0 : 0.f;
        float w02 = (e + 2 < deg0) ? __int_as_float(e02.y) * di0 : 0.f;
        float w03 = (e + 3 < deg0) ? __int_as_float(e03.y) * di0 : 0.f;
        float w10 = (e     < deg1) ? __int_as_float(e10.y) * di1 : 0.f;
        float w11 = (e + 1 < deg1) ? __int_as_float(e11.y) * di1 : 0.f;
        float w12 = (e + 2 < deg1) ? __int_as_float(e12.y) * di1 : 0.f;
        float w13 = (e + 3 < deg1) ? __int_as_float(e13.y) * di1 : 0.f;
        a0x += u00.x * w00 + u01.x * w01 + u02.x * w02 + u03.x * w03;
        a0y += u00.y * w00 + u01.y * w01 + u02.y * w02 + u03.y * w03;
        a0z += u00.z * w00 + u01.z * w01 + u02.z * w02 + u03.z * w03;
        a0w += u00.w * w00 + u01.w * w01 + u02.w * w02 + u03.w * w03;
        a1x += u10.x * w10 + u11.x * w11 + u12.x * w12 + u13.x * w13;
        a1y += u10.y * w10 + u11.y * w11 + u12.y * w12 + u13.y * w13;
        a1z += u10.z * w10 + u11.z * w11 + u12.z * w12 + u13.z * w13;
        a1w += u10.w * w10 + u11.w * w11 + u12.w * w12 + u13.w * w13;
    }
    float4 bv = ((const float4*)bias)[sl];
    float4 r0, r1;
    r0.x = lrelu(a0x + bv.x) + ho0.x;
    r0.y = lrelu(a0y + bv.y) + ho0.y;
    r0.z = lrelu(a0z + bv.z) + ho0.z;
    r0.w = lrelu(a0w + bv.w) + ho0.w;
    r1.x = lrelu(a1x + bv.x) + ho1.x;
    r1.y = lrelu(a1y + bv.y) + ho1.y;
    r1.z = lrelu(a1z + bv.z) + ho1.z;
    r1.w = lrelu(a1w + bv.w) + ho1.w;
    ((float4*)(h + (size_t)n0 * FEAT))[sl] = r0;
    ((float4*)(h + (size_t)n1 * FEAT))[sl] = r1;
}

// ---------------- GCN aggregation + bias + leaky + residual, h IN PLACE ----------------
template <bool LIST>
__global__ void k_agg(const float* __restrict__ hw, float* __restrict__ h,
                      const int4* __restrict__ meta, const int2* __restrict__ csre,
                      const int* __restrict__ list,
                      const float* __restrict__ bias) {
    int tid = threadIdx.x;
    int sl = tid & 31;
    int p = blockIdx.x * 8 + (tid >> 5);
    int n0, n1;
    bool val0 = true, val1 = true;
    if (LIST) {
        n0 = list[p * 2];
        n1 = list[p * 2 + 1];
        val0 = (unsigned)n0 < (unsigned)NN;
        val1 = (unsigned)n1 < (unsigned)NN;
        n0 = val0 ? n0 : 0;
        n1 = val1 ? n1 : 0;
    } else {
        n0 = p * 2;
        n1 = n0 + 1;
    }
    int4 m0 = meta[n0], m1 = meta[n1];
    float di0 = __int_as_float(m0.z), di1 = __int_as_float(m1.z);
    int off0 = m0.x, deg0 = LIST ? (val0 ? m0.y : 0) : m0.y;
    int off1 = m1.x, deg1 = LIST ? (val1 ? m1.y : 0) : m1.y;
    float4 v0 = ((const float4*)(hw + (size_t)n0 * FEAT))[sl];
    float4 v1 = ((const float4*)(hw + (size_t)n1 * FEAT))[sl];
    float4 ho0 = ((const float4*)(h + (size_t)n0 * FEAT))[sl];
    float4 ho1 = ((const float4*)(h + (size_t)n1 * FEAT))[sl];
    float s20 = di0 * di0, s21 = di1 * di1;
    float a0x = v0.x * s20, a0y = v0.y * s20, a0z = v0.z * s20, a0w = v0.w * s20;
    float a1x = v1.x * s21, a1y = v1.y * s21, a1z = v1.z * s21, a1w = v1.w * s21;
    int d0c = max(deg0 - 1, 0), d1c = max(deg1 - 1, 0);
    int dm = max(deg0, deg1);
    for (int e = 0; e < dm; e += 4) {
        int2 e00 = csre[off0 + min(e,     d0c)];
        int2 e01 = csre[off0 + min(e + 1, d0c)];
        int2 e02 = csre[off0 + min(e + 2, d0c)];
        int2 e03 = csre[off0 + min(e + 3, d0c)];
        int2 e10 = csre[off1 + min(e,     d1c)];
        int2 e11 = csre[off1 + min(e + 1, d1c)];
        int2 e12 = csre[off1 + min(e + 2, d1c)];
        int2 e13 = csre[off1 + min(e + 3, d1c)];
        float4 u00 = ((const float4*)(hw + (size_t)e00.x * FEAT))[sl];
        float4 u01 = ((const float4*)(hw + (size_t)e01.x * FEAT))[sl];
        float4 u02 = ((const float4*)(hw + (size_t)e02.x * FEAT))[sl];
        float4 u03 = ((const float4*)(hw + (size_t)e03.x * FEAT))[sl];
        float4 u10 = ((const float4*)(hw + (size_t)e10.x * FEAT))[sl];
        float4 u11 = ((const float4*)(hw + (size_t)e11.x * FEAT))[sl];
        float4 u12 = ((const float4*)(hw + (size_t)e12.x * FEAT))[sl];
        float4 u13 = ((const float4*)(hw + (size_t)e13.x * FEAT))[sl];
        float w00 = (e     < deg0) ? __int_as_float(e00.y) * di0 : 0.f;
        float w01 = (e + 1 < deg0) ? __int_as_float(e01.y) * di0 : 0.f;
        float w02 = (e + 2 < deg0) ? __int_as_float(e02.y) * di0 : 0.f;
        float w03 = (e + 3 < deg0) ? __int_as_float(e03.y) * di0 : 0.f;
        float w10 = (e     < deg1) ? __int_as_float(e10.y) * di1 : 0.f;
        float w11 = (e + 1 < deg1) ? __int_as_float(e11.y) * di1 : 0.f;
        float w12 = (e + 2 < deg1) ? __int_as_float(e12.y) * di1 : 0.f;
        float w13 = (e + 3 < deg1) ? __int_as_float(e13.y) * di1 : 0.f;
        a0x += u00.x * w00 + u01.x * w01 + u02.x * w02 + u03.x * w03;
        a0y += u00.y * w00 + u01.y * w01 + u02.y * w02 + u03.y * w03;
        a0z += u00.z * w00 + u01.z * w01 + u02.z * w02 + u03.z * w03;
        a0w += u00.w * w00 + u01.w * w01 + u02.w * w02 + u03.w * w03;
        a1x += u10.x * w10 + u11.x * w11 + u12.x * w12 + u13.x * w13;
        a1y += u10.y * w10 + u11.y * w11 + u12.y * w12 + u13.y * w13;
        a1z += u10.z * w10 + u11.z * w11 + u12.z * w12 + u13.z * w13;
        a1w += u10.w * w10 + u11.w * w11 + u12.w * w12 + u13.w * w13;
    }
    float4 bv = ((const float4*)bias)[sl];
    float4 r0, r1;
    r0.x = lrelu(a0x + bv.x) + ho0.x;
    r0.y = lrelu(a0y + bv.y) + ho0.y;
    r0.z = lrelu(a0z + bv.z) + ho0.z;
    r0.w = lrelu(a0w + bv.w) + ho0.w;
    r1.x = lrelu(a1x + bv.x) + ho1.x;
    r1.y = lrelu(a1y + bv.y) + ho1.y;
    r1.z = lrelu(a1z + bv.z) + ho1.z;
    r1.w = lrelu(a1w + bv.w) + ho1.w;
    if (!LIST || val0) ((float4*)(h + (size_t)n0 * FEAT))[sl] = r0;
    if (!LIST || val1) ((float4*)(h + (size_t)n1 * FEAT))[sl] = r1;
}

// ---------------- selective final agg (layer 4): S0 rows only -> hq, no leaky ----------------
__global__ void k_aggq(const float* __restrict__ hw, const float* __restrict__ h,
                       const int4* __restrict__ meta, const int2* __restrict__ csre,
                       const float* __restrict__ gbias, float* __restrict__ hq) {
    int tid = threadIdx.x;
    int sl = tid & 31;
    int q = blockIdx.x * 8 + (tid >> 5);   // 0..2559
    int b = q / NQ, i = q - b * NQ;
    int node = b * (NQ * NLAY) + i;
    int4 m = meta[node];
    float di = __int_as_float(m.z);
    int off = m.x, deg = m.y;
    float s2 = di * di;
    float4 v = ((const float4*)(hw + (size_t)node * FEAT))[sl];
    float ax = v.x * s2, ay = v.y * s2, az = v.z * s2, aw = v.w * s2;
    int dc = max(deg - 1, 0);
    for (int e = 0; e < deg; e += 4) {
        int2 e0 = csre[off + min(e,     dc)];
        int2 e1 = csre[off + min(e + 1, dc)];
        int2 e2 = csre[off + min(e + 2, dc)];
        int2 e3 = csre[off + min(e + 3, dc)];
        float4 u0 = ((const float4*)(hw + (size_t)e0.x * FEAT))[sl];
        float4 u1 = ((const float4*)(hw + (size_t)e1.x * FEAT))[sl];
        float4 u2 = ((const float4*)(hw + (size_t)e2.x * FEAT))[sl];
        float4 u3 = ((const float4*)(hw + (size_t)e3.x * FEAT))[sl];
        float w0 = (e     < deg) ? __int_as_float(e0.y) * di : 0.f;
        float w1 = (e + 1 < deg) ? __int_as_float(e1.y) * di : 0.f;
        float w2 = (e + 2 < deg) ? __int_as_float(e2.y) * di : 0.f;
        float w3 = (e + 3 < deg) ? __int_as_float(e3.y) * di : 0.f;
        ax += u0.x * w0 + u1.x * w1 + u2.x * w2 + u3.x * w3;
        ay += u0.y * w0 + u1.y * w1 + u2.y * w2 + u3.y * w3;
        az += u0.z * w0 + u1.z * w1 + u2.z * w2 + u3.z * w3;
        aw += u0.w * w0 + u1.w * w1 + u2.w * w2 + u3.w * w3;
    }
    float4 bv = ((const float4*)gbias)[sl];
    float4 ho = ((const float4*)(h + (size_t)node * FEAT))[sl];
    ((float4*)(hq + (size_t)q * FEAT))[sl] =
        make_float4(ax + bv.x + ho.x, ay + bv.y + ho.y, az + bv.z + ho.z, aw + bv.w + ho.w);
}

// ---------------- last layer + symmetrize, one block per batch ----------------
__global__ void k_lastsym(const float* __restrict__ X4, const float* __restrict__ mw5,
                          const float* __restrict__ mb5, float* __restrict__ out) {
    __shared__ float w[64];
    __shared__ float sm[NQ * NQ];
    int t = threadIdx.x;
    if (t < 64) w[t] = mw5[t];
    __syncthreads();
    int b = blockIdx.x;
    for (int p = t; p < NQ * NQ; p += 256) {
        const float4* row = (const float4*)(X4 + (size_t)(b * NQ * NQ + p) * 64);
        float s = 0.f;
#pragma unroll
        for (int k4 = 0; k4 < 16; k4++) {
            float4 v = row[k4];
            s += v.x * w[k4 * 4] + v.y * w[k4 * 4 + 1] + v.z * w[k4 * 4 + 2] + v.w * w[k4 * 4 + 3];
        }
        sm[p] = s + mb5[0];
    }
    __syncthreads();
    for (int r = t; r < NQ * NQ; r += 256) {
        int i = r / NQ, j = r % NQ;
        out[(size_t)b * NQ * NQ + r] = 0.5f * (sm[r] + sm[j * NQ + i]);
    }
}

extern "C" void kernel_launch(void* const* d_in, const int* in_sizes, int n_in,
                              void* d_out, int out_size, void* d_ws, size_t ws_size,
                              hipStream_t stream) {
    const int* x = (const int*)d_in[0];
    const int* ei = (const int*)d_in[1];
    const int* e_src = ei;
    const int* e_dst = ei + NE;
    const float* emb = (const float*)d_in[2];
    const float* gw = (const float*)d_in[3];   // [5,128,128]
    const float* gb = (const float*)d_in[4];   // [5,128]
    const float* mw0 = (const float*)d_in[5];
    const float* mb0 = (const float*)d_in[6];
    const float* mw1 = (const float*)d_in[7];
    const float* mb1 = (const float*)d_in[8];
    const float* mw2 = (const float*)d_in[9];
    const float* mb2 = (const float*)d_in[10];
    const float* mw3 = (const float*)d_in[11];
    const float* mb3 = (const float*)d_in[12];
    const float* mw4 = (const float*)d_in[13];
    const float* mb4 = (const float*)d_in[14];
    const float* mw5 = (const float*)d_in[15];
    const float* mb5 = (const float*)d_in[16];
    float* out = (float*)d_out;

    float* wsf = (float*)d_ws;
    size_t o = 0;
    const size_t HSZ = (size_t)NN * FEAT;             // 16,711,680
    float* h  = wsf + o; o += HSZ;    // single in-place h buffer
    float* hw = wsf + o; o += HSZ;
    // zero-memset region: cnt, fill, flag1, flag2 (contiguous)
    int* cnt   = (int*)(wsf + o); o += NN;
    int* fill  = (int*)(wsf + o); o += NN;
    int* flag1 = (int*)(wsf + o); o += NN;
    int* flag2 = (int*)(wsf + o); o += NN;
    // 0xFF-memset region: list1, list2 (contiguous, sentinel -1)
    int* list1 = (int*)(wsf + o); o += NN;
    int* list2 = (int*)(wsf + o); o += NN;
    int* offs = (int*)(wsf + o); o += NN;
    float* dinv = wsf + o; o += NN;
    int4* meta = (int4*)(wsf + o); o += 4 * (size_t)NN;
    int2* csre  = (int2*)(wsf + o); o += 2 * (size_t)(NE + 8);  // +8 slop for deg-0 clamp
    int2* csre0 = (int2*)(wsf + o); o += 2 * (size_t)(NE + 8);  // token edges
    int* part  = (int*)(wsf + o); o += 512;
    int* pscan = (int*)(wsf + o); o += 512;
    int* idmap = (int*)(wsf + o); o += 1024;
    float* embW = wsf + o; o += (size_t)1024 * FEAT;          // emb@W0 table (1021 rows + pad)
    float* hq = wsf + o; o += (size_t)BATCH * NQ * FEAT;      // 327,680
    float* Abuf = wsf + o; o += (size_t)BATCH * NQ * 256;     // 655,360
    float* Bbuf = wsf + o; o += (size_t)BATCH * NQ * 256;     // 655,360
    _Float16* bt_hi = (_Float16*)(wsf + o); o += (TS_TOTAL + 2) / 2;
    _Float16* bt_lo = (_Float16*)(wsf + o); o += (TS_TOTAL + 2) / 2;
    // pair-phase aliases (hw, h dead after aggq)
    float* X1 = hw;                         // 51200*128
    float* X2 = hw + (size_t)NPAIR * 128;   // 51200*128
    float* X3 = h;                          // 51200*64
    float* X4 = h + (size_t)NPAIR * 64;     // 51200*64

    // --- weight transpose+split+pack ---
    k_tsplit_all<<<TS_TOTAL / 256, 256, 0, stream>>>(gw, mw0, mw1, mw2, mw3, mw4, bt_hi, bt_lo);

    // --- CSR build (deterministic scan chain) ---
    hipMemsetAsync(cnt, 0, 4 * NN * sizeof(int), stream);      // cnt+fill+flag1+flag2
    hipMemsetAsync(list1, 0xFF, 2 * NN * sizeof(int), stream); // list sentinels (-1)
    hipMemsetAsync(csre + NE, 0, 8 * sizeof(int2), stream);    // slop: node 0, weight 0
    hipMemsetAsync(csre0 + NE, 0, 8 * sizeof(int2), stream);   // slop: token 0, weight 0
    k_count<<<NE / 256, 256, 0, stream>>>(e_dst, cnt);
    k_partial<<<NB, 256, 0, stream>>>(cnt, part);
    k_scanpart<<<1, 512, 0, stream>>>(part, pscan, NB);
    k_offsets<<<NB, 256, 0, stream>>>(cnt, pscan, x, offs, dinv, meta, idmap);
    k_fill<<<NE / 256, 256, 0, stream>>>(e_src, e_dst, offs, fill, dinv, x, csre, csre0);

    // --- dependency-cone lists S1, S2 (sentinel-padded, ascending order) ---
    k_markS1<<<(BATCH * NQ + 255) / 256, 256, 0, stream>>>(meta, csre, flag1);
    k_partial<<<NB, 256, 0, stream>>>(flag1, part);
    k_scanpart<<<1, 512, 0, stream>>>(part, pscan, NB);
    k_emit<<<NB, 256, 0, stream>>>(flag1, pscan, list1);
    k_markS2<<<NB, 256, 0, stream>>>(meta, csre, list1, flag2);
    k_partial<<<NB, 256, 0, stream>>>(flag2, part);
    k_scanpart<<<1, 512, 0, stream>>>(part, pscan, NB);
    k_emit<<<NB, 256, 0, stream>>>(flag2, pscan, list2);

    // --- layer 0 via token table: embW = emb@W0 (1021 rows, clamped id map) ---
    hgemm<8, false, false, false, false, true, false><<<dim3(8, 1), 256, 0, stream>>>(
        emb, nullptr, nullptr, bt_hi + OFF_GCN, bt_lo + OFF_GCN,
        nullptr, embW, nullptr, FEAT, FEAT, idmap, nullptr);
    // agg0 from the L2-resident table: gathers embW[x[src]], residual emb[x[n]] -> h
    k_agg0<<<NN / 16, 256, 0, stream>>>(embW, emb, h, meta, csre0, gb + 0 * FEAT);

    // --- layer 1: full gemm + full agg (h in place) ---
    hgemm<8, false, false, false, false, false, false><<<dim3(NN / 128, 1), 256, 0, stream>>>(
        h, nullptr, nullptr, bt_hi + OFF_GCN + 1 * 16384, bt_lo + OFF_GCN + 1 * 16384,
        nullptr, hw, nullptr, FEAT, FEAT, nullptr, nullptr);
    k_agg<false><<<NN / 16, 256, 0, stream>>>(hw, h, meta, csre, nullptr, gb + 1 * FEAT);

    // --- layer 2: full gemm + agg@S2 (h in place; non-S2 rows keep h2 — never read) ---
    hgemm<8, false, false, false, false, false, false><<<dim3(NN / 128, 1), 256, 0, stream>>>(
        h, nullptr, nullptr, bt_hi + OFF_GCN + 2 * 16384, bt_lo + OFF_GCN + 2 * 16384,
        nullptr, hw, nullptr, FEAT, FEAT, nullptr, nullptr);
    k_agg<true><<<NN / 16, 256, 0, stream>>>(hw, h, meta, csre, list2, gb + 2 * FEAT);

    // --- layer 3: gemm@S2 + agg@S1 ---
    hgemm<8, false, false, false, false, false, true><<<dim3(NN / 128, 1), 256, 0, stream>>>(
        h, nullptr, nullptr, bt_hi + OFF_GCN + 3 * 16384, bt_lo + OFF_GCN + 3 * 16384,
        nullptr, hw, nullptr, FEAT, FEAT, nullptr, list2);
    k_agg<true><<<NN / 16, 256, 0, stream>>>(hw, h, meta, csre, list1, gb + 3 * FEAT);

    // --- layer 4: gemm@S1 + selective agg@S0 -> hq ---
    hgemm<8, false, false, false, false, false, true><<<dim3(NN / 128, 1), 256, 0, stream>>>(
        h, nullptr, nullptr, bt_hi + OFF_GCN + 4 * 16384, bt_lo + OFF_GCN + 4 * 16384,
        nullptr, hw, nullptr, FEAT, FEAT, nullptr, list1);
    k_aggq<<<(BATCH * NQ) / 8, 256, 0, stream>>>(hw, h, meta, csre,
                                                 gb + 4 * (size_t)FEAT, hq);

    // --- pair MLP ---
    // combined P0: Abuf = hq@mw0_top + mb0 ; Bbuf = hq@mw0_bot   (M=2560, K=128, N=512)
    hgemm<8, false, false, true, false, false, false><<<dim3(20, 4), 256, 0, stream>>>(
        hq, nullptr, nullptr, bt_hi + OFF_P0, bt_lo + OFF_P0, mb0, Abuf, Bbuf, 512, 128,
        nullptr, nullptr);
    // L1 fused pair0: A[p,:] = lrelu(Abuf[b,i,:] + Bbuf[b,j,:]) ; [51200,256]@[256,128]
    hgemm<8, true, true, false, true, false, false><<<dim3(NPAIR / 128, 1), 256, 0, stream>>>(
        nullptr, Abuf, Bbuf, bt_hi + OFF_M1, bt_lo + OFF_M1, mb1, X1, nullptr, 128, 256,
        nullptr, nullptr);
    // L2: [51200,128] @ [128,128]
    hgemm<8, true, true, false, false, false, false><<<dim3(NPAIR / 128, 1), 256, 0, stream>>>(
        X1, nullptr, nullptr, bt_hi + OFF_M2, bt_lo + OFF_M2, mb2, X2, nullptr, 128, 128,
        nullptr, nullptr);
    // L3: [51200,128] @ [128,64]
    hgemm<4, true, true, false, false, false, false><<<dim3(NPAIR / 128, 1), 256, 0, stream>>>(
        X2, nullptr, nullptr, bt_hi + OFF_M3, bt_lo + OFF_M3, mb3, X3, nullptr, 64, 128,
        nullptr, nullptr);
    // L4: [51200,64] @ [64,64]
    hgemm<4, true, true, false, false, false, false><<<dim3(NPAIR / 128, 1), 256, 0, stream>>>(
        X3, nullptr, nullptr, bt_hi + OFF_M4, bt_lo + OFF_M4, mb4, X4, nullptr, 64, 64,
        nullptr, nullptr);
    // L5 + symmetrize
    k_lastsym<<<BATCH, 256, 0, stream>>>(X4, mw5, mb5, out);
}

// Round 14
// 545.971 us; speedup vs baseline: 1.2577x; 1.0044x over previous
//
#include <hip/hip_runtime.h>
#include <hip/hip_bf16.h>

#define NQ 20
#define NLAY 51            // N_LAYER+1
#define FEAT 128
#define BATCH 128
#define NN (BATCH * NQ * NLAY)   // 130560
#define NE 524288
#define NPAIR (BATCH * NQ * NQ)  // 51200
#define NB (NN / 256)            // 510
#define VOCAB 1021

typedef _Float16 half8 __attribute__((ext_vector_type(8)));
typedef float floatx4 __attribute__((ext_vector_type(4)));

__device__ __forceinline__ float lrelu(float v) { return v >= 0.f ? v : 0.01f * v; }

// ---------------- CSR build ----------------
__global__ void k_count(const int* __restrict__ dst, int* __restrict__ cnt) {
    int e = blockIdx.x * 256 + threadIdx.x;
    atomicAdd(&cnt[dst[e]], 1);
}

// offsets via block-scan + global cursor (R7-proven; segment placement order irrelevant).
// Also: dinv, packed meta {off, deg, dinv_bits, x[node]}, S0 seed into flag1, idmap.
__global__ void k_offsets(const int* __restrict__ cnt, const int* __restrict__ x,
                          int* __restrict__ offs, float* __restrict__ dinv,
                          int4* __restrict__ meta, int* __restrict__ cursor,
                          int* __restrict__ flag1, int* __restrict__ idmap) {
    __shared__ int sm[256];
    __shared__ int sbase;
    int t = threadIdx.x, g = blockIdx.x * 256 + t;
    int v = cnt[g];
    sm[t] = v;
    __syncthreads();
    for (int s = 1; s < 256; s <<= 1) {
        int add = (t >= s) ? sm[t - s] : 0;
        __syncthreads();
        sm[t] += add;
        __syncthreads();
    }
    if (t == 255) sbase = atomicAdd(cursor, sm[255]);
    __syncthreads();
    int off = sbase + sm[t] - v;
    float di = rsqrtf((float)(v + 1));  // +1 self loop
    offs[g] = off;
    dinv[g] = di;
    meta[g] = make_int4(off, v, __float_as_int(di), x[g]);
    if (g % (NQ * NLAY) < NQ) flag1[g] = 1;      // S0 seed
    if (g < 1024) idmap[g] = min(g, VOCAB - 1);
}

// fill packed edges {src, norm_bits} and token edges {x[src], norm_bits};
// norm = dinv[src]*dinv[dst] (full GCN edge weight). Also mark flag1[src] for S0 dsts.
__global__ void k_fill(const int* __restrict__ src, const int* __restrict__ dst,
                       const int* __restrict__ offs, int* __restrict__ fill,
                       const float* __restrict__ dinv, const int* __restrict__ x,
                       int2* __restrict__ csre, int2* __restrict__ csre0,
                       int* __restrict__ flag1) {
    int e = blockIdx.x * 256 + threadIdx.x;
    int d = dst[e];
    int s = src[e];
    int pos = offs[d] + atomicAdd(&fill[d], 1);
    int wb = __float_as_int(dinv[s] * dinv[d]);
    csre[pos] = make_int2(s, wb);
    csre0[pos] = make_int2(x[s], wb);
    if (d % (NQ * NLAY) < NQ) flag1[s] = 1;      // src feeds an S0 node
}

// S1 pass: emit list1 (cursor-packed, chunk-ascending) + mark flag2 = S1 ∪ N(S1)
__global__ void k_s1pass(const int* __restrict__ flag1, const int4* __restrict__ meta,
                         const int2* __restrict__ csre, int* __restrict__ cur1,
                         int* __restrict__ list1, int* __restrict__ flag2) {
    __shared__ int sm[256];
    __shared__ int sbase;
    int t = threadIdx.x, g = blockIdx.x * 256 + t;
    int v = flag1[g];
    sm[t] = v;
    __syncthreads();
    for (int s = 1; s < 256; s <<= 1) {
        int add = (t >= s) ? sm[t - s] : 0;
        __syncthreads();
        sm[t] += add;
        __syncthreads();
    }
    if (t == 255) sbase = atomicAdd(cur1, sm[255]);
    __syncthreads();
    if (v) {
        list1[sbase + sm[t] - 1] = g;
        flag2[g] = 1;
        int4 m = meta[g];
        for (int e = 0; e < m.y; e++) flag2[csre[m.x + e].x] = 1;   // benign races
    }
}

// emit list2 from flag2 (cursor-packed)
__global__ void k_emit2(const int* __restrict__ flag2, int* __restrict__ cur2,
                        int* __restrict__ list2) {
    __shared__ int sm[256];
    __shared__ int sbase;
    int t = threadIdx.x, g = blockIdx.x * 256 + t;
    int v = flag2[g];
    sm[t] = v;
    __syncthreads();
    for (int s = 1; s < 256; s <<= 1) {
        int add = (t >= s) ? sm[t - s] : 0;
        __syncthreads();
        sm[t] += add;
        __syncthreads();
    }
    if (t == 255) sbase = atomicAdd(cur2, sm[255]);
    __syncthreads();
    if (v) list2[sbase + sm[t] - 1] = g;
}

// ---------------- weight transpose + fp16 hi/lo split, PACKED MFMA-fragment layout -------
#define OFF_GCN 0                 // 5 x K=128 N=128
#define OFF_P0  81920             // combined mw0: K=128 N=512
#define OFF_M1  147456            // mw1: K=256 N=128
#define OFF_M2  180224            // mw2: K=128 N=128
#define OFF_M3  196608            // mw3: K=128 N=64
#define OFF_M4  204800            // mw4: K=64  N=64
#define TS_TOTAL 208896

__global__ void k_tsplit_all(const float* __restrict__ gw, const float* __restrict__ mw0,
                             const float* __restrict__ mw1, const float* __restrict__ mw2,
                             const float* __restrict__ mw3, const float* __restrict__ mw4,
                             _Float16* __restrict__ hi, _Float16* __restrict__ lo) {
    int idx = blockIdx.x * 256 + threadIdx.x;
    const float* src;
    int K, N, rel;
    bool p0 = false;
    if (idx < OFF_P0) {
        int L = (idx - OFF_GCN) >> 14; rel = (idx - OFF_GCN) & 16383;
        src = gw + L * 16384; K = 128; N = 128;
    } else if (idx < OFF_M1) {
        rel = idx - OFF_P0; src = mw0; K = 128; N = 512; p0 = true;
    } else if (idx < OFF_M2) {
        rel = idx - OFF_M1;  src = mw1; K = 256; N = 128;
    } else if (idx < OFF_M3) {
        rel = idx - OFF_M2;  src = mw2; K = 128; N = 128;
    } else if (idx < OFF_M4) {
        rel = idx - OFF_M3;  src = mw3; K = 128; N = 64;
    } else {
        rel = idx - OFF_M4;  src = mw4; K = 64;  N = 64;
    }
    int kblks = K >> 5;
    int j = rel & 7;
    int lane = (rel >> 3) & 63;
    int t2 = rel >> 9;
    int kblk = t2 % kblks;
    int ntile = t2 / kblks;
    int col = ntile * 16 + (lane & 15);
    int k = kblk * 32 + ((lane >> 4) << 3) + j;
    float f;
    if (p0) {
        f = (col < 256) ? src[k * 256 + col] : src[(k + 128) * 256 + (col - 256)];
    } else {
        f = src[k * N + col];
    }
    _Float16 h = (_Float16)f;
    hi[idx] = h;
    lo[idx] = (_Float16)(f - (float)h);
}

// ---------------- split-fp16 MFMA GEMM ----------------
template <int NT_N, bool LEAKY, bool BIAS, bool P0SPLIT, bool FUSEA, bool GATHA, bool LISTM>
__launch_bounds__(256, 2)
__global__ void hgemm(const float* __restrict__ A,
                      const float* __restrict__ FA, const float* __restrict__ FB,
                      const _Float16* __restrict__ Bh, const _Float16* __restrict__ Bl,
                      const float* __restrict__ bias,
                      float* __restrict__ C, float* __restrict__ C2,
                      int N, int K, const int* __restrict__ gmap,
                      const int* __restrict__ listm) {
    if (LISTM) {
        if ((unsigned)listm[blockIdx.x * 128] >= (unsigned)NN) return;  // all-sentinel block
    }
    const int KB = K >> 5;
    const int lane = threadIdx.x & 63;
    const int wid = threadIdx.x >> 6;
    const int lm = lane & 15, lq = lane >> 4;
    const int m0 = blockIdx.x * 128 + wid * 32;
    const int n0t = blockIdx.y * NT_N;

    const float* arow[2];
    const float* brow[2];
#pragma unroll
    for (int mt = 0; mt < 2; mt++) {
        int row = m0 + mt * 16 + lm;
        if (FUSEA) {
            int b = row / (NQ * NQ);
            int rr = row - b * (NQ * NQ);
            int i = rr / NQ;
            int j = rr - i * NQ;
            arow[mt] = FA + (size_t)(b * NQ + i) * 256;
            brow[mt] = FB + (size_t)(b * NQ + j) * 256;
        } else if (GATHA) {
            arow[mt] = A + (size_t)gmap[row] * K;
        } else if (LISTM) {
            int lr = listm[row];
            lr = ((unsigned)lr < (unsigned)NN) ? lr : 0;
            arow[mt] = A + (size_t)lr * K;
        } else {
            arow[mt] = A + (size_t)row * K;
        }
    }

    floatx4 acc[2][NT_N];
#pragma unroll
    for (int mt = 0; mt < 2; mt++)
#pragma unroll
        for (int nt = 0; nt < NT_N; nt++) acc[mt][nt] = (floatx4)0.f;

    for (int kb = 0; kb < KB; kb++) {
        const int k0 = kb * 32 + lq * 8;
        half8 ahi[2], alo[2];
#pragma unroll
        for (int mt = 0; mt < 2; mt++) {
            floatx4 av0, av1;
            if (FUSEA) {
                floatx4 fa0 = *(const floatx4*)(arow[mt] + k0);
                floatx4 fa1 = *(const floatx4*)(arow[mt] + k0 + 4);
                floatx4 fb0 = *(const floatx4*)(brow[mt] + k0);
                floatx4 fb1 = *(const floatx4*)(brow[mt] + k0 + 4);
#pragma unroll
                for (int q = 0; q < 4; q++) {
                    av0[q] = lrelu(fa0[q] + fb0[q]);
                    av1[q] = lrelu(fa1[q] + fb1[q]);
                }
            } else {
                av0 = *(const floatx4*)(arow[mt] + k0);
                av1 = *(const floatx4*)(arow[mt] + k0 + 4);
            }
#pragma unroll
            for (int q = 0; q < 4; q++) {
                _Float16 h0 = (_Float16)av0[q];
                ahi[mt][q] = h0;
                alo[mt][q] = (_Float16)(av0[q] - (float)h0);
                _Float16 h1 = (_Float16)av1[q];
                ahi[mt][4 + q] = h1;
                alo[mt][4 + q] = (_Float16)(av1[q] - (float)h1);
            }
        }
#pragma unroll
        for (int nt = 0; nt < NT_N; nt++) {
            size_t boff = (((size_t)(n0t + nt) * KB + kb) * 64 + lane) * 8;
            half8 bhi = *(const half8*)(Bh + boff);
            half8 blo = *(const half8*)(Bl + boff);
#pragma unroll
            for (int mt = 0; mt < 2; mt++) {
                acc[mt][nt] = __builtin_amdgcn_mfma_f32_16x16x32_f16(ahi[mt], bhi, acc[mt][nt], 0, 0, 0);
                acc[mt][nt] = __builtin_amdgcn_mfma_f32_16x16x32_f16(ahi[mt], blo, acc[mt][nt], 0, 0, 0);
                acc[mt][nt] = __builtin_amdgcn_mfma_f32_16x16x32_f16(alo[mt], bhi, acc[mt][nt], 0, 0, 0);
            }
        }
    }

    // store-row mapping (C/D layout: col=lane&15, row=(lane>>4)*4+reg)
    int strow[2][4];
    bool svalid[2][4];
#pragma unroll
    for (int mt = 0; mt < 2; mt++)
#pragma unroll
        for (int r = 0; r < 4; r++) {
            int mlog = m0 + mt * 16 + lq * 4 + r;
            if (LISTM) {
                int sr = listm[mlog];
                svalid[mt][r] = (unsigned)sr < (unsigned)NN;
                strow[mt][r] = svalid[mt][r] ? sr : 0;
            } else {
                svalid[mt][r] = true;
                strow[mt][r] = mlog;
            }
        }

#pragma unroll
    for (int nt = 0; nt < NT_N; nt++) {
        int col = (n0t + nt) * 16 + lm;
        float bv = (BIAS || P0SPLIT) ? bias[col < 256 ? col : 0] : 0.f;
#pragma unroll
        for (int mt = 0; mt < 2; mt++) {
#pragma unroll
            for (int r = 0; r < 4; r++) {
                if (!svalid[mt][r]) continue;
                int row = strow[mt][r];
                float val = acc[mt][nt][r];
                if (P0SPLIT) {
                    if (col < 256) C[(size_t)row * 256 + col] = val + bv;
                    else C2[(size_t)row * 256 + col - 256] = val;
                } else {
                    if (BIAS) val += bv;
                    if (LEAKY) val = lrelu(val);
                    C[(size_t)row * N + col] = val;
                }
            }
        }
    }
}

// ---------------- layer-0 aggregation from the L2-resident token table ----------------
__global__ void k_agg0(const float* __restrict__ embW, const float* __restrict__ emb,
                       float* __restrict__ h,
                       const int4* __restrict__ meta, const int2* __restrict__ csre0,
                       const float* __restrict__ bias) {
    int tid = threadIdx.x;
    int sl = tid & 31;
    int p = blockIdx.x * 8 + (tid >> 5);
    int n0 = p * 2, n1 = n0 + 1;
    int4 m0 = meta[n0], m1 = meta[n1];
    float di0 = __int_as_float(m0.z), di1 = __int_as_float(m1.z);
    int off0 = m0.x, deg0 = m0.y;
    int off1 = m1.x, deg1 = m1.y;
    float4 v0 = ((const float4*)(embW + (size_t)m0.w * FEAT))[sl];
    float4 v1 = ((const float4*)(embW + (size_t)m1.w * FEAT))[sl];
    float4 ho0 = ((const float4*)(emb + (size_t)m0.w * FEAT))[sl];
    float4 ho1 = ((const float4*)(emb + (size_t)m1.w * FEAT))[sl];
    float s20 = di0 * di0, s21 = di1 * di1;
    float a0x = v0.x * s20, a0y = v0.y * s20, a0z = v0.z * s20, a0w = v0.w * s20;
    float a1x = v1.x * s21, a1y = v1.y * s21, a1z = v1.z * s21, a1w = v1.w * s21;
    int d0c = max(deg0 - 1, 0), d1c = max(deg1 - 1, 0);
    int dm = max(deg0, deg1);
    for (int e = 0; e < dm; e += 4) {
        int2 e00 = csre0[off0 + min(e,     d0c)];
        int2 e01 = csre0[off0 + min(e + 1, d0c)];
        int2 e02 = csre0[off0 + min(e + 2, d0c)];
        int2 e03 = csre0[off0 + min(e + 3, d0c)];
        int2 e10 = csre0[off1 + min(e,     d1c)];
        int2 e11 = csre0[off1 + min(e + 1, d1c)];
        int2 e12 = csre0[off1 + min(e + 2, d1c)];
        int2 e13 = csre0[off1 + min(e + 3, d1c)];
        float4 u00 = ((const float4*)(embW + (size_t)e00.x * FEAT))[sl];
        float4 u01 = ((const float4*)(embW + (size_t)e01.x * FEAT))[sl];
        float4 u02 = ((const float4*)(embW + (size_t)e02.x * FEAT))[sl];
        float4 u03 = ((const float4*)(embW + (size_t)e03.x * FEAT))[sl];
        float4 u10 = ((const float4*)(embW + (size_t)e10.x * FEAT))[sl];
        float4 u11 = ((const float4*)(embW + (size_t)e11.x * FEAT))[sl];
        float4 u12 = ((const float4*)(embW + (size_t)e12.x * FEAT))[sl];
        float4 u13 = ((const float4*)(embW + (size_t)e13.x * FEAT))[sl];
        float w00 = (e     < deg0) ? __int_as_float(e00.y) : 0.f;
        float w01 = (e + 1 < deg0) ? __int_as_float(e01.y) : 0.f;
        float w02 = (e + 2 < deg0) ? __int_as_float(e02.y) : 0.f;
        float w03 = (e + 3 < deg0) ? __int_as_float(e03.y) : 0.f;
        float w10 = (e     < deg1) ? __int_as_float(e10.y) : 0.f;
        float w11 = (e + 1 < deg1) ? __int_as_float(e11.y) : 0.f;
        float w12 = (e + 2 < deg1) ? __int_as_float(e12.y) : 0.f;
        float w13 = (e + 3 < deg1) ? __int_as_float(e13.y) : 0.f;
        a0x += u00.x * w00 + u01.x * w01 + u02.x * w02 + u03.x * w03;
        a0y += u00.y * w00 + u01.y * w01 + u02.y * w02 + u03.y * w03;
        a0z += u00.z * w00 + u01.z * w01 + u02.z * w02 + u03.z * w03;
        a0w += u00.w * w00 + u01.w * w01 + u02.w * w02 + u03.w * w03;
        a1x += u10.x * w10 + u11.x * w11 + u12.x * w12 + u13.x * w13;
        a1y += u10.y * w10 + u11.y * w11 + u12.y * w12 + u13.y * w13;
        a1z += u10.z * w10 + u11.z * w11 + u12.z * w12 + u13.z * w13;
        a1w += u10.w * w10 + u11.w * w11 + u12.w * w12 + u13.w * w13;
    }
    float4 bv = ((const float4*)bias)[sl];
    float4 r0, r1;
    r0.x = lrelu(a0x + bv.x) + ho0.x;
    r0.y = lrelu(a0y + bv.y) + ho0.y;
    r0.z = lrelu(a0z + bv.z) + ho0.z;
    r0.w = lrelu(a0w + bv.w) + ho0.w;
    r1.x = lrelu(a1x + bv.x) + ho1.x;
    r1.y = lrelu(a1y + bv.y) + ho1.y;
    r1.z = lrelu(a1z + bv.z) + ho1.z;
    r1.w = lrelu(a1w + bv.w) + ho1.w;
    ((float4*)(h + (size_t)n0 * FEAT))[sl] = r0;
    ((float4*)(h + (size_t)n1 * FEAT))[sl] = r1;
}

// ---------------- GCN aggregation + bias + leaky + residual, h IN PLACE ----------------
template <bool LIST>
__global__ void k_agg(const float* __restrict__ hw, float* __restrict__ h,
                      const int4* __restrict__ meta, const int2* __restrict__ csre,
                      const int* __restrict__ list,
                      const float* __restrict__ bias) {
    int tid = threadIdx.x;
    int sl = tid & 31;
    int p = blockIdx.x * 8 + (tid >> 5);
    int n0, n1;
    bool val0 = true, val1 = true;
    if (LIST) {
        n0 = list[p * 2];
        n1 = list[p * 2 + 1];
        val0 = (unsigned)n0 < (unsigned)NN;
        val1 = (unsigned)n1 < (unsigned)NN;
        n0 = val0 ? n0 : 0;
        n1 = val1 ? n1 : 0;
    } else {
        n0 = p * 2;
        n1 = n0 + 1;
    }
    int4 m0 = meta[n0], m1 = meta[n1];
    float di0 = __int_as_float(m0.z), di1 = __int_as_float(m1.z);
    int off0 = m0.x, deg0 = LIST ? (val0 ? m0.y : 0) : m0.y;
    int off1 = m1.x, deg1 = LIST ? (val1 ? m1.y : 0) : m1.y;
    float4 v0 = ((const float4*)(hw + (size_t)n0 * FEAT))[sl];
    float4 v1 = ((const float4*)(hw + (size_t)n1 * FEAT))[sl];
    float4 ho0 = ((const float4*)(h + (size_t)n0 * FEAT))[sl];
    float4 ho1 = ((const float4*)(h + (size_t)n1 * FEAT))[sl];
    float s20 = di0 * di0, s21 = di1 * di1;
    float a0x = v0.x * s20, a0y = v0.y * s20, a0z = v0.z * s20, a0w = v0.w * s20;
    float a1x = v1.x * s21, a1y = v1.y * s21, a1z = v1.z * s21, a1w = v1.w * s21;
    int d0c = max(deg0 - 1, 0), d1c = max(deg1 - 1, 0);
    int dm = max(deg0, deg1);
    for (int e = 0; e < dm; e += 4) {
        int2 e00 = csre[off0 + min(e,     d0c)];
        int2 e01 = csre[off0 + min(e + 1, d0c)];
        int2 e02 = csre[off0 + min(e + 2, d0c)];
        int2 e03 = csre[off0 + min(e + 3, d0c)];
        int2 e10 = csre[off1 + min(e,     d1c)];
        int2 e11 = csre[off1 + min(e + 1, d1c)];
        int2 e12 = csre[off1 + min(e + 2, d1c)];
        int2 e13 = csre[off1 + min(e + 3, d1c)];
        float4 u00 = ((const float4*)(hw + (size_t)e00.x * FEAT))[sl];
        float4 u01 = ((const float4*)(hw + (size_t)e01.x * FEAT))[sl];
        float4 u02 = ((const float4*)(hw + (size_t)e02.x * FEAT))[sl];
        float4 u03 = ((const float4*)(hw + (size_t)e03.x * FEAT))[sl];
        float4 u10 = ((const float4*)(hw + (size_t)e10.x * FEAT))[sl];
        float4 u11 = ((const float4*)(hw + (size_t)e11.x * FEAT))[sl];
        float4 u12 = ((const float4*)(hw + (size_t)e12.x * FEAT))[sl];
        float4 u13 = ((const float4*)(hw + (size_t)e13.x * FEAT))[sl];
        float w00 = (e     < deg0) ? __int_as_float(e00.y) : 0.f;
        float w01 = (e + 1 < deg0) ? __int_as_float(e01.y) : 0.f;
        float w02 = (e + 2 < deg0) ? __int_as_float(e02.y) : 0.f;
        float w03 = (e + 3 < deg0) ? __int_as_float(e03.y) : 0.f;
        float w10 = (e     < deg1) ? __int_as_float(e10.y) : 0.f;
        float w11 = (e + 1 < deg1) ? __int_as_float(e11.y) : 0.f;
        float w12 = (e + 2 < deg1) ? __int_as_float(e12.y) : 0.f;
        float w13 = (e + 3 < deg1) ? __int_as_float(e13.y) : 0.f;
        a0x += u00.x * w00 + u01.x * w01 + u02.x * w02 + u03.x * w03;
        a0y += u00.y * w00 + u01.y * w01 + u02.y * w02 + u03.y * w03;
        a0z += u00.z * w00 + u01.z * w01 + u02.z * w02 + u03.z * w03;
        a0w += u00.w * w00 + u01.w * w01 + u02.w * w02 + u03.w * w03;
        a1x += u10.x * w10 + u11.x * w11 + u12.x * w12 + u13.x * w13;
        a1y += u10.y * w10 + u11.y * w11 + u12.y * w12 + u13.y * w13;
        a1z += u10.z * w10 + u11.z * w11 + u12.z * w12 + u13.z * w13;
        a1w += u10.w * w10 + u11.w * w11 + u12.w * w12 + u13.w * w13;
    }
    float4 bv = ((const float4*)bias)[sl];
    float4 r0, r1;
    r0.x = lrelu(a0x + bv.x) + ho0.x;
    r0.y = lrelu(a0y + bv.y) + ho0.y;
    r0.z = lrelu(a0z + bv.z) + ho0.z;
    r0.w = lrelu(a0w + bv.w) + ho0.w;
    r1.x = lrelu(a1x + bv.x) + ho1.x;
    r1.y = lrelu(a1y + bv.y) + ho1.y;
    r1.z = lrelu(a1z + bv.z) + ho1.z;
    r1.w = lrelu(a1w + bv.w) + ho1.w;
    if (!LIST || val0) ((float4*)(h + (size_t)n0 * FEAT))[sl] = r0;
    if (!LIST || val1) ((float4*)(h + (size_t)n1 * FEAT))[sl] = r1;
}

// ---------------- selective final agg (layer 4): S0 rows only -> hq, no leaky ----------------
__global__ void k_aggq(const float* __restrict__ hw, const float* __restrict__ h,
                       const int4* __restrict__ meta, const int2* __restrict__ csre,
                       const float* __restrict__ gbias, float* __restrict__ hq) {
    int tid = threadIdx.x;
    int sl = tid & 31;
    int q = blockIdx.x * 8 + (tid >> 5);   // 0..2559
    int b = q / NQ, i = q - b * NQ;
    int node = b * (NQ * NLAY) + i;
    int4 m = meta[node];
    float di = __int_as_float(m.z);
    int off = m.x, deg = m.y;
    float s2 = di * di;
    float4 v = ((const float4*)(hw + (size_t)node * FEAT))[sl];
    float ax = v.x * s2, ay = v.y * s2, az = v.z * s2, aw = v.w * s2;
    int dc = max(deg - 1, 0);
    for (int e = 0; e < deg; e += 4) {
        int2 e0 = csre[off + min(e,     dc)];
        int2 e1 = csre[off + min(e + 1, dc)];
        int2 e2 = csre[off + min(e + 2, dc)];
        int2 e3 = csre[off + min(e + 3, dc)];
        float4 u0 = ((const float4*)(hw + (size_t)e0.x * FEAT))[sl];
        float4 u1 = ((const float4*)(hw + (size_t)e1.x * FEAT))[sl];
        float4 u2 = ((const float4*)(hw + (size_t)e2.x * FEAT))[sl];
        float4 u3 = ((const float4*)(hw + (size_t)e3.x * FEAT))[sl];
        float w0 = (e     < deg) ? __int_as_float(e0.y) : 0.f;
        float w1 = (e + 1 < deg) ? __int_as_float(e1.y) : 0.f;
        float w2 = (e + 2 < deg) ? __int_as_float(e2.y) : 0.f;
        float w3 = (e + 3 < deg) ? __int_as_float(e3.y) : 0.f;
        ax += u0.x * w0 + u1.x * w1 + u2.x * w2 + u3.x * w3;
        ay += u0.y * w0 + u1.y * w1 + u2.y * w2 + u3.y * w3;
        az += u0.z * w0 + u1.z * w1 + u2.z * w2 + u3.z * w3;
        aw += u0.w * w0 + u1.w * w1 + u2.w * w2 + u3.w * w3;
    }
    float4 bv = ((const float4*)gbias)[sl];
    float4 ho = ((const float4*)(h + (size_t)node * FEAT))[sl];
    ((float4*)(hq + (size_t)q * FEAT))[sl] =
        make_float4(ax + bv.x + ho.x, ay + bv.y + ho.y, az + bv.z + ho.z, aw + bv.w + ho.w);
}

// ---------------- last layer + symmetrize, one block per batch ----------------
__global__ void k_lastsym(const float* __restrict__ X4, const float* __restrict__ mw5,
                          const float* __restrict__ mb5, float* __restrict__ out) {
    __shared__ float w[64];
    __shared__ float sm[NQ * NQ];
    int t = threadIdx.x;
    if (t < 64) w[t] = mw5[t];
    __syncthreads();
    int b = blockIdx.x;
    for (int p = t; p < NQ * NQ; p += 256) {
        const float4* row = (const float4*)(X4 + (size_t)(b * NQ * NQ + p) * 64);
        float s = 0.f;
#pragma unroll
        for (int k4 = 0; k4 < 16; k4++) {
            float4 v = row[k4];
            s += v.x * w[k4 * 4] + v.y * w[k4 * 4 + 1] + v.z * w[k4 * 4 + 2] + v.w * w[k4 * 4 + 3];
        }
        sm[p] = s + mb5[0];
    }
    __syncthreads();
    for (int r = t; r < NQ * NQ; r += 256) {
        int i = r / NQ, j = r % NQ;
        out[(size_t)b * NQ * NQ + r] = 0.5f * (sm[r] + sm[j * NQ + i]);
    }
}

extern "C" void kernel_launch(void* const* d_in, const int* in_sizes, int n_in,
                              void* d_out, int out_size, void* d_ws, size_t ws_size,
                              hipStream_t stream) {
    const int* x = (const int*)d_in[0];
    const int* ei = (const int*)d_in[1];
    const int* e_src = ei;
    const int* e_dst = ei + NE;
    const float* emb = (const float*)d_in[2];
    const float* gw = (const float*)d_in[3];   // [5,128,128]
    const float* gb = (const float*)d_in[4];   // [5,128]
    const float* mw0 = (const float*)d_in[5];
    const float* mb0 = (const float*)d_in[6];
    const float* mw1 = (const float*)d_in[7];
    const float* mb1 = (const float*)d_in[8];
    const float* mw2 = (const float*)d_in[9];
    const float* mb2 = (const float*)d_in[10];
    const float* mw3 = (const float*)d_in[11];
    const float* mb3 = (const float*)d_in[12];
    const float* mw4 = (const float*)d_in[13];
    const float* mb4 = (const float*)d_in[14];
    const float* mw5 = (const float*)d_in[15];
    const float* mb5 = (const float*)d_in[16];
    float* out = (float*)d_out;

    float* wsf = (float*)d_ws;
    size_t o = 0;
    const size_t HSZ = (size_t)NN * FEAT;             // 16,711,680
    float* h  = wsf + o; o += HSZ;    // single in-place h buffer
    float* hw = wsf + o; o += HSZ;
    // zero-memset region: cnt, fill, flag1, flag2, cursors (contiguous)
    int* cnt   = (int*)(wsf + o); o += NN;
    int* fill  = (int*)(wsf + o); o += NN;
    int* flag1 = (int*)(wsf + o); o += NN;
    int* flag2 = (int*)(wsf + o); o += NN;
    int* curs  = (int*)(wsf + o); o += 16;   // [0]=offs cursor [1]=list1 [2]=list2
    // 0xFF-memset region: list1, list2 (contiguous, sentinel -1)
    int* list1 = (int*)(wsf + o); o += NN;
    int* list2 = (int*)(wsf + o); o += NN;
    int* offs = (int*)(wsf + o); o += NN;
    float* dinv = wsf + o; o += NN;
    int4* meta = (int4*)(wsf + o); o += 4 * (size_t)NN;
    int2* csre  = (int2*)(wsf + o); o += 2 * (size_t)(NE + 8);  // +8 slop for deg-0 clamp
    int2* csre0 = (int2*)(wsf + o); o += 2 * (size_t)(NE + 8);  // token edges
    int* idmap = (int*)(wsf + o); o += 1024;
    float* embW = wsf + o; o += (size_t)1024 * FEAT;          // emb@W0 table
    float* hq = wsf + o; o += (size_t)BATCH * NQ * FEAT;      // 327,680
    float* Abuf = wsf + o; o += (size_t)BATCH * NQ * 256;     // 655,360
    float* Bbuf = wsf + o; o += (size_t)BATCH * NQ * 256;     // 655,360
    _Float16* bt_hi = (_Float16*)(wsf + o); o += (TS_TOTAL + 2) / 2;
    _Float16* bt_lo = (_Float16*)(wsf + o); o += (TS_TOTAL + 2) / 2;
    // pair-phase aliases (hw, h dead after aggq)
    float* X1 = hw;                         // 51200*128
    float* X2 = hw + (size_t)NPAIR * 128;   // 51200*128
    float* X3 = h;                          // 51200*64
    float* X4 = h + (size_t)NPAIR * 64;     // 51200*64

    // --- weight transpose+split+pack ---
    k_tsplit_all<<<TS_TOTAL / 256, 256, 0, stream>>>(gw, mw0, mw1, mw2, mw3, mw4, bt_hi, bt_lo);

    // --- CSR build + cone lists (consolidated: 5 kernels) ---
    hipMemsetAsync(cnt, 0, (4 * NN + 16) * sizeof(int), stream); // cnt+fill+flags+cursors
    hipMemsetAsync(list1, 0xFF, 2 * NN * sizeof(int), stream);   // list sentinels (-1)
    hipMemsetAsync(csre + NE, 0, 8 * sizeof(int2), stream);      // slop
    hipMemsetAsync(csre0 + NE, 0, 8 * sizeof(int2), stream);     // slop
    k_count<<<NE / 256, 256, 0, stream>>>(e_dst, cnt);
    k_offsets<<<NB, 256, 0, stream>>>(cnt, x, offs, dinv, meta, curs + 0, flag1, idmap);
    k_fill<<<NE / 256, 256, 0, stream>>>(e_src, e_dst, offs, fill, dinv, x, csre, csre0, flag1);
    k_s1pass<<<NB, 256, 0, stream>>>(flag1, meta, csre, curs + 1, list1, flag2);
    k_emit2<<<NB, 256, 0, stream>>>(flag2, curs + 2, list2);

    // --- layer 0 via token table: embW = emb@W0 (1021 rows, clamped id map) ---
    hgemm<8, false, false, false, false, true, false><<<dim3(8, 1), 256, 0, stream>>>(
        emb, nullptr, nullptr, bt_hi + OFF_GCN, bt_lo + OFF_GCN,
        nullptr, embW, nullptr, FEAT, FEAT, idmap, nullptr);
    k_agg0<<<NN / 16, 256, 0, stream>>>(embW, emb, h, meta, csre0, gb + 0 * FEAT);

    // --- layer 1: full gemm + full agg (h in place) ---
    hgemm<8, false, false, false, false, false, false><<<dim3(NN / 128, 1), 256, 0, stream>>>(
        h, nullptr, nullptr, bt_hi + OFF_GCN + 1 * 16384, bt_lo + OFF_GCN + 1 * 16384,
        nullptr, hw, nullptr, FEAT, FEAT, nullptr, nullptr);
    k_agg<false><<<NN / 16, 256, 0, stream>>>(hw, h, meta, csre, nullptr, gb + 1 * FEAT);

    // --- layer 2: full gemm + agg@S2 ---
    hgemm<8, false, false, false, false, false, false><<<dim3(NN / 128, 1), 256, 0, stream>>>(
        h, nullptr, nullptr, bt_hi + OFF_GCN + 2 * 16384, bt_lo + OFF_GCN + 2 * 16384,
        nullptr, hw, nullptr, FEAT, FEAT, nullptr, nullptr);
    k_agg<true><<<NN / 16, 256, 0, stream>>>(hw, h, meta, csre, list2, gb + 2 * FEAT);

    // --- layer 3: gemm@S2 + agg@S1 ---
    hgemm<8, false, false, false, false, false, true><<<dim3(NN / 128, 1), 256, 0, stream>>>(
        h, nullptr, nullptr, bt_hi + OFF_GCN + 3 * 16384, bt_lo + OFF_GCN + 3 * 16384,
        nullptr, hw, nullptr, FEAT, FEAT, nullptr, list2);
    k_agg<true><<<NN / 16, 256, 0, stream>>>(hw, h, meta, csre, list1, gb + 3 * FEAT);

    // --- layer 4: gemm@S1 + selective agg@S0 -> hq ---
    hgemm<8, false, false, false, false, false, true><<<dim3(NN / 128, 1), 256, 0, stream>>>(
        h, nullptr, nullptr, bt_hi + OFF_GCN + 4 * 16384, bt_lo + OFF_GCN + 4 * 16384,
        nullptr, hw, nullptr, FEAT, FEAT, nullptr, list1);
    k_aggq<<<(BATCH * NQ) / 8, 256, 0, stream>>>(hw, h, meta, csre,
                                                 gb + 4 * (size_t)FEAT, hq);

    // --- pair MLP ---
    hgemm<8, false, false, true, false, false, false><<<dim3(20, 4), 256, 0, stream>>>(
        hq, nullptr, nullptr, bt_hi + OFF_P0, bt_lo + OFF_P0, mb0, Abuf, Bbuf, 512, 128,
        nullptr, nullptr);
    hgemm<8, true, true, false, true, false, false><<<dim3(NPAIR / 128, 1), 256, 0, stream>>>(
        nullptr, Abuf, Bbuf, bt_hi + OFF_M1, bt_lo + OFF_M1, mb1, X1, nullptr, 128, 256,
        nullptr, nullptr);
    hgemm<8, true, true, false, false, false, false><<<dim3(NPAIR / 128, 1), 256, 0, stream>>>(
        X1, nullptr, nullptr, bt_hi + OFF_M2, bt_lo + OFF_M2, mb2, X2, nullptr, 128, 128,
        nullptr, nullptr);
    hgemm<4, true, true, false, false, false, false><<<dim3(NPAIR / 128, 1), 256, 0, stream>>>(
        X2, nullptr, nullptr, bt_hi + OFF_M3, bt_lo + OFF_M3, mb3, X3, nullptr, 64, 128,
        nullptr, nullptr);
    hgemm<4, true, true, false, false, false, false><<<dim3(NPAIR / 128, 1), 256, 0, stream>>>(
        X3, nullptr, nullptr, bt_hi + OFF_M4, bt_lo + OFF_M4, mb4, X4, nullptr, 64, 64,
        nullptr, nullptr);
    k_lastsym<<<BATCH, 256, 0, stream>>>(X4, mw5, mb5, out);
}

// Round 15
// 537.656 us; speedup vs baseline: 1.2771x; 1.0155x over previous
//
#include <hip/hip_runtime.h>
#include <hip/hip_bf16.h>

#define NQ 20
#define NLAY 51            // N_LAYER+1
#define FEAT 128
#define BATCH 128
#define NN (BATCH * NQ * NLAY)   // 130560
#define NE 524288
#define NPAIR (BATCH * NQ * NQ)  // 51200
#define NB (NN / 256)            // 510
#define VOCAB 1021

typedef _Float16 half8 __attribute__((ext_vector_type(8)));
typedef float floatx4 __attribute__((ext_vector_type(4)));

__device__ __forceinline__ float lrelu(float v) { return v >= 0.f ? v : 0.01f * v; }

// ---------------- CSR build ----------------
__global__ void k_count(const int* __restrict__ dst, int* __restrict__ cnt) {
    int e = blockIdx.x * 256 + threadIdx.x;
    atomicAdd(&cnt[dst[e]], 1);
}

// offsets via block-scan + global cursor; also dinv, meta, S0 seed, idmap.
__global__ void k_offsets(const int* __restrict__ cnt, const int* __restrict__ x,
                          int* __restrict__ offs, float* __restrict__ dinv,
                          int4* __restrict__ meta, int* __restrict__ cursor,
                          int* __restrict__ flag1, int* __restrict__ idmap) {
    __shared__ int sm[256];
    __shared__ int sbase;
    int t = threadIdx.x, g = blockIdx.x * 256 + t;
    int v = cnt[g];
    sm[t] = v;
    __syncthreads();
    for (int s = 1; s < 256; s <<= 1) {
        int add = (t >= s) ? sm[t - s] : 0;
        __syncthreads();
        sm[t] += add;
        __syncthreads();
    }
    if (t == 255) sbase = atomicAdd(cursor, sm[255]);
    __syncthreads();
    int off = sbase + sm[t] - v;
    float di = rsqrtf((float)(v + 1));  // +1 self loop
    offs[g] = off;
    dinv[g] = di;
    meta[g] = make_int4(off, v, __float_as_int(di), x[g]);
    if (g % (NQ * NLAY) < NQ) flag1[g] = 1;      // S0 seed
    if (g < 1024) idmap[g] = min(g, VOCAB - 1);
}

// fill packed edges {src, norm_bits} and token edges {x[src], norm_bits};
// norm = dinv[src]*dinv[dst]. Also mark flag1[src] for S0 dsts.
__global__ void k_fill(const int* __restrict__ src, const int* __restrict__ dst,
                       const int* __restrict__ offs, int* __restrict__ fill,
                       const float* __restrict__ dinv, const int* __restrict__ x,
                       int2* __restrict__ csre, int2* __restrict__ csre0,
                       int* __restrict__ flag1) {
    int e = blockIdx.x * 256 + threadIdx.x;
    int d = dst[e];
    int s = src[e];
    int pos = offs[d] + atomicAdd(&fill[d], 1);
    int wb = __float_as_int(dinv[s] * dinv[d]);
    csre[pos] = make_int2(s, wb);
    csre0[pos] = make_int2(x[s], wb);
    if (d % (NQ * NLAY) < NQ) flag1[s] = 1;      // src feeds an S0 node
}

// generic cone pass: emit listO from flagI (cursor-packed dense prefix) and, if flagO,
// mark flagO = flagI-members ∪ their in-neighbors
__global__ void k_s1pass(const int* __restrict__ flagI, const int4* __restrict__ meta,
                         const int2* __restrict__ csre, int* __restrict__ cur,
                         int* __restrict__ listO, int* __restrict__ flagO) {
    __shared__ int sm[256];
    __shared__ int sbase;
    int t = threadIdx.x, g = blockIdx.x * 256 + t;
    int v = flagI[g];
    sm[t] = v;
    __syncthreads();
    for (int s = 1; s < 256; s <<= 1) {
        int add = (t >= s) ? sm[t - s] : 0;
        __syncthreads();
        sm[t] += add;
        __syncthreads();
    }
    if (t == 255) sbase = atomicAdd(cur, sm[255]);
    __syncthreads();
    if (v) {
        listO[sbase + sm[t] - 1] = g;
        if (flagO) {
            flagO[g] = 1;
            int4 m = meta[g];
            for (int e = 0; e < m.y; e++) flagO[csre[m.x + e].x] = 1;   // benign races
        }
    }
}

// emit list from flag (cursor-packed)
__global__ void k_emit2(const int* __restrict__ flag, int* __restrict__ cur,
                        int* __restrict__ list) {
    __shared__ int sm[256];
    __shared__ int sbase;
    int t = threadIdx.x, g = blockIdx.x * 256 + t;
    int v = flag[g];
    sm[t] = v;
    __syncthreads();
    for (int s = 1; s < 256; s <<= 1) {
        int add = (t >= s) ? sm[t - s] : 0;
        __syncthreads();
        sm[t] += add;
        __syncthreads();
    }
    if (t == 255) sbase = atomicAdd(cur, sm[255]);
    __syncthreads();
    if (v) list[sbase + sm[t] - 1] = g;
}

// ---------------- weight transpose + fp16 hi/lo split, PACKED MFMA-fragment layout -------
#define OFF_GCN 0                 // 5 x K=128 N=128
#define OFF_P0  81920             // combined mw0: K=128 N=512
#define OFF_M1  147456            // mw1: K=256 N=128
#define OFF_M2  180224            // mw2: K=128 N=128
#define OFF_M3  196608            // mw3: K=128 N=64
#define OFF_M4  204800            // mw4: K=64  N=64
#define TS_TOTAL 208896

__global__ void k_tsplit_all(const float* __restrict__ gw, const float* __restrict__ mw0,
                             const float* __restrict__ mw1, const float* __restrict__ mw2,
                             const float* __restrict__ mw3, const float* __restrict__ mw4,
                             _Float16* __restrict__ hi, _Float16* __restrict__ lo) {
    int idx = blockIdx.x * 256 + threadIdx.x;
    const float* src;
    int K, N, rel;
    bool p0 = false;
    if (idx < OFF_P0) {
        int L = (idx - OFF_GCN) >> 14; rel = (idx - OFF_GCN) & 16383;
        src = gw + L * 16384; K = 128; N = 128;
    } else if (idx < OFF_M1) {
        rel = idx - OFF_P0; src = mw0; K = 128; N = 512; p0 = true;
    } else if (idx < OFF_M2) {
        rel = idx - OFF_M1;  src = mw1; K = 256; N = 128;
    } else if (idx < OFF_M3) {
        rel = idx - OFF_M2;  src = mw2; K = 128; N = 128;
    } else if (idx < OFF_M4) {
        rel = idx - OFF_M3;  src = mw3; K = 128; N = 64;
    } else {
        rel = idx - OFF_M4;  src = mw4; K = 64;  N = 64;
    }
    int kblks = K >> 5;
    int j = rel & 7;
    int lane = (rel >> 3) & 63;
    int t2 = rel >> 9;
    int kblk = t2 % kblks;
    int ntile = t2 / kblks;
    int col = ntile * 16 + (lane & 15);
    int k = kblk * 32 + ((lane >> 4) << 3) + j;
    float f;
    if (p0) {
        f = (col < 256) ? src[k * 256 + col] : src[(k + 128) * 256 + (col - 256)];
    } else {
        f = src[k * N + col];
    }
    _Float16 h = (_Float16)f;
    hi[idx] = h;
    lo[idx] = (_Float16)(f - (float)h);
}

// ---------------- split-fp16 MFMA GEMM ----------------
template <int NT_N, bool LEAKY, bool BIAS, bool P0SPLIT, bool FUSEA, bool GATHA, bool LISTM>
__launch_bounds__(256, 2)
__global__ void hgemm(const float* __restrict__ A,
                      const float* __restrict__ FA, const float* __restrict__ FB,
                      const _Float16* __restrict__ Bh, const _Float16* __restrict__ Bl,
                      const float* __restrict__ bias,
                      float* __restrict__ C, float* __restrict__ C2,
                      int N, int K, const int* __restrict__ gmap,
                      const int* __restrict__ listm) {
    if (LISTM) {
        if ((unsigned)listm[blockIdx.x * 128] >= (unsigned)NN) return;  // all-sentinel block
    }
    const int KB = K >> 5;
    const int lane = threadIdx.x & 63;
    const int wid = threadIdx.x >> 6;
    const int lm = lane & 15, lq = lane >> 4;
    const int m0 = blockIdx.x * 128 + wid * 32;
    const int n0t = blockIdx.y * NT_N;

    const float* arow[2];
    const float* brow[2];
#pragma unroll
    for (int mt = 0; mt < 2; mt++) {
        int row = m0 + mt * 16 + lm;
        if (FUSEA) {
            int b = row / (NQ * NQ);
            int rr = row - b * (NQ * NQ);
            int i = rr / NQ;
            int j = rr - i * NQ;
            arow[mt] = FA + (size_t)(b * NQ + i) * 256;
            brow[mt] = FB + (size_t)(b * NQ + j) * 256;
        } else if (GATHA) {
            arow[mt] = A + (size_t)gmap[row] * K;
        } else if (LISTM) {
            int lr = listm[row];
            lr = ((unsigned)lr < (unsigned)NN) ? lr : 0;
            arow[mt] = A + (size_t)lr * K;
        } else {
            arow[mt] = A + (size_t)row * K;
        }
    }

    floatx4 acc[2][NT_N];
#pragma unroll
    for (int mt = 0; mt < 2; mt++)
#pragma unroll
        for (int nt = 0; nt < NT_N; nt++) acc[mt][nt] = (floatx4)0.f;

    for (int kb = 0; kb < KB; kb++) {
        const int k0 = kb * 32 + lq * 8;
        half8 ahi[2], alo[2];
#pragma unroll
        for (int mt = 0; mt < 2; mt++) {
            floatx4 av0, av1;
            if (FUSEA) {
                floatx4 fa0 = *(const floatx4*)(arow[mt] + k0);
                floatx4 fa1 = *(const floatx4*)(arow[mt] + k0 + 4);
                floatx4 fb0 = *(const floatx4*)(brow[mt] + k0);
                floatx4 fb1 = *(const floatx4*)(brow[mt] + k0 + 4);
#pragma unroll
                for (int q = 0; q < 4; q++) {
                    av0[q] = lrelu(fa0[q] + fb0[q]);
                    av1[q] = lrelu(fa1[q] + fb1[q]);
                }
            } else {
                av0 = *(const floatx4*)(arow[mt] + k0);
                av1 = *(const floatx4*)(arow[mt] + k0 + 4);
            }
#pragma unroll
            for (int q = 0; q < 4; q++) {
                _Float16 h0 = (_Float16)av0[q];
                ahi[mt][q] = h0;
                alo[mt][q] = (_Float16)(av0[q] - (float)h0);
                _Float16 h1 = (_Float16)av1[q];
                ahi[mt][4 + q] = h1;
                alo[mt][4 + q] = (_Float16)(av1[q] - (float)h1);
            }
        }
#pragma unroll
        for (int nt = 0; nt < NT_N; nt++) {
            size_t boff = (((size_t)(n0t + nt) * KB + kb) * 64 + lane) * 8;
            half8 bhi = *(const half8*)(Bh + boff);
            half8 blo = *(const half8*)(Bl + boff);
#pragma unroll
            for (int mt = 0; mt < 2; mt++) {
                acc[mt][nt] = __builtin_amdgcn_mfma_f32_16x16x32_f16(ahi[mt], bhi, acc[mt][nt], 0, 0, 0);
                acc[mt][nt] = __builtin_amdgcn_mfma_f32_16x16x32_f16(ahi[mt], blo, acc[mt][nt], 0, 0, 0);
                acc[mt][nt] = __builtin_amdgcn_mfma_f32_16x16x32_f16(alo[mt], bhi, acc[mt][nt], 0, 0, 0);
            }
        }
    }

    // store-row mapping (C/D layout: col=lane&15, row=(lane>>4)*4+reg)
    int strow[2][4];
    bool svalid[2][4];
#pragma unroll
    for (int mt = 0; mt < 2; mt++)
#pragma unroll
        for (int r = 0; r < 4; r++) {
            int mlog = m0 + mt * 16 + lq * 4 + r;
            if (LISTM) {
                int sr = listm[mlog];
                svalid[mt][r] = (unsigned)sr < (unsigned)NN;
                strow[mt][r] = svalid[mt][r] ? sr : 0;
            } else {
                svalid[mt][r] = true;
                strow[mt][r] = mlog;
            }
        }

#pragma unroll
    for (int nt = 0; nt < NT_N; nt++) {
        int col = (n0t + nt) * 16 + lm;
        float bv = (BIAS || P0SPLIT) ? bias[col < 256 ? col : 0] : 0.f;
#pragma unroll
        for (int mt = 0; mt < 2; mt++) {
#pragma unroll
            for (int r = 0; r < 4; r++) {
                if (!svalid[mt][r]) continue;
                int row = strow[mt][r];
                float val = acc[mt][nt][r];
                if (P0SPLIT) {
                    if (col < 256) C[(size_t)row * 256 + col] = val + bv;
                    else C2[(size_t)row * 256 + col - 256] = val;
                } else {
                    if (BIAS) val += bv;
                    if (LEAKY) val = lrelu(val);
                    C[(size_t)row * N + col] = val;
                }
            }
        }
    }
}

// ---------------- layer-0 aggregation from the L2-resident token table ----------------
__global__ void k_agg0(const float* __restrict__ embW, const float* __restrict__ emb,
                       float* __restrict__ h,
                       const int4* __restrict__ meta, const int2* __restrict__ csre0,
                       const float* __restrict__ bias) {
    int tid = threadIdx.x;
    int sl = tid & 31;
    int p = blockIdx.x * 8 + (tid >> 5);
    int n0 = p * 2, n1 = n0 + 1;
    int4 m0 = meta[n0], m1 = meta[n1];
    float di0 = __int_as_float(m0.z), di1 = __int_as_float(m1.z);
    int off0 = m0.x, deg0 = m0.y;
    int off1 = m1.x, deg1 = m1.y;
    float4 v0 = ((const float4*)(embW + (size_t)m0.w * FEAT))[sl];
    float4 v1 = ((const float4*)(embW + (size_t)m1.w * FEAT))[sl];
    float4 ho0 = ((const float4*)(emb + (size_t)m0.w * FEAT))[sl];
    float4 ho1 = ((const float4*)(emb + (size_t)m1.w * FEAT))[sl];
    float s20 = di0 * di0, s21 = di1 * di1;
    float a0x = v0.x * s20, a0y = v0.y * s20, a0z = v0.z * s20, a0w = v0.w * s20;
    float a1x = v1.x * s21, a1y = v1.y * s21, a1z = v1.z * s21, a1w = v1.w * s21;
    int d0c = max(deg0 - 1, 0), d1c = max(deg1 - 1, 0);
    int dm = max(deg0, deg1);
    for (int e = 0; e < dm; e += 4) {
        int2 e00 = csre0[off0 + min(e,     d0c)];
        int2 e01 = csre0[off0 + min(e + 1, d0c)];
        int2 e02 = csre0[off0 + min(e + 2, d0c)];
        int2 e03 = csre0[off0 + min(e + 3, d0c)];
        int2 e10 = csre0[off1 + min(e,     d1c)];
        int2 e11 = csre0[off1 + min(e + 1, d1c)];
        int2 e12 = csre0[off1 + min(e + 2, d1c)];
        int2 e13 = csre0[off1 + min(e + 3, d1c)];
        float4 u00 = ((const float4*)(embW + (size_t)e00.x * FEAT))[sl];
        float4 u01 = ((const float4*)(embW + (size_t)e01.x * FEAT))[sl];
        float4 u02 = ((const float4*)(embW + (size_t)e02.x * FEAT))[sl];
        float4 u03 = ((const float4*)(embW + (size_t)e03.x * FEAT))[sl];
        float4 u10 = ((const float4*)(embW + (size_t)e10.x * FEAT))[sl];
        float4 u11 = ((const float4*)(embW + (size_t)e11.x * FEAT))[sl];
        float4 u12 = ((const float4*)(embW + (size_t)e12.x * FEAT))[sl];
        float4 u13 = ((const float4*)(embW + (size_t)e13.x * FEAT))[sl];
        float w00 = (e     < deg0) ? __int_as_float(e00.y) : 0.f;
        float w01 = (e + 1 < deg0) ? __int_as_float(e01.y) : 0.f;
        float w02 = (e + 2 < deg0) ? __int_as_float(e02.y) : 0.f;
        float w03 = (e + 3 < deg0) ? __int_as_float(e03.y) : 0.f;
        float w10 = (e     < deg1) ? __int_as_float(e10.y) : 0.f;
        float w11 = (e + 1 < deg1) ? __int_as_float(e11.y) : 0.f;
        float w12 = (e + 2 < deg1) ? __int_as_float(e12.y) : 0.f;
        float w13 = (e + 3 < deg1) ? __int_as_float(e13.y) : 0.f;
        a0x += u00.x * w00 + u01.x * w01 + u02.x * w02 + u03.x * w03;
        a0y += u00.y * w00 + u01.y * w01 + u02.y * w02 + u03.y * w03;
        a0z += u00.z * w00 + u01.z * w01 + u02.z * w02 + u03.z * w03;
        a0w += u00.w * w00 + u01.w * w01 + u02.w * w02 + u03.w * w03;
        a1x += u10.x * w10 + u11.x * w11 + u12.x * w12 + u13.x * w13;
        a1y += u10.y * w10 + u11.y * w11 + u12.y * w12 + u13.y * w13;
        a1z += u10.z * w10 + u11.z * w11 + u12.z * w12 + u13.z * w13;
        a1w += u10.w * w10 + u11.w * w11 + u12.w * w12 + u13.w * w13;
    }
    float4 bv = ((const float4*)bias)[sl];
    float4 r0, r1;
    r0.x = lrelu(a0x + bv.x) + ho0.x;
    r0.y = lrelu(a0y + bv.y) + ho0.y;
    r0.z = lrelu(a0z + bv.z) + ho0.z;
    r0.w = lrelu(a0w + bv.w) + ho0.w;
    r1.x = lrelu(a1x + bv.x) + ho1.x;
    r1.y = lrelu(a1y + bv.y) + ho1.y;
    r1.z = lrelu(a1z + bv.z) + ho1.z;
    r1.w = lrelu(a1w + bv.w) + ho1.w;
    ((float4*)(h + (size_t)n0 * FEAT))[sl] = r0;
    ((float4*)(h + (size_t)n1 * FEAT))[sl] = r1;
}

// ---------------- GCN aggregation + bias + leaky + residual, h IN PLACE ----------------
// LIST lists are dense-prefix valid then sentinel -> block-level early exit is safe.
template <bool LIST>
__global__ void k_agg(const float* __restrict__ hw, float* __restrict__ h,
                      const int4* __restrict__ meta, const int2* __restrict__ csre,
                      const int* __restrict__ list,
                      const float* __restrict__ bias) {
    if (LIST) {
        if ((unsigned)list[blockIdx.x * 16] >= (unsigned)NN) return;  // all-sentinel block
    }
    int tid = threadIdx.x;
    int sl = tid & 31;
    int p = blockIdx.x * 8 + (tid >> 5);
    int n0, n1;
    bool val0 = true, val1 = true;
    if (LIST) {
        n0 = list[p * 2];
        n1 = list[p * 2 + 1];
        val0 = (unsigned)n0 < (unsigned)NN;
        val1 = (unsigned)n1 < (unsigned)NN;
        n0 = val0 ? n0 : 0;
        n1 = val1 ? n1 : 0;
    } else {
        n0 = p * 2;
        n1 = n0 + 1;
    }
    int4 m0 = meta[n0], m1 = meta[n1];
    float di0 = __int_as_float(m0.z), di1 = __int_as_float(m1.z);
    int off0 = m0.x, deg0 = LIST ? (val0 ? m0.y : 0) : m0.y;
    int off1 = m1.x, deg1 = LIST ? (val1 ? m1.y : 0) : m1.y;
    float4 v0 = ((const float4*)(hw + (size_t)n0 * FEAT))[sl];
    float4 v1 = ((const float4*)(hw + (size_t)n1 * FEAT))[sl];
    float4 ho0 = ((const float4*)(h + (size_t)n0 * FEAT))[sl];
    float4 ho1 = ((const float4*)(h + (size_t)n1 * FEAT))[sl];
    float s20 = di0 * di0, s21 = di1 * di1;
    float a0x = v0.x * s20, a0y = v0.y * s20, a0z = v0.z * s20, a0w = v0.w * s20;
    float a1x = v1.x * s21, a1y = v1.y * s21, a1z = v1.z * s21, a1w = v1.w * s21;
    int d0c = max(deg0 - 1, 0), d1c = max(deg1 - 1, 0);
    int dm = max(deg0, deg1);
    for (int e = 0; e < dm; e += 4) {
        int2 e00 = csre[off0 + min(e,     d0c)];
        int2 e01 = csre[off0 + min(e + 1, d0c)];
        int2 e02 = csre[off0 + min(e + 2, d0c)];
        int2 e03 = csre[off0 + min(e + 3, d0c)];
        int2 e10 = csre[off1 + min(e,     d1c)];
        int2 e11 = csre[off1 + min(e + 1, d1c)];
        int2 e12 = csre[off1 + min(e + 2, d1c)];
        int2 e13 = csre[off1 + min(e + 3, d1c)];
        float4 u00 = ((const float4*)(hw + (size_t)e00.x * FEAT))[sl];
        float4 u01 = ((const float4*)(hw + (size_t)e01.x * FEAT))[sl];
        float4 u02 = ((const float4*)(hw + (size_t)e02.x * FEAT))[sl];
        float4 u03 = ((const float4*)(hw + (size_t)e03.x * FEAT))[sl];
        float4 u10 = ((const float4*)(hw + (size_t)e10.x * FEAT))[sl];
        float4 u11 = ((const float4*)(hw + (size_t)e11.x * FEAT))[sl];
        float4 u12 = ((const float4*)(hw + (size_t)e12.x * FEAT))[sl];
        float4 u13 = ((const float4*)(hw + (size_t)e13.x * FEAT))[sl];
        float w00 = (e     < deg0) ? __int_as_float(e00.y) : 0.f;
        float w01 = (e + 1 < deg0) ? __int_as_float(e01.y) : 0.f;
        float w02 = (e + 2 < deg0) ? __int_as_float(e02.y) : 0.f;
        float w03 = (e + 3 < deg0) ? __int_as_float(e03.y) : 0.f;
        float w10 = (e     < deg1) ? __int_as_float(e10.y) : 0.f;
        float w11 = (e + 1 < deg1) ? __int_as_float(e11.y) : 0.f;
        float w12 = (e + 2 < deg1) ? __int_as_float(e12.y) : 0.f;
        float w13 = (e + 3 < deg1) ? __int_as_float(e13.y) : 0.f;
        a0x += u00.x * w00 + u01.x * w01 + u02.x * w02 + u03.x * w03;
        a0y += u00.y * w00 + u01.y * w01 + u02.y * w02 + u03.y * w03;
        a0z += u00.z * w00 + u01.z * w01 + u02.z * w02 + u03.z * w03;
        a0w += u00.w * w00 + u01.w * w01 + u02.w * w02 + u03.w * w03;
        a1x += u10.x * w10 + u11.x * w11 + u12.x * w12 + u13.x * w13;
        a1y += u10.y * w10 + u11.y * w11 + u12.y * w12 + u13.y * w13;
        a1z += u10.z * w10 + u11.z * w11 + u12.z * w12 + u13.z * w13;
        a1w += u10.w * w10 + u11.w * w11 + u12.w * w12 + u13.w * w13;
    }
    float4 bv = ((const float4*)bias)[sl];
    float4 r0, r1;
    r0.x = lrelu(a0x + bv.x) + ho0.x;
    r0.y = lrelu(a0y + bv.y) + ho0.y;
    r0.z = lrelu(a0z + bv.z) + ho0.z;
    r0.w = lrelu(a0w + bv.w) + ho0.w;
    r1.x = lrelu(a1x + bv.x) + ho1.x;
    r1.y = lrelu(a1y + bv.y) + ho1.y;
    r1.z = lrelu(a1z + bv.z) + ho1.z;
    r1.w = lrelu(a1w + bv.w) + ho1.w;
    if (!LIST || val0) ((float4*)(h + (size_t)n0 * FEAT))[sl] = r0;
    if (!LIST || val1) ((float4*)(h + (size_t)n1 * FEAT))[sl] = r1;
}

// ---------------- selective final agg (layer 4): S0 rows only -> hq, no leaky ----------------
__global__ void k_aggq(const float* __restrict__ hw, const float* __restrict__ h,
                       const int4* __restrict__ meta, const int2* __restrict__ csre,
                       const float* __restrict__ gbias, float* __restrict__ hq) {
    int tid = threadIdx.x;
    int sl = tid & 31;
    int q = blockIdx.x * 8 + (tid >> 5);   // 0..2559
    int b = q / NQ, i = q - b * NQ;
    int node = b * (NQ * NLAY) + i;
    int4 m = meta[node];
    float di = __int_as_float(m.z);
    int off = m.x, deg = m.y;
    float s2 = di * di;
    float4 v = ((const float4*)(hw + (size_t)node * FEAT))[sl];
    float ax = v.x * s2, ay = v.y * s2, az = v.z * s2, aw = v.w * s2;
    int dc = max(deg - 1, 0);
    for (int e = 0; e < deg; e += 4) {
        int2 e0 = csre[off + min(e,     dc)];
        int2 e1 = csre[off + min(e + 1, dc)];
        int2 e2 = csre[off + min(e + 2, dc)];
        int2 e3 = csre[off + min(e + 3, dc)];
        float4 u0 = ((const float4*)(hw + (size_t)e0.x * FEAT))[sl];
        float4 u1 = ((const float4*)(hw + (size_t)e1.x * FEAT))[sl];
        float4 u2 = ((const float4*)(hw + (size_t)e2.x * FEAT))[sl];
        float4 u3 = ((const float4*)(hw + (size_t)e3.x * FEAT))[sl];
        float w0 = (e     < deg) ? __int_as_float(e0.y) : 0.f;
        float w1 = (e + 1 < deg) ? __int_as_float(e1.y) : 0.f;
        float w2 = (e + 2 < deg) ? __int_as_float(e2.y) : 0.f;
        float w3 = (e + 3 < deg) ? __int_as_float(e3.y) : 0.f;
        ax += u0.x * w0 + u1.x * w1 + u2.x * w2 + u3.x * w3;
        ay += u0.y * w0 + u1.y * w1 + u2.y * w2 + u3.y * w3;
        az += u0.z * w0 + u1.z * w1 + u2.z * w2 + u3.z * w3;
        aw += u0.w * w0 + u1.w * w1 + u2.w * w2 + u3.w * w3;
    }
    float4 bv = ((const float4*)gbias)[sl];
    float4 ho = ((const float4*)(h + (size_t)node * FEAT))[sl];
    ((float4*)(hq + (size_t)q * FEAT))[sl] =
        make_float4(ax + bv.x + ho.x, ay + bv.y + ho.y, az + bv.z + ho.z, aw + bv.w + ho.w);
}

// ---------------- last layer + symmetrize, one block per batch ----------------
__global__ void k_lastsym(const float* __restrict__ X4, const float* __restrict__ mw5,
                          const float* __restrict__ mb5, float* __restrict__ out) {
    __shared__ float w[64];
    __shared__ float sm[NQ * NQ];
    int t = threadIdx.x;
    if (t < 64) w[t] = mw5[t];
    __syncthreads();
    int b = blockIdx.x;
    for (int p = t; p < NQ * NQ; p += 256) {
        const float4* row = (const float4*)(X4 + (size_t)(b * NQ * NQ + p) * 64);
        float s = 0.f;
#pragma unroll
        for (int k4 = 0; k4 < 16; k4++) {
            float4 v = row[k4];
            s += v.x * w[k4 * 4] + v.y * w[k4 * 4 + 1] + v.z * w[k4 * 4 + 2] + v.w * w[k4 * 4 + 3];
        }
        sm[p] = s + mb5[0];
    }
    __syncthreads();
    for (int r = t; r < NQ * NQ; r += 256) {
        int i = r / NQ, j = r % NQ;
        out[(size_t)b * NQ * NQ + r] = 0.5f * (sm[r] + sm[j * NQ + i]);
    }
}

extern "C" void kernel_launch(void* const* d_in, const int* in_sizes, int n_in,
                              void* d_out, int out_size, void* d_ws, size_t ws_size,
                              hipStream_t stream) {
    const int* x = (const int*)d_in[0];
    const int* ei = (const int*)d_in[1];
    const int* e_src = ei;
    const int* e_dst = ei + NE;
    const float* emb = (const float*)d_in[2];
    const float* gw = (const float*)d_in[3];   // [5,128,128]
    const float* gb = (const float*)d_in[4];   // [5,128]
    const float* mw0 = (const float*)d_in[5];
    const float* mb0 = (const float*)d_in[6];
    const float* mw1 = (const float*)d_in[7];
    const float* mb1 = (const float*)d_in[8];
    const float* mw2 = (const float*)d_in[9];
    const float* mb2 = (const float*)d_in[10];
    const float* mw3 = (const float*)d_in[11];
    const float* mb3 = (const float*)d_in[12];
    const float* mw4 = (const float*)d_in[13];
    const float* mb4 = (const float*)d_in[14];
    const float* mw5 = (const float*)d_in[15];
    const float* mb5 = (const float*)d_in[16];
    float* out = (float*)d_out;

    float* wsf = (float*)d_ws;
    size_t o = 0;
    const size_t HSZ = (size_t)NN * FEAT;             // 16,711,680
    float* h  = wsf + o; o += HSZ;    // single in-place h buffer
    float* hw = wsf + o; o += HSZ;
    // zero-memset region: cnt, fill, flag1, flag2, flag3, cursors (contiguous)
    int* cnt   = (int*)(wsf + o); o += NN;
    int* fill  = (int*)(wsf + o); o += NN;
    int* flag1 = (int*)(wsf + o); o += NN;
    int* flag2 = (int*)(wsf + o); o += NN;
    int* flag3 = (int*)(wsf + o); o += NN;
    int* curs  = (int*)(wsf + o); o += 16;   // [0]=offs [1]=list1 [2]=list2 [3]=list3
    // 0xFF-memset region: list1, list2, list3 (contiguous, sentinel -1)
    int* list1 = (int*)(wsf + o); o += NN;
    int* list2 = (int*)(wsf + o); o += NN;
    int* list3 = (int*)(wsf + o); o += NN;
    int* offs = (int*)(wsf + o); o += NN;
    float* dinv = wsf + o; o += NN;
    int4* meta = (int4*)(wsf + o); o += 4 * (size_t)NN;
    int2* csre  = (int2*)(wsf + o); o += 2 * (size_t)(NE + 8);  // +8 slop for deg-0 clamp
    int2* csre0 = (int2*)(wsf + o); o += 2 * (size_t)(NE + 8);  // token edges
    int* idmap = (int*)(wsf + o); o += 1024;
    float* embW = wsf + o; o += (size_t)1024 * FEAT;          // emb@W0 table
    float* hq = wsf + o; o += (size_t)BATCH * NQ * FEAT;      // 327,680
    float* Abuf = wsf + o; o += (size_t)BATCH * NQ * 256;     // 655,360
    float* Bbuf = wsf + o; o += (size_t)BATCH * NQ * 256;     // 655,360
    _Float16* bt_hi = (_Float16*)(wsf + o); o += (TS_TOTAL + 2) / 2;
    _Float16* bt_lo = (_Float16*)(wsf + o); o += (TS_TOTAL + 2) / 2;
    // pair-phase aliases (hw, h dead after aggq)
    float* X1 = hw;                         // 51200*128
    float* X2 = hw + (size_t)NPAIR * 128;   // 51200*128
    float* X3 = h;                          // 51200*64
    float* X4 = h + (size_t)NPAIR * 64;     // 51200*64

    // --- weight transpose+split+pack ---
    k_tsplit_all<<<TS_TOTAL / 256, 256, 0, stream>>>(gw, mw0, mw1, mw2, mw3, mw4, bt_hi, bt_lo);

    // --- CSR build + cone lists S1/S2/S3 ---
    hipMemsetAsync(cnt, 0, (5 * NN + 16) * sizeof(int), stream); // cnt+fill+flags+cursors
    hipMemsetAsync(list1, 0xFF, 3 * NN * sizeof(int), stream);   // list sentinels (-1)
    hipMemsetAsync(csre + NE, 0, 8 * sizeof(int2), stream);      // slop
    hipMemsetAsync(csre0 + NE, 0, 8 * sizeof(int2), stream);     // slop
    k_count<<<NE / 256, 256, 0, stream>>>(e_dst, cnt);
    k_offsets<<<NB, 256, 0, stream>>>(cnt, x, offs, dinv, meta, curs + 0, flag1, idmap);
    k_fill<<<NE / 256, 256, 0, stream>>>(e_src, e_dst, offs, fill, dinv, x, csre, csre0, flag1);
    k_s1pass<<<NB, 256, 0, stream>>>(flag1, meta, csre, curs + 1, list1, flag2);  // S1 + mark S2
    k_s1pass<<<NB, 256, 0, stream>>>(flag2, meta, csre, curs + 2, list2, flag3);  // S2 + mark S3
    k_emit2<<<NB, 256, 0, stream>>>(flag3, curs + 3, list3);                      // S3

    // --- layer 0 via token table: embW = emb@W0 (1021 rows, clamped id map) ---
    hgemm<8, false, false, false, false, true, false><<<dim3(8, 1), 256, 0, stream>>>(
        emb, nullptr, nullptr, bt_hi + OFF_GCN, bt_lo + OFF_GCN,
        nullptr, embW, nullptr, FEAT, FEAT, idmap, nullptr);
    k_agg0<<<NN / 16, 256, 0, stream>>>(embW, emb, h, meta, csre0, gb + 0 * FEAT);

    // --- layer 1: full gemm + agg@S3 (h2 only needed at S3 = gemm2 rows ∪ agg2 residuals) ---
    hgemm<8, false, false, false, false, false, false><<<dim3(NN / 128, 1), 256, 0, stream>>>(
        h, nullptr, nullptr, bt_hi + OFF_GCN + 1 * 16384, bt_lo + OFF_GCN + 1 * 16384,
        nullptr, hw, nullptr, FEAT, FEAT, nullptr, nullptr);
    k_agg<true><<<NN / 16, 256, 0, stream>>>(hw, h, meta, csre, list3, gb + 1 * FEAT);

    // --- layer 2: gemm@S3 + agg@S2 (agg2 needs hw2 at S2 ∪ N(S2) = S3) ---
    hgemm<8, false, false, false, false, false, true><<<dim3(NN / 128, 1), 256, 0, stream>>>(
        h, nullptr, nullptr, bt_hi + OFF_GCN + 2 * 16384, bt_lo + OFF_GCN + 2 * 16384,
        nullptr, hw, nullptr, FEAT, FEAT, nullptr, list3);
    k_agg<true><<<NN / 16, 256, 0, stream>>>(hw, h, meta, csre, list2, gb + 2 * FEAT);

    // --- layer 3: gemm@S2 + agg@S1 ---
    hgemm<8, false, false, false, false, false, true><<<dim3(NN / 128, 1), 256, 0, stream>>>(
        h, nullptr, nullptr, bt_hi + OFF_GCN + 3 * 16384, bt_lo + OFF_GCN + 3 * 16384,
        nullptr, hw, nullptr, FEAT, FEAT, nullptr, list2);
    k_agg<true><<<NN / 16, 256, 0, stream>>>(hw, h, meta, csre, list1, gb + 3 * FEAT);

    // --- layer 4: gemm@S1 + selective agg@S0 -> hq ---
    hgemm<8, false, false, false, false, false, true><<<dim3(NN / 128, 1), 256, 0, stream>>>(
        h, nullptr, nullptr, bt_hi + OFF_GCN + 4 * 16384, bt_lo + OFF_GCN + 4 * 16384,
        nullptr, hw, nullptr, FEAT, FEAT, nullptr, list1);
    k_aggq<<<(BATCH * NQ) / 8, 256, 0, stream>>>(hw, h, meta, csre,
                                                 gb + 4 * (size_t)FEAT, hq);

    // --- pair MLP ---
    hgemm<8, false, false, true, false, false, false><<<dim3(20, 4), 256, 0, stream>>>(
        hq, nullptr, nullptr, bt_hi + OFF_P0, bt_lo + OFF_P0, mb0, Abuf, Bbuf, 512, 128,
        nullptr, nullptr);
    hgemm<8, true, true, false, true, false, false><<<dim3(NPAIR / 128, 1), 256, 0, stream>>>(
        nullptr, Abuf, Bbuf, bt_hi + OFF_M1, bt_lo + OFF_M1, mb1, X1, nullptr, 128, 256,
        nullptr, nullptr);
    hgemm<8, true, true, false, false, false, false><<<dim3(NPAIR / 128, 1), 256, 0, stream>>>(
        X1, nullptr, nullptr, bt_hi + OFF_M2, bt_lo + OFF_M2, mb2, X2, nullptr, 128, 128,
        nullptr, nullptr);
    hgemm<4, true, true, false, false, false, false><<<dim3(NPAIR / 128, 1), 256, 0, stream>>>(
        X2, nullptr, nullptr, bt_hi + OFF_M3, bt_lo + OFF_M3, mb3, X3, nullptr, 64, 128,
        nullptr, nullptr);
    hgemm<4, true, true, false, false, false, false><<<dim3(NPAIR / 128, 1), 256, 0, stream>>>(
        X3, nullptr, nullptr, bt_hi + OFF_M4, bt_lo + OFF_M4, mb4, X4, nullptr, 64, 64,
        nullptr, nullptr);
    k_lastsym<<<BATCH, 256, 0, stream>>>(X4, mw5, mb5, out);
}

// Round 16
// 536.676 us; speedup vs baseline: 1.2795x; 1.0018x over previous
//
#include <hip/hip_runtime.h>
#include <hip/hip_bf16.h>

#define NQ 20
#define NLAY 51            // N_LAYER+1
#define FEAT 128
#define BATCH 128
#define NN (BATCH * NQ * NLAY)   // 130560
#define NE 524288
#define NPAIR (BATCH * NQ * NQ)  // 51200
#define NB (NN / 256)            // 510
#define VOCAB 1021

typedef _Float16 half8 __attribute__((ext_vector_type(8)));
typedef float floatx4 __attribute__((ext_vector_type(4)));

__device__ __forceinline__ float lrelu(float v) { return v >= 0.f ? v : 0.01f * v; }

// ---------------- CSR build ----------------
__global__ void k_count(const int* __restrict__ dst, int* __restrict__ cnt) {
    int e = blockIdx.x * 256 + threadIdx.x;
    atomicAdd(&cnt[dst[e]], 1);
}

// offsets via block-scan + global cursor; also dinv, meta, S0 seed, idmap.
__global__ void k_offsets(const int* __restrict__ cnt, const int* __restrict__ x,
                          int* __restrict__ offs, float* __restrict__ dinv,
                          int4* __restrict__ meta, int* __restrict__ cursor,
                          int* __restrict__ flag1, int* __restrict__ idmap) {
    __shared__ int sm[256];
    __shared__ int sbase;
    int t = threadIdx.x, g = blockIdx.x * 256 + t;
    int v = cnt[g];
    sm[t] = v;
    __syncthreads();
    for (int s = 1; s < 256; s <<= 1) {
        int add = (t >= s) ? sm[t - s] : 0;
        __syncthreads();
        sm[t] += add;
        __syncthreads();
    }
    if (t == 255) sbase = atomicAdd(cursor, sm[255]);
    __syncthreads();
    int off = sbase + sm[t] - v;
    float di = rsqrtf((float)(v + 1));  // +1 self loop
    offs[g] = off;
    dinv[g] = di;
    meta[g] = make_int4(off, v, __float_as_int(di), x[g]);
    if (g % (NQ * NLAY) < NQ) flag1[g] = 1;      // S0 seed
    if (g < 1024) idmap[g] = min(g, VOCAB - 1);
}

// fill packed edges {src, norm_bits} and token edges {x[src], norm_bits};
// norm = dinv[src]*dinv[dst]. Also mark flag1[src] for S0 dsts.
__global__ void k_fill(const int* __restrict__ src, const int* __restrict__ dst,
                       const int* __restrict__ offs, int* __restrict__ fill,
                       const float* __restrict__ dinv, const int* __restrict__ x,
                       int2* __restrict__ csre, int2* __restrict__ csre0,
                       int* __restrict__ flag1) {
    int e = blockIdx.x * 256 + threadIdx.x;
    int d = dst[e];
    int s = src[e];
    int pos = offs[d] + atomicAdd(&fill[d], 1);
    int wb = __float_as_int(dinv[s] * dinv[d]);
    csre[pos] = make_int2(s, wb);
    csre0[pos] = make_int2(x[s], wb);
    if (d % (NQ * NLAY) < NQ) flag1[s] = 1;      // src feeds an S0 node
}

// generic cone pass: emit listO from flagI (cursor-packed dense prefix) and, if flagO,
// mark flagO = flagI-members ∪ their in-neighbors
__global__ void k_s1pass(const int* __restrict__ flagI, const int4* __restrict__ meta,
                         const int2* __restrict__ csre, int* __restrict__ cur,
                         int* __restrict__ listO, int* __restrict__ flagO) {
    __shared__ int sm[256];
    __shared__ int sbase;
    int t = threadIdx.x, g = blockIdx.x * 256 + t;
    int v = flagI[g];
    sm[t] = v;
    __syncthreads();
    for (int s = 1; s < 256; s <<= 1) {
        int add = (t >= s) ? sm[t - s] : 0;
        __syncthreads();
        sm[t] += add;
        __syncthreads();
    }
    if (t == 255) sbase = atomicAdd(cur, sm[255]);
    __syncthreads();
    if (v) {
        listO[sbase + sm[t] - 1] = g;
        if (flagO) {
            flagO[g] = 1;
            int4 m = meta[g];
            for (int e = 0; e < m.y; e++) flagO[csre[m.x + e].x] = 1;   // benign races
        }
    }
}

// emit list from flag (cursor-packed)
__global__ void k_emit2(const int* __restrict__ flag, int* __restrict__ cur,
                        int* __restrict__ list) {
    __shared__ int sm[256];
    __shared__ int sbase;
    int t = threadIdx.x, g = blockIdx.x * 256 + t;
    int v = flag[g];
    sm[t] = v;
    __syncthreads();
    for (int s = 1; s < 256; s <<= 1) {
        int add = (t >= s) ? sm[t - s] : 0;
        __syncthreads();
        sm[t] += add;
        __syncthreads();
    }
    if (t == 255) sbase = atomicAdd(cur, sm[255]);
    __syncthreads();
    if (v) list[sbase + sm[t] - 1] = g;
}

// ---------------- weight transpose + fp16 hi/lo split, PACKED MFMA-fragment layout -------
#define OFF_GCN 0                 // 5 x K=128 N=128
#define OFF_P0  81920             // combined mw0: K=128 N=512
#define OFF_M1  147456            // mw1: K=256 N=128
#define OFF_M2  180224            // mw2: K=128 N=128
#define OFF_M3  196608            // mw3: K=128 N=64
#define OFF_M4  204800            // mw4: K=64  N=64
#define TS_TOTAL 208896

__global__ void k_tsplit_all(const float* __restrict__ gw, const float* __restrict__ mw0,
                             const float* __restrict__ mw1, const float* __restrict__ mw2,
                             const float* __restrict__ mw3, const float* __restrict__ mw4,
                             _Float16* __restrict__ hi, _Float16* __restrict__ lo) {
    int idx = blockIdx.x * 256 + threadIdx.x;
    const float* src;
    int K, N, rel;
    bool p0 = false;
    if (idx < OFF_P0) {
        int L = (idx - OFF_GCN) >> 14; rel = (idx - OFF_GCN) & 16383;
        src = gw + L * 16384; K = 128; N = 128;
    } else if (idx < OFF_M1) {
        rel = idx - OFF_P0; src = mw0; K = 128; N = 512; p0 = true;
    } else if (idx < OFF_M2) {
        rel = idx - OFF_M1;  src = mw1; K = 256; N = 128;
    } else if (idx < OFF_M3) {
        rel = idx - OFF_M2;  src = mw2; K = 128; N = 128;
    } else if (idx < OFF_M4) {
        rel = idx - OFF_M3;  src = mw3; K = 128; N = 64;
    } else {
        rel = idx - OFF_M4;  src = mw4; K = 64;  N = 64;
    }
    int kblks = K >> 5;
    int j = rel & 7;
    int lane = (rel >> 3) & 63;
    int t2 = rel >> 9;
    int kblk = t2 % kblks;
    int ntile = t2 / kblks;
    int col = ntile * 16 + (lane & 15);
    int k = kblk * 32 + ((lane >> 4) << 3) + j;
    float f;
    if (p0) {
        f = (col < 256) ? src[k * 256 + col] : src[(k + 128) * 256 + (col - 256)];
    } else {
        f = src[k * N + col];
    }
    _Float16 h = (_Float16)f;
    hi[idx] = h;
    lo[idx] = (_Float16)(f - (float)h);
}

// ---------------- split-fp16 MFMA GEMM ----------------
template <int NT_N, bool LEAKY, bool BIAS, bool P0SPLIT, bool FUSEA, bool GATHA, bool LISTM>
__launch_bounds__(256, 2)
__global__ void hgemm(const float* __restrict__ A,
                      const float* __restrict__ FA, const float* __restrict__ FB,
                      const _Float16* __restrict__ Bh, const _Float16* __restrict__ Bl,
                      const float* __restrict__ bias,
                      float* __restrict__ C, float* __restrict__ C2,
                      int N, int K, const int* __restrict__ gmap,
                      const int* __restrict__ listm) {
    if (LISTM) {
        if ((unsigned)listm[blockIdx.x * 128] >= (unsigned)NN) return;  // all-sentinel block
    }
    const int KB = K >> 5;
    const int lane = threadIdx.x & 63;
    const int wid = threadIdx.x >> 6;
    const int lm = lane & 15, lq = lane >> 4;
    const int m0 = blockIdx.x * 128 + wid * 32;
    const int n0t = blockIdx.y * NT_N;

    const float* arow[2];
    const float* brow[2];
#pragma unroll
    for (int mt = 0; mt < 2; mt++) {
        int row = m0 + mt * 16 + lm;
        if (FUSEA) {
            int b = row / (NQ * NQ);
            int rr = row - b * (NQ * NQ);
            int i = rr / NQ;
            int j = rr - i * NQ;
            arow[mt] = FA + (size_t)(b * NQ + i) * 256;
            brow[mt] = FB + (size_t)(b * NQ + j) * 256;
        } else if (GATHA) {
            arow[mt] = A + (size_t)gmap[row] * K;
        } else if (LISTM) {
            int lr = listm[row];
            lr = ((unsigned)lr < (unsigned)NN) ? lr : 0;
            arow[mt] = A + (size_t)lr * K;
        } else {
            arow[mt] = A + (size_t)row * K;
        }
    }

    floatx4 acc[2][NT_N];
#pragma unroll
    for (int mt = 0; mt < 2; mt++)
#pragma unroll
        for (int nt = 0; nt < NT_N; nt++) acc[mt][nt] = (floatx4)0.f;

    for (int kb = 0; kb < KB; kb++) {
        const int k0 = kb * 32 + lq * 8;
        half8 ahi[2], alo[2];
#pragma unroll
        for (int mt = 0; mt < 2; mt++) {
            floatx4 av0, av1;
            if (FUSEA) {
                floatx4 fa0 = *(const floatx4*)(arow[mt] + k0);
                floatx4 fa1 = *(const floatx4*)(arow[mt] + k0 + 4);
                floatx4 fb0 = *(const floatx4*)(brow[mt] + k0);
                floatx4 fb1 = *(const floatx4*)(brow[mt] + k0 + 4);
#pragma unroll
                for (int q = 0; q < 4; q++) {
                    av0[q] = lrelu(fa0[q] + fb0[q]);
                    av1[q] = lrelu(fa1[q] + fb1[q]);
                }
            } else {
                av0 = *(const floatx4*)(arow[mt] + k0);
                av1 = *(const floatx4*)(arow[mt] + k0 + 4);
            }
#pragma unroll
            for (int q = 0; q < 4; q++) {
                _Float16 h0 = (_Float16)av0[q];
                ahi[mt][q] = h0;
                alo[mt][q] = (_Float16)(av0[q] - (float)h0);
                _Float16 h1 = (_Float16)av1[q];
                ahi[mt][4 + q] = h1;
                alo[mt][4 + q] = (_Float16)(av1[q] - (float)h1);
            }
        }
#pragma unroll
        for (int nt = 0; nt < NT_N; nt++) {
            size_t boff = (((size_t)(n0t + nt) * KB + kb) * 64 + lane) * 8;
            half8 bhi = *(const half8*)(Bh + boff);
            half8 blo = *(const half8*)(Bl + boff);
#pragma unroll
            for (int mt = 0; mt < 2; mt++) {
                acc[mt][nt] = __builtin_amdgcn_mfma_f32_16x16x32_f16(ahi[mt], bhi, acc[mt][nt], 0, 0, 0);
                acc[mt][nt] = __builtin_amdgcn_mfma_f32_16x16x32_f16(ahi[mt], blo, acc[mt][nt], 0, 0, 0);
                acc[mt][nt] = __builtin_amdgcn_mfma_f32_16x16x32_f16(alo[mt], bhi, acc[mt][nt], 0, 0, 0);
            }
        }
    }

    // store-row mapping (C/D layout: col=lane&15, row=(lane>>4)*4+reg)
    int strow[2][4];
    bool svalid[2][4];
#pragma unroll
    for (int mt = 0; mt < 2; mt++)
#pragma unroll
        for (int r = 0; r < 4; r++) {
            int mlog = m0 + mt * 16 + lq * 4 + r;
            if (LISTM) {
                int sr = listm[mlog];
                svalid[mt][r] = (unsigned)sr < (unsigned)NN;
                strow[mt][r] = svalid[mt][r] ? sr : 0;
            } else {
                svalid[mt][r] = true;
                strow[mt][r] = mlog;
            }
        }

#pragma unroll
    for (int nt = 0; nt < NT_N; nt++) {
        int col = (n0t + nt) * 16 + lm;
        float bv = (BIAS || P0SPLIT) ? bias[col < 256 ? col : 0] : 0.f;
#pragma unroll
        for (int mt = 0; mt < 2; mt++) {
#pragma unroll
            for (int r = 0; r < 4; r++) {
                if (!svalid[mt][r]) continue;
                int row = strow[mt][r];
                float val = acc[mt][nt][r];
                if (P0SPLIT) {
                    if (col < 256) C[(size_t)row * 256 + col] = val + bv;
                    else C2[(size_t)row * 256 + col - 256] = val;
                } else {
                    if (BIAS) val += bv;
                    if (LEAKY) val = lrelu(val);
                    C[(size_t)row * N + col] = val;
                }
            }
        }
    }
}

// ---------------- layer-0 aggregation from the L2-resident token table ----------------
__global__ void k_agg0(const float* __restrict__ embW, const float* __restrict__ emb,
                       float* __restrict__ h,
                       const int4* __restrict__ meta, const int2* __restrict__ csre0,
                       const float* __restrict__ bias) {
    int tid = threadIdx.x;
    int sl = tid & 31;
    int p = blockIdx.x * 8 + (tid >> 5);
    int n0 = p * 2, n1 = n0 + 1;
    int4 m0 = meta[n0], m1 = meta[n1];
    float di0 = __int_as_float(m0.z), di1 = __int_as_float(m1.z);
    int off0 = m0.x, deg0 = m0.y;
    int off1 = m1.x, deg1 = m1.y;
    float4 v0 = ((const float4*)(embW + (size_t)m0.w * FEAT))[sl];
    float4 v1 = ((const float4*)(embW + (size_t)m1.w * FEAT))[sl];
    float4 ho0 = ((const float4*)(emb + (size_t)m0.w * FEAT))[sl];
    float4 ho1 = ((const float4*)(emb + (size_t)m1.w * FEAT))[sl];
    float s20 = di0 * di0, s21 = di1 * di1;
    float a0x = v0.x * s20, a0y = v0.y * s20, a0z = v0.z * s20, a0w = v0.w * s20;
    float a1x = v1.x * s21, a1y = v1.y * s21, a1z = v1.z * s21, a1w = v1.w * s21;
    int d0c = max(deg0 - 1, 0), d1c = max(deg1 - 1, 0);
    int dm = max(deg0, deg1);
    for (int e = 0; e < dm; e += 4) {
        int2 e00 = csre0[off0 + min(e,     d0c)];
        int2 e01 = csre0[off0 + min(e + 1, d0c)];
        int2 e02 = csre0[off0 + min(e + 2, d0c)];
        int2 e03 = csre0[off0 + min(e + 3, d0c)];
        int2 e10 = csre0[off1 + min(e,     d1c)];
        int2 e11 = csre0[off1 + min(e + 1, d1c)];
        int2 e12 = csre0[off1 + min(e + 2, d1c)];
        int2 e13 = csre0[off1 + min(e + 3, d1c)];
        float4 u00 = ((const float4*)(embW + (size_t)e00.x * FEAT))[sl];
        float4 u01 = ((const float4*)(embW + (size_t)e01.x * FEAT))[sl];
        float4 u02 = ((const float4*)(embW + (size_t)e02.x * FEAT))[sl];
        float4 u03 = ((const float4*)(embW + (size_t)e03.x * FEAT))[sl];
        float4 u10 = ((const float4*)(embW + (size_t)e10.x * FEAT))[sl];
        float4 u11 = ((const float4*)(embW + (size_t)e11.x * FEAT))[sl];
        float4 u12 = ((const float4*)(embW + (size_t)e12.x * FEAT))[sl];
        float4 u13 = ((const float4*)(embW + (size_t)e13.x * FEAT))[sl];
        float w00 = (e     < deg0) ? __int_as_float(e00.y) : 0.f;
        float w01 = (e + 1 < deg0) ? __int_as_float(e01.y) : 0.f;
        float w02 = (e + 2 < deg0) ? __int_as_float(e02.y) : 0.f;
        float w03 = (e + 3 < deg0) ? __int_as_float(e03.y) : 0.f;
        float w10 = (e     < deg1) ? __int_as_float(e10.y) : 0.f;
        float w11 = (e + 1 < deg1) ? __int_as_float(e11.y) : 0.f;
        float w12 = (e + 2 < deg1) ? __int_as_float(e12.y) : 0.f;
        float w13 = (e + 3 < deg1) ? __int_as_float(e13.y) : 0.f;
        a0x += u00.x * w00 + u01.x * w01 + u02.x * w02 + u03.x * w03;
        a0y += u00.y * w00 + u01.y * w01 + u02.y * w02 + u03.y * w03;
        a0z += u00.z * w00 + u01.z * w01 + u02.z * w02 + u03.z * w03;
        a0w += u00.w * w00 + u01.w * w01 + u02.w * w02 + u03.w * w03;
        a1x += u10.x * w10 + u11.x * w11 + u12.x * w12 + u13.x * w13;
        a1y += u10.y * w10 + u11.y * w11 + u12.y * w12 + u13.y * w13;
        a1z += u10.z * w10 + u11.z * w11 + u12.z * w12 + u13.z * w13;
        a1w += u10.w * w10 + u11.w * w11 + u12.w * w12 + u13.w * w13;
    }
    float4 bv = ((const float4*)bias)[sl];
    float4 r0, r1;
    r0.x = lrelu(a0x + bv.x) + ho0.x;
    r0.y = lrelu(a0y + bv.y) + ho0.y;
    r0.z = lrelu(a0z + bv.z) + ho0.z;
    r0.w = lrelu(a0w + bv.w) + ho0.w;
    r1.x = lrelu(a1x + bv.x) + ho1.x;
    r1.y = lrelu(a1y + bv.y) + ho1.y;
    r1.z = lrelu(a1z + bv.z) + ho1.z;
    r1.w = lrelu(a1w + bv.w) + ho1.w;
    ((float4*)(h + (size_t)n0 * FEAT))[sl] = r0;
    ((float4*)(h + (size_t)n1 * FEAT))[sl] = r1;
}

// ---------------- GCN aggregation + bias + leaky + residual, h IN PLACE ----------------
// Sentinel-padded dense-prefix list; block early exit; clamp; store suppress.
// Unroll-6: 12 gathers in flight per half-wave (~52 VGPR, under the 64-VGPR cliff).
__global__ void k_agg(const float* __restrict__ hw, float* __restrict__ h,
                      const int4* __restrict__ meta, const int2* __restrict__ csre,
                      const int* __restrict__ list,
                      const float* __restrict__ bias) {
    if ((unsigned)list[blockIdx.x * 16] >= (unsigned)NN) return;  // all-sentinel block
    int tid = threadIdx.x;
    int sl = tid & 31;
    int p = blockIdx.x * 8 + (tid >> 5);
    int n0 = list[p * 2];
    int n1 = list[p * 2 + 1];
    bool val0 = (unsigned)n0 < (unsigned)NN;
    bool val1 = (unsigned)n1 < (unsigned)NN;
    n0 = val0 ? n0 : 0;
    n1 = val1 ? n1 : 0;
    int4 m0 = meta[n0], m1 = meta[n1];
    float di0 = __int_as_float(m0.z), di1 = __int_as_float(m1.z);
    int off0 = m0.x, deg0 = val0 ? m0.y : 0;
    int off1 = m1.x, deg1 = val1 ? m1.y : 0;
    float4 v0 = ((const float4*)(hw + (size_t)n0 * FEAT))[sl];
    float4 v1 = ((const float4*)(hw + (size_t)n1 * FEAT))[sl];
    float4 ho0 = ((const float4*)(h + (size_t)n0 * FEAT))[sl];
    float4 ho1 = ((const float4*)(h + (size_t)n1 * FEAT))[sl];
    float s20 = di0 * di0, s21 = di1 * di1;
    float a0x = v0.x * s20, a0y = v0.y * s20, a0z = v0.z * s20, a0w = v0.w * s20;
    float a1x = v1.x * s21, a1y = v1.y * s21, a1z = v1.z * s21, a1w = v1.w * s21;
    int d0c = max(deg0 - 1, 0), d1c = max(deg1 - 1, 0);
    int dm = max(deg0, deg1);
    for (int e = 0; e < dm; e += 6) {
        int2 e00 = csre[off0 + min(e,     d0c)];
        int2 e01 = csre[off0 + min(e + 1, d0c)];
        int2 e02 = csre[off0 + min(e + 2, d0c)];
        int2 e03 = csre[off0 + min(e + 3, d0c)];
        int2 e04 = csre[off0 + min(e + 4, d0c)];
        int2 e05 = csre[off0 + min(e + 5, d0c)];
        int2 e10 = csre[off1 + min(e,     d1c)];
        int2 e11 = csre[off1 + min(e + 1, d1c)];
        int2 e12 = csre[off1 + min(e + 2, d1c)];
        int2 e13 = csre[off1 + min(e + 3, d1c)];
        int2 e14 = csre[off1 + min(e + 4, d1c)];
        int2 e15 = csre[off1 + min(e + 5, d1c)];
        float4 u00 = ((const float4*)(hw + (size_t)e00.x * FEAT))[sl];
        float4 u01 = ((const float4*)(hw + (size_t)e01.x * FEAT))[sl];
        float4 u02 = ((const float4*)(hw + (size_t)e02.x * FEAT))[sl];
        float4 u03 = ((const float4*)(hw + (size_t)e03.x * FEAT))[sl];
        float4 u04 = ((const float4*)(hw + (size_t)e04.x * FEAT))[sl];
        float4 u05 = ((const float4*)(hw + (size_t)e05.x * FEAT))[sl];
        float4 u10 = ((const float4*)(hw + (size_t)e10.x * FEAT))[sl];
        float4 u11 = ((const float4*)(hw + (size_t)e11.x * FEAT))[sl];
        float4 u12 = ((const float4*)(hw + (size_t)e12.x * FEAT))[sl];
        float4 u13 = ((const float4*)(hw + (size_t)e13.x * FEAT))[sl];
        float4 u14 = ((const float4*)(hw + (size_t)e14.x * FEAT))[sl];
        float4 u15 = ((const float4*)(hw + (size_t)e15.x * FEAT))[sl];
        float w00 = (e     < deg0) ? __int_as_float(e00.y) : 0.f;
        float w01 = (e + 1 < deg0) ? __int_as_float(e01.y) : 0.f;
        float w02 = (e + 2 < deg0) ? __int_as_float(e02.y) : 0.f;
        float w03 = (e + 3 < deg0) ? __int_as_float(e03.y) : 0.f;
        float w04 = (e + 4 < deg0) ? __int_as_float(e04.y) : 0.f;
        float w05 = (e + 5 < deg0) ? __int_as_float(e05.y) : 0.f;
        float w10 = (e     < deg1) ? __int_as_float(e10.y) : 0.f;
        float w11 = (e + 1 < deg1) ? __int_as_float(e11.y) : 0.f;
        float w12 = (e + 2 < deg1) ? __int_as_float(e12.y) : 0.f;
        float w13 = (e + 3 < deg1) ? __int_as_float(e13.y) : 0.f;
        float w14 = (e + 4 < deg1) ? __int_as_float(e14.y) : 0.f;
        float w15 = (e + 5 < deg1) ? __int_as_float(e15.y) : 0.f;
        a0x += u00.x * w00 + u01.x * w01 + u02.x * w02 + u03.x * w03 + u04.x * w04 + u05.x * w05;
        a0y += u00.y * w00 + u01.y * w01 + u02.y * w02 + u03.y * w03 + u04.y * w04 + u05.y * w05;
        a0z += u00.z * w00 + u01.z * w01 + u02.z * w02 + u03.z * w03 + u04.z * w04 + u05.z * w05;
        a0w += u00.w * w00 + u01.w * w01 + u02.w * w02 + u03.w * w03 + u04.w * w04 + u05.w * w05;
        a1x += u10.x * w10 + u11.x * w11 + u12.x * w12 + u13.x * w13 + u14.x * w14 + u15.x * w15;
        a1y += u10.y * w10 + u11.y * w11 + u12.y * w12 + u13.y * w13 + u14.y * w14 + u15.y * w15;
        a1z += u10.z * w10 + u11.z * w11 + u12.z * w12 + u13.z * w13 + u14.z * w14 + u15.z * w15;
        a1w += u10.w * w10 + u11.w * w11 + u12.w * w12 + u13.w * w13 + u14.w * w14 + u15.w * w15;
    }
    float4 bv = ((const float4*)bias)[sl];
    float4 r0, r1;
    r0.x = lrelu(a0x + bv.x) + ho0.x;
    r0.y = lrelu(a0y + bv.y) + ho0.y;
    r0.z = lrelu(a0z + bv.z) + ho0.z;
    r0.w = lrelu(a0w + bv.w) + ho0.w;
    r1.x = lrelu(a1x + bv.x) + ho1.x;
    r1.y = lrelu(a1y + bv.y) + ho1.y;
    r1.z = lrelu(a1z + bv.z) + ho1.z;
    r1.w = lrelu(a1w + bv.w) + ho1.w;
    if (val0) ((float4*)(h + (size_t)n0 * FEAT))[sl] = r0;
    if (val1) ((float4*)(h + (size_t)n1 * FEAT))[sl] = r1;
}

// ---------------- selective final agg (layer 4): S0 rows only -> hq, no leaky ----------------
__global__ void k_aggq(const float* __restrict__ hw, const float* __restrict__ h,
                       const int4* __restrict__ meta, const int2* __restrict__ csre,
                       const float* __restrict__ gbias, float* __restrict__ hq) {
    int tid = threadIdx.x;
    int sl = tid & 31;
    int q = blockIdx.x * 8 + (tid >> 5);   // 0..2559
    int b = q / NQ, i = q - b * NQ;
    int node = b * (NQ * NLAY) + i;
    int4 m = meta[node];
    float di = __int_as_float(m.z);
    int off = m.x, deg = m.y;
    float s2 = di * di;
    float4 v = ((const float4*)(hw + (size_t)node * FEAT))[sl];
    float ax = v.x * s2, ay = v.y * s2, az = v.z * s2, aw = v.w * s2;
    int dc = max(deg - 1, 0);
    for (int e = 0; e < deg; e += 4) {
        int2 e0 = csre[off + min(e,     dc)];
        int2 e1 = csre[off + min(e + 1, dc)];
        int2 e2 = csre[off + min(e + 2, dc)];
        int2 e3 = csre[off + min(e + 3, dc)];
        float4 u0 = ((const float4*)(hw + (size_t)e0.x * FEAT))[sl];
        float4 u1 = ((const float4*)(hw + (size_t)e1.x * FEAT))[sl];
        float4 u2 = ((const float4*)(hw + (size_t)e2.x * FEAT))[sl];
        float4 u3 = ((const float4*)(hw + (size_t)e3.x * FEAT))[sl];
        float w0 = (e     < deg) ? __int_as_float(e0.y) : 0.f;
        float w1 = (e + 1 < deg) ? __int_as_float(e1.y) : 0.f;
        float w2 = (e + 2 < deg) ? __int_as_float(e2.y) : 0.f;
        float w3 = (e + 3 < deg) ? __int_as_float(e3.y) : 0.f;
        ax += u0.x * w0 + u1.x * w1 + u2.x * w2 + u3.x * w3;
        ay += u0.y * w0 + u1.y * w1 + u2.y * w2 + u3.y * w3;
        az += u0.z * w0 + u1.z * w1 + u2.z * w2 + u3.z * w3;
        aw += u0.w * w0 + u1.w * w1 + u2.w * w2 + u3.w * w3;
    }
    float4 bv = ((const float4*)gbias)[sl];
    float4 ho = ((const float4*)(h + (size_t)node * FEAT))[sl];
    ((float4*)(hq + (size_t)q * FEAT))[sl] =
        make_float4(ax + bv.x + ho.x, ay + bv.y + ho.y, az + bv.z + ho.z, aw + bv.w + ho.w);
}

// ---------------- last layer + symmetrize, one block per batch ----------------
__global__ void k_lastsym(const float* __restrict__ X4, const float* __restrict__ mw5,
                          const float* __restrict__ mb5, float* __restrict__ out) {
    __shared__ float w[64];
    __shared__ float sm[NQ * NQ];
    int t = threadIdx.x;
    if (t < 64) w[t] = mw5[t];
    __syncthreads();
    int b = blockIdx.x;
    for (int p = t; p < NQ * NQ; p += 256) {
        const float4* row = (const float4*)(X4 + (size_t)(b * NQ * NQ + p) * 64);
        float s = 0.f;
#pragma unroll
        for (int k4 = 0; k4 < 16; k4++) {
            float4 v = row[k4];
            s += v.x * w[k4 * 4] + v.y * w[k4 * 4 + 1] + v.z * w[k4 * 4 + 2] + v.w * w[k4 * 4 + 3];
        }
        sm[p] = s + mb5[0];
    }
    __syncthreads();
    for (int r = t; r < NQ * NQ; r += 256) {
        int i = r / NQ, j = r % NQ;
        out[(size_t)b * NQ * NQ + r] = 0.5f * (sm[r] + sm[j * NQ + i]);
    }
}

extern "C" void kernel_launch(void* const* d_in, const int* in_sizes, int n_in,
                              void* d_out, int out_size, void* d_ws, size_t ws_size,
                              hipStream_t stream) {
    const int* x = (const int*)d_in[0];
    const int* ei = (const int*)d_in[1];
    const int* e_src = ei;
    const int* e_dst = ei + NE;
    const float* emb = (const float*)d_in[2];
    const float* gw = (const float*)d_in[3];   // [5,128,128]
    const float* gb = (const float*)d_in[4];   // [5,128]
    const float* mw0 = (const float*)d_in[5];
    const float* mb0 = (const float*)d_in[6];
    const float* mw1 = (const float*)d_in[7];
    const float* mb1 = (const float*)d_in[8];
    const float* mw2 = (const float*)d_in[9];
    const float* mb2 = (const float*)d_in[10];
    const float* mw3 = (const float*)d_in[11];
    const float* mb3 = (const float*)d_in[12];
    const float* mw4 = (const float*)d_in[13];
    const float* mb4 = (const float*)d_in[14];
    const float* mw5 = (const float*)d_in[15];
    const float* mb5 = (const float*)d_in[16];
    float* out = (float*)d_out;

    float* wsf = (float*)d_ws;
    size_t o = 0;
    const size_t HSZ = (size_t)NN * FEAT;             // 16,711,680
    float* h  = wsf + o; o += HSZ;    // single in-place h buffer
    float* hw = wsf + o; o += HSZ;
    // zero-memset region: cnt, fill, flag1, flag2, flag3, cursors (contiguous)
    int* cnt   = (int*)(wsf + o); o += NN;
    int* fill  = (int*)(wsf + o); o += NN;
    int* flag1 = (int*)(wsf + o); o += NN;
    int* flag2 = (int*)(wsf + o); o += NN;
    int* flag3 = (int*)(wsf + o); o += NN;
    int* curs  = (int*)(wsf + o); o += 16;   // [0]=offs [1]=list1 [2]=list2 [3]=list3
    // 0xFF-memset region: list1, list2, list3 (contiguous, sentinel -1)
    int* list1 = (int*)(wsf + o); o += NN;
    int* list2 = (int*)(wsf + o); o += NN;
    int* list3 = (int*)(wsf + o); o += NN;
    int* offs = (int*)(wsf + o); o += NN;
    float* dinv = wsf + o; o += NN;
    int4* meta = (int4*)(wsf + o); o += 4 * (size_t)NN;
    int2* csre  = (int2*)(wsf + o); o += 2 * (size_t)(NE + 8);  // +8 slop for deg-0 clamp
    int2* csre0 = (int2*)(wsf + o); o += 2 * (size_t)(NE + 8);  // token edges
    int* idmap = (int*)(wsf + o); o += 1024;
    float* embW = wsf + o; o += (size_t)1024 * FEAT;          // emb@W0 table
    float* hq = wsf + o; o += (size_t)BATCH * NQ * FEAT;      // 327,680
    float* Abuf = wsf + o; o += (size_t)BATCH * NQ * 256;     // 655,360
    float* Bbuf = wsf + o; o += (size_t)BATCH * NQ * 256;     // 655,360
    _Float16* bt_hi = (_Float16*)(wsf + o); o += (TS_TOTAL + 2) / 2;
    _Float16* bt_lo = (_Float16*)(wsf + o); o += (TS_TOTAL + 2) / 2;
    // pair-phase aliases (hw, h dead after aggq)
    float* X1 = hw;                         // 51200*128
    float* X2 = hw + (size_t)NPAIR * 128;   // 51200*128
    float* X3 = h;                          // 51200*64
    float* X4 = h + (size_t)NPAIR * 64;     // 51200*64

    // --- weight transpose+split+pack ---
    k_tsplit_all<<<TS_TOTAL / 256, 256, 0, stream>>>(gw, mw0, mw1, mw2, mw3, mw4, bt_hi, bt_lo);

    // --- CSR build + cone lists S1/S2/S3 ---
    hipMemsetAsync(cnt, 0, (5 * NN + 16) * sizeof(int), stream); // cnt+fill+flags+cursors
    hipMemsetAsync(list1, 0xFF, 3 * NN * sizeof(int), stream);   // list sentinels (-1)
    hipMemsetAsync(csre + NE, 0, 8 * sizeof(int2), stream);      // slop
    hipMemsetAsync(csre0 + NE, 0, 8 * sizeof(int2), stream);     // slop
    k_count<<<NE / 256, 256, 0, stream>>>(e_dst, cnt);
    k_offsets<<<NB, 256, 0, stream>>>(cnt, x, offs, dinv, meta, curs + 0, flag1, idmap);
    k_fill<<<NE / 256, 256, 0, stream>>>(e_src, e_dst, offs, fill, dinv, x, csre, csre0, flag1);
    k_s1pass<<<NB, 256, 0, stream>>>(flag1, meta, csre, curs + 1, list1, flag2);  // S1 + mark S2
    k_s1pass<<<NB, 256, 0, stream>>>(flag2, meta, csre, curs + 2, list2, flag3);  // S2 + mark S3
    k_emit2<<<NB, 256, 0, stream>>>(flag3, curs + 3, list3);                      // S3

    // --- layer 0 via token table: embW = emb@W0 (1021 rows, clamped id map) ---
    hgemm<8, false, false, false, false, true, false><<<dim3(8, 1), 256, 0, stream>>>(
        emb, nullptr, nullptr, bt_hi + OFF_GCN, bt_lo + OFF_GCN,
        nullptr, embW, nullptr, FEAT, FEAT, idmap, nullptr);
    k_agg0<<<NN / 16, 256, 0, stream>>>(embW, emb, h, meta, csre0, gb + 0 * FEAT);

    // --- layer 1: full gemm + agg@S3 ---
    hgemm<8, false, false, false, false, false, false><<<dim3(NN / 128, 1), 256, 0, stream>>>(
        h, nullptr, nullptr, bt_hi + OFF_GCN + 1 * 16384, bt_lo + OFF_GCN + 1 * 16384,
        nullptr, hw, nullptr, FEAT, FEAT, nullptr, nullptr);
    k_agg<<<NN / 16, 256, 0, stream>>>(hw, h, meta, csre, list3, gb + 1 * FEAT);

    // --- layer 2: gemm@S3 + agg@S2 ---
    hgemm<8, false, false, false, false, false, true><<<dim3(NN / 128, 1), 256, 0, stream>>>(
        h, nullptr, nullptr, bt_hi + OFF_GCN + 2 * 16384, bt_lo + OFF_GCN + 2 * 16384,
        nullptr, hw, nullptr, FEAT, FEAT, nullptr, list3);
    k_agg<<<NN / 16, 256, 0, stream>>>(hw, h, meta, csre, list2, gb + 2 * FEAT);

    // --- layer 3: gemm@S2 + agg@S1 ---
    hgemm<8, false, false, false, false, false, true><<<dim3(NN / 128, 1), 256, 0, stream>>>(
        h, nullptr, nullptr, bt_hi + OFF_GCN + 3 * 16384, bt_lo + OFF_GCN + 3 * 16384,
        nullptr, hw, nullptr, FEAT, FEAT, nullptr, list2);
    k_agg<<<NN / 16, 256, 0, stream>>>(hw, h, meta, csre, list1, gb + 3 * FEAT);

    // --- layer 4: gemm@S1 + selective agg@S0 -> hq ---
    hgemm<8, false, false, false, false, false, true><<<dim3(NN / 128, 1), 256, 0, stream>>>(
        h, nullptr, nullptr, bt_hi + OFF_GCN + 4 * 16384, bt_lo + OFF_GCN + 4 * 16384,
        nullptr, hw, nullptr, FEAT, FEAT, nullptr, list1);
    k_aggq<<<(BATCH * NQ) / 8, 256, 0, stream>>>(hw, h, meta, csre,
                                                 gb + 4 * (size_t)FEAT, hq);

    // --- pair MLP ---
    hgemm<8, false, false, true, false, false, false><<<dim3(20, 4), 256, 0, stream>>>(
        hq, nullptr, nullptr, bt_hi + OFF_P0, bt_lo + OFF_P0, mb0, Abuf, Bbuf, 512, 128,
        nullptr, nullptr);
    hgemm<8, true, true, false, true, false, false><<<dim3(NPAIR / 128, 1), 256, 0, stream>>>(
        nullptr, Abuf, Bbuf, bt_hi + OFF_M1, bt_lo + OFF_M1, mb1, X1, nullptr, 128, 256,
        nullptr, nullptr);
    hgemm<8, true, true, false, false, false, false><<<dim3(NPAIR / 128, 1), 256, 0, stream>>>(
        X1, nullptr, nullptr, bt_hi + OFF_M2, bt_lo + OFF_M2, mb2, X2, nullptr, 128, 128,
        nullptr, nullptr);
    hgemm<4, true, true, false, false, false, false><<<dim3(NPAIR / 128, 1), 256, 0, stream>>>(
        X2, nullptr, nullptr, bt_hi + OFF_M3, bt_lo + OFF_M3, mb3, X3, nullptr, 64, 128,
        nullptr, nullptr);
    hgemm<4, true, true, false, false, false, false><<<dim3(NPAIR / 128, 1), 256, 0, stream>>>(
        X3, nullptr, nullptr, bt_hi + OFF_M4, bt_lo + OFF_M4, mb4, X4, nullptr, 64, 64,
        nullptr, nullptr);
    k_lastsym<<<BATCH, 256, 0, stream>>>(X4, mw5, mb5, out);
}